// Round 1
// baseline (2317.241 us; speedup 1.0000x reference)
//
#include <hip/hip_runtime.h>

#define EPSF 1e-9f

__device__ __forceinline__ float2 cmul(float cr, float ci, float2 v) {
    return make_float2(cr * v.x - ci * v.y, ci * v.x + cr * v.y);
}

// ---------------- lambda tables: L1, O1(one-minus), L2, L3 ----------------
__global__ void k_lamtab(const float* __restrict__ ldt, const float* __restrict__ llr,
                         const float* __restrict__ lim, float* __restrict__ tab) {
    int p = threadIdx.x;
    if (p >= 64) return;
    float dt  = expf(ldt[0]);
    float mag = expf(-expf(llr[p]) * dt);
    float ph  = lim[p] * dt;
    float c = cosf(ph), s = sinf(ph);
    float m2 = mag * mag, m3 = m2 * mag;
    float c2 = c * c - s * s, s2 = 2.f * c * s;
    float c3 = c2 * c - s2 * s, s3 = s2 * c + c2 * s;
    tab[p]        = c * mag;          tab[64 + p]  = s * mag;          // L1
    tab[128 + p]  = c * (1.f - mag);  tab[192 + p] = s * (1.f - mag);  // O1
    tab[256 + p]  = c2 * m2;          tab[320 + p] = s2 * m2;          // L2
    tab[384 + p]  = c3 * m3;          tab[448 + p] = s3 * m3;          // L3
}

// ---------------- fused MLP: xp = (silu(xW1) * (xW2)) @ Wp + bp ----------------
__global__ void __launch_bounds__(256)
k_mlp(const float* __restrict__ x, const float* __restrict__ W1,
      const float* __restrict__ W2, const float* __restrict__ Wp,
      const float* __restrict__ bp, float* __restrict__ xp, int N) {
    __shared__ float smem[64 * 256];                 // 64KB: xs (32KB) then reused as hs
    float (*xs)[128] = (float (*)[128])smem;
    float (*hs)[256] = (float (*)[256])smem;

    const int t = threadIdx.x;
    const int row0 = blockIdx.x * 64;

    {   // stage 64x128 x-tile
        const float4* xsrc = (const float4*)x;
        float4* xd = (float4*)smem;
#pragma unroll
        for (int j = 0; j < 8; ++j) {
            int idx = t + 256 * j;
            int r = idx >> 5;
            int gr = row0 + r;
            float4 v = make_float4(0.f, 0.f, 0.f, 0.f);
            if (gr < N) v = xsrc[(size_t)gr * 32 + (idx & 31)];
            xd[idx] = v;
        }
    }
    __syncthreads();

    const int wid = t >> 6, lane = t & 63;
    const int r0 = wid * 16;
    const int c4 = lane * 4;

    float g1[16][4], g2[16][4];
#pragma unroll
    for (int r = 0; r < 16; ++r)
#pragma unroll
        for (int j = 0; j < 4; ++j) { g1[r][j] = 0.f; g2[r][j] = 0.f; }

    for (int k = 0; k < 128; ++k) {
        float4 w1 = *(const float4*)&W1[k * 256 + c4];
        float4 w2 = *(const float4*)&W2[k * 256 + c4];
#pragma unroll
        for (int r = 0; r < 16; ++r) {
            float xv = xs[r0 + r][k];
            g1[r][0] += xv * w1.x; g1[r][1] += xv * w1.y;
            g1[r][2] += xv * w1.z; g1[r][3] += xv * w1.w;
            g2[r][0] += xv * w2.x; g2[r][1] += xv * w2.y;
            g2[r][2] += xv * w2.z; g2[r][3] += xv * w2.w;
        }
    }
    __syncthreads();   // all waves done reading xs; smem becomes hs
#pragma unroll
    for (int r = 0; r < 16; ++r) {
        float4 h;
        float a0 = g1[r][0], a1v = g1[r][1], a2v = g1[r][2], a3v = g1[r][3];
        h.x = (a0  / (1.f + __expf(-a0)))  * g2[r][0];
        h.y = (a1v / (1.f + __expf(-a1v))) * g2[r][1];
        h.z = (a2v / (1.f + __expf(-a2v))) * g2[r][2];
        h.w = (a3v / (1.f + __expf(-a3v))) * g2[r][3];
        *(float4*)&hs[r0 + r][c4] = h;
    }
    __syncthreads();

    const int c2 = lane * 2;
    float o[16][2];
#pragma unroll
    for (int r = 0; r < 16; ++r) { o[r][0] = 0.f; o[r][1] = 0.f; }

    for (int k = 0; k < 256; ++k) {
        float2 wp = *(const float2*)&Wp[k * 128 + c2];
#pragma unroll
        for (int r = 0; r < 16; ++r) {
            float hv = hs[r0 + r][k];
            o[r][0] += hv * wp.x; o[r][1] += hv * wp.y;
        }
    }
    float2 bv = *(const float2*)&bp[c2];
#pragma unroll
    for (int r = 0; r < 16; ++r) {
        int gr = row0 + r0 + r;
        if (gr < N) {
            float2 ov = make_float2(o[r][0] + bv.x, o[r][1] + bv.y);
            *(float2*)&xp[(size_t)gr * 128 + c2] = ov;
        }
    }
}

// ---------------- degree + node scalars ----------------
__global__ void k_deg(const int* __restrict__ ei, int E, int* degi) {
    int e = blockIdx.x * blockDim.x + threadIdx.x;
    if (e < E) atomicAdd(&degi[ei[e]], 1);
}

__global__ void k_bq(const int* __restrict__ degi, int N, float* __restrict__ bv) {
    int v = blockIdx.x * blockDim.x + threadIdx.x;
    if (v < N) {
        int d = degi[v];
        bv[v] = (d > 1) ? (-1.f / ((float)d - 1.f + EPSF)) : 0.f;
    }
}

__global__ void k_scalagg(const int* __restrict__ ei, int E, const float* __restrict__ bv,
                          float* __restrict__ B, float* __restrict__ B2) {
    int e = blockIdx.x * blockDim.x + threadIdx.x;
    if (e < E) {
        int s = ei[e], d = ei[E + e];
        float bs = bv[s];
        atomicAdd(&B[d], bs);
        atomicAdd(&B2[d], bs * bs);
    }
}

// ---------------- vector aggregation: o1[d] += tbl[s]; o2[d] += b[s]*tbl[s] ----------------
__global__ void k_agg2(const float* __restrict__ tbl, const float* __restrict__ bw,
                       float* __restrict__ o1, float* o2,
                       const int* __restrict__ ei, int E) {
    int tid = blockIdx.x * blockDim.x + threadIdx.x;
    int e = tid >> 6, l = tid & 63;
    if (e >= E) return;
    int s = ei[e], d = ei[E + e];
    float2 v = *(const float2*)&tbl[(size_t)s * 128 + 2 * l];
    float* p1 = &o1[(size_t)d * 128 + 2 * l];
    atomicAdd(p1, v.x);
    atomicAdd(p1 + 1, v.y);
    if (o2 != nullptr) {
        float bs = bw[s];
        float* p2 = &o2[(size_t)d * 128 + 2 * l];
        atomicAdd(p2, bs * v.x);
        atomicAdd(p2 + 1, bs * v.y);
    }
}

// ---------------- node kernels ----------------
__global__ void k_node1(const float* __restrict__ xp, const float* __restrict__ m0,
                        const int* __restrict__ degi, const float* __restrict__ tab,
                        float* __restrict__ a1, int N) {
    int tid = blockIdx.x * blockDim.x + threadIdx.x;
    int v = tid >> 6, p = tid & 63;
    if (v >= N) return;
    size_t off = (size_t)v * 128 + 2 * p;
    float2 xv = *(const float2*)&xp[off];
    float2 mv = *(const float2*)&m0[off];
    int dg = degi[v];
    float L1r = tab[p], L1i = tab[64 + p], O1r = tab[128 + p], O1i = tab[192 + p];
    float Q = 1.f / ((float)dg - 1.f + EPSF);
    float2 t1 = cmul(O1r, O1i, xv);
    float2 t2 = cmul(L1r, L1i, mv);
    float2 a = make_float2(t1.x + Q * t2.x, t1.y + Q * t2.y);
    if (dg == 1) a = xv;
    *(float2*)&a1[off] = a;
}

__global__ void k_node2(const float* __restrict__ xp, const float* __restrict__ A1,
                        const float* __restrict__ Bv, const int* __restrict__ degi,
                        const float* __restrict__ tab, float* __restrict__ a2, int N) {
    int tid = blockIdx.x * blockDim.x + threadIdx.x;
    int v = tid >> 6, p = tid & 63;
    if (v >= N) return;
    size_t off = (size_t)v * 128 + 2 * p;
    float2 xv = *(const float2*)&xp[off];
    float2 Av = *(const float2*)&A1[off];
    int dg = degi[v];
    float Bs = Bv[v];
    float L1r = tab[p], L1i = tab[64 + p], O1r = tab[128 + p], O1i = tab[192 + p];
    float2 lx = cmul(L1r, L1i, xv);
    float2 m1 = make_float2(Av.x + Bs * lx.x, Av.y + Bs * lx.y);
    float Q = 1.f / ((float)dg - 1.f + EPSF);
    float2 t1 = cmul(O1r, O1i, xv);
    float2 lm = cmul(L1r, L1i, m1);
    float2 a = make_float2(t1.x + Q * lm.x, t1.y + Q * lm.y);
    if (dg == 1) a = xv;
    *(float2*)&a2[off] = a;
}

__global__ void k_node3(const float* __restrict__ xp, const float* __restrict__ A2,
                        const float* __restrict__ a1, const float* __restrict__ Xb,
                        const float* __restrict__ Bv, const float* __restrict__ bv,
                        const int* __restrict__ degi, const float* __restrict__ tab,
                        float* __restrict__ a3, int N) {
    int tid = blockIdx.x * blockDim.x + threadIdx.x;
    int v = tid >> 6, p = tid & 63;
    if (v >= N) return;
    size_t off = (size_t)v * 128 + 2 * p;
    float2 xv  = *(const float2*)&xp[off];
    float2 Av  = *(const float2*)&A2[off];
    float2 a1v = *(const float2*)&a1[off];
    float2 Xbv = *(const float2*)&Xb[off];
    int dg = degi[v];
    float Bs = Bv[v], bs = bv[v];
    float L1r = tab[p], L1i = tab[64 + p], O1r = tab[128 + p], O1i = tab[192 + p];
    float L2r = tab[256 + p], L2i = tab[320 + p];
    float2 la1 = cmul(L1r, L1i, a1v);
    float2 lxb = cmul(L2r, L2i, Xbv);
    float2 m2 = make_float2(Av.x + Bs * la1.x + bs * lxb.x,
                            Av.y + Bs * la1.y + bs * lxb.y);
    float Q = 1.f / ((float)dg - 1.f + EPSF);
    float2 t1 = cmul(O1r, O1i, xv);
    float2 lm = cmul(L1r, L1i, m2);
    float2 a = make_float2(t1.x + Q * lm.x, t1.y + Q * lm.y);
    if (dg == 1) a = xv;
    *(float2*)&a3[off] = a;
}

__global__ void k_node4(const float* __restrict__ xin, const float* __restrict__ xp,
                        const float* __restrict__ A3, const float* a2,
                        const float* __restrict__ Ab1,
                        const float* __restrict__ Bv, const float* __restrict__ bv,
                        const float* __restrict__ B2v, const int* __restrict__ degi,
                        const float* __restrict__ tab, float* out, int N) {
    int tid = blockIdx.x * blockDim.x + threadIdx.x;
    int v = tid >> 6, p = tid & 63;
    if (v >= N) return;
    size_t off = (size_t)v * 128 + 2 * p;
    float2 xv  = *(const float2*)&xp[off];
    float2 Av  = *(const float2*)&A3[off];
    float2 a2v = *(const float2*)&a2[off];
    float2 Abv = *(const float2*)&Ab1[off];
    int dg = degi[v];
    float Bs = Bv[v], bs = bv[v], B2s = B2v[v];
    float L1r = tab[p], L1i = tab[64 + p], O1r = tab[128 + p], O1i = tab[192 + p];
    float L2r = tab[256 + p], L2i = tab[320 + p];
    float L3r = tab[384 + p], L3i = tab[448 + p];
    float2 la2 = cmul(L1r, L1i, a2v);
    float2 lab = cmul(L2r, L2i, Abv);
    float2 lx3 = cmul(L3r, L3i, xv);
    float bB2 = bs * B2s;
    float2 m3 = make_float2(Av.x + Bs * la2.x + bs * lab.x + bB2 * lx3.x,
                            Av.y + Bs * la2.y + bs * lab.y + bB2 * lx3.y);
    float2 g;
    if (dg == 0) {
        g = xv;
    } else {
        float inv = 1.f / ((float)dg + EPSF);
        float2 t1 = cmul(O1r, O1i, xv);
        float2 lm = cmul(L1r, L1i, m3);
        g = make_float2(t1.x + lm.x * inv, t1.y + lm.y * inv);
    }
    float2 xi = *(const float2*)&xin[off];
    float2 res = make_float2(xi.x + fmaxf(g.x, 0.f), xi.y + fmaxf(g.y, 0.f));
    *(float2*)&out[off] = res;
}

extern "C" void kernel_launch(void* const* d_in, const int* in_sizes, int n_in,
                              void* d_out, int out_size, void* d_ws, size_t ws_size,
                              hipStream_t stream) {
    const float* x   = (const float*)d_in[0];
    const int*   ei  = (const int*)d_in[1];
    const float* ldt = (const float*)d_in[2];
    const float* llr = (const float*)d_in[3];
    const float* lim = (const float*)d_in[4];
    const float* W1  = (const float*)d_in[5];
    const float* W2  = (const float*)d_in[6];
    const float* Wp  = (const float*)d_in[7];
    const float* bp  = (const float*)d_in[8];
    float* out = (float*)d_out;

    const int N = in_sizes[0] / 128;
    const int E = in_sizes[1] / 2;
    const size_t nd = (size_t)N * 128;

    float* ws  = (float*)d_ws;
    float* xp  = ws;            // post-MLP x
    float* s1  = ws + nd;       // m0, later A2
    float* s2  = ws + 2 * nd;   // Xb, later A3
    float* a1  = ws + 3 * nd;   // a1
    float* s4  = ws + 4 * nd;   // A1, later a3
    float* ab1 = ws + 5 * nd;   // Ab1
    float* a2  = out;           // a2 lives in d_out until k_node4 overwrites it
    float* scal = ws + 6 * nd;
    int*   degi = (int*)scal;        // N ints
    float* bv   = scal + (size_t)N;
    float* Bv   = scal + 2 * (size_t)N;
    float* B2v  = scal + 3 * (size_t)N;
    float* tab  = scal + 4 * (size_t)N;  // 512 floats

    const int nodeBlocks = (int)(((size_t)N * 64 + 255) / 256);
    const int aggBlocks  = (int)(((size_t)E * 64 + 255) / 256);
    const int eBlocks    = (E + 255) / 256;

    // scalars
    hipMemsetAsync(scal, 0, 4 * (size_t)N * sizeof(float), stream);
    k_lamtab<<<1, 64, 0, stream>>>(ldt, llr, lim, tab);
    k_mlp<<<(N + 63) / 64, 256, 0, stream>>>(x, W1, W2, Wp, bp, xp, N);
    k_deg<<<eBlocks, 256, 0, stream>>>(ei, E, degi);
    k_bq<<<(N + 255) / 256, 256, 0, stream>>>(degi, N, bv);
    k_scalagg<<<eBlocks, 256, 0, stream>>>(ei, E, bv, Bv, B2v);

    // P0: m0 = sum x_s, Xb = sum b_s x_s
    hipMemsetAsync(s1, 0, 2 * nd * sizeof(float), stream);
    k_agg2<<<aggBlocks, 256, 0, stream>>>(xp, bv, s1, s2, ei, E);
    k_node1<<<nodeBlocks, 256, 0, stream>>>(xp, s1, degi, tab, a1, N);

    // P1: A1 = sum a1, Ab1 = sum b a1
    hipMemsetAsync(s4, 0, 2 * nd * sizeof(float), stream);
    k_agg2<<<aggBlocks, 256, 0, stream>>>(a1, bv, s4, ab1, ei, E);
    k_node2<<<nodeBlocks, 256, 0, stream>>>(xp, s4, Bv, degi, tab, a2, N);

    // P2: A2 = sum a2   (A2 reuses s1)
    hipMemsetAsync(s1, 0, nd * sizeof(float), stream);
    k_agg2<<<aggBlocks, 256, 0, stream>>>(a2, nullptr, s1, nullptr, ei, E);
    k_node3<<<nodeBlocks, 256, 0, stream>>>(xp, s1, a1, s2, Bv, bv, degi, tab, s4, N); // a3 -> s4

    // P3: A3 = sum a3   (A3 reuses s2)
    hipMemsetAsync(s2, 0, nd * sizeof(float), stream);
    k_agg2<<<aggBlocks, 256, 0, stream>>>(s4, nullptr, s2, nullptr, ei, E);
    k_node4<<<nodeBlocks, 256, 0, stream>>>(x, xp, s2, a2, ab1, Bv, bv, B2v, degi, tab, out, N);
}

// Round 2
// 589.902 us; speedup vs baseline: 3.9282x; 3.9282x over previous
//
#include <hip/hip_runtime.h>

#define EPSF 1e-9f

__device__ __forceinline__ float2 cmul(float cr, float ci, float2 v) {
    return make_float2(cr * v.x - ci * v.y, ci * v.x + cr * v.y);
}

// ---------------- lambda tables: L1, O1(one-minus), L2, L3 ----------------
__global__ void k_lamtab(const float* __restrict__ ldt, const float* __restrict__ llr,
                         const float* __restrict__ lim, float* __restrict__ tab) {
    int p = threadIdx.x;
    if (p >= 64) return;
    float dt  = expf(ldt[0]);
    float mag = expf(-expf(llr[p]) * dt);
    float ph  = lim[p] * dt;
    float c = cosf(ph), s = sinf(ph);
    float m2 = mag * mag, m3 = m2 * mag;
    float c2 = c * c - s * s, s2 = 2.f * c * s;
    float c3 = c2 * c - s2 * s, s3 = s2 * c + c2 * s;
    tab[p]        = c * mag;          tab[64 + p]  = s * mag;          // L1
    tab[128 + p]  = c * (1.f - mag);  tab[192 + p] = s * (1.f - mag);  // O1
    tab[256 + p]  = c2 * m2;          tab[320 + p] = s2 * m2;          // L2
    tab[384 + p]  = c3 * m3;          tab[448 + p] = s3 * m3;          // L3
}

// ---------------- fused MLP: xp = (silu(xW1) * (xW2)) @ Wp + bp ----------------
__global__ void __launch_bounds__(256)
k_mlp(const float* __restrict__ x, const float* __restrict__ W1,
      const float* __restrict__ W2, const float* __restrict__ Wp,
      const float* __restrict__ bp, float* __restrict__ xp, int N) {
    __shared__ float smem[64 * 256];                 // 64KB: xs (32KB) then reused as hs
    float (*xs)[128] = (float (*)[128])smem;
    float (*hs)[256] = (float (*)[256])smem;

    const int t = threadIdx.x;
    const int row0 = blockIdx.x * 64;

    {   // stage 64x128 x-tile
        const float4* xsrc = (const float4*)x;
        float4* xd = (float4*)smem;
#pragma unroll
        for (int j = 0; j < 8; ++j) {
            int idx = t + 256 * j;
            int r = idx >> 5;
            int gr = row0 + r;
            float4 v = make_float4(0.f, 0.f, 0.f, 0.f);
            if (gr < N) v = xsrc[(size_t)gr * 32 + (idx & 31)];
            xd[idx] = v;
        }
    }
    __syncthreads();

    const int wid = t >> 6, lane = t & 63;
    const int r0 = wid * 16;
    const int c4 = lane * 4;

    float g1[16][4], g2[16][4];
#pragma unroll
    for (int r = 0; r < 16; ++r)
#pragma unroll
        for (int j = 0; j < 4; ++j) { g1[r][j] = 0.f; g2[r][j] = 0.f; }

    for (int k = 0; k < 128; ++k) {
        float4 w1 = *(const float4*)&W1[k * 256 + c4];
        float4 w2 = *(const float4*)&W2[k * 256 + c4];
#pragma unroll
        for (int r = 0; r < 16; ++r) {
            float xv = xs[r0 + r][k];
            g1[r][0] += xv * w1.x; g1[r][1] += xv * w1.y;
            g1[r][2] += xv * w1.z; g1[r][3] += xv * w1.w;
            g2[r][0] += xv * w2.x; g2[r][1] += xv * w2.y;
            g2[r][2] += xv * w2.z; g2[r][3] += xv * w2.w;
        }
    }
    __syncthreads();   // all waves done reading xs; smem becomes hs
#pragma unroll
    for (int r = 0; r < 16; ++r) {
        float4 h;
        float a0 = g1[r][0], a1v = g1[r][1], a2v = g1[r][2], a3v = g1[r][3];
        h.x = (a0  / (1.f + __expf(-a0)))  * g2[r][0];
        h.y = (a1v / (1.f + __expf(-a1v))) * g2[r][1];
        h.z = (a2v / (1.f + __expf(-a2v))) * g2[r][2];
        h.w = (a3v / (1.f + __expf(-a3v))) * g2[r][3];
        *(float4*)&hs[r0 + r][c4] = h;
    }
    __syncthreads();

    const int c2 = lane * 2;
    float o[16][2];
#pragma unroll
    for (int r = 0; r < 16; ++r) { o[r][0] = 0.f; o[r][1] = 0.f; }

    for (int k = 0; k < 256; ++k) {
        float2 wp = *(const float2*)&Wp[k * 128 + c2];
#pragma unroll
        for (int r = 0; r < 16; ++r) {
            float hv = hs[r0 + r][k];
            o[r][0] += hv * wp.x; o[r][1] += hv * wp.y;
        }
    }
    float2 bv = *(const float2*)&bp[c2];
#pragma unroll
    for (int r = 0; r < 16; ++r) {
        int gr = row0 + r0 + r;
        if (gr < N) {
            float2 ov = make_float2(o[r][0] + bv.x, o[r][1] + bv.y);
            *(float2*)&xp[(size_t)gr * 128 + c2] = ov;
        }
    }
}

// ---------------- CSR build (by dst). in-deg == out-deg for this edge list ----------------
__global__ void k_hist(const int* __restrict__ ei, int E, int* __restrict__ cnt) {
    int e = blockIdx.x * blockDim.x + threadIdx.x;
    if (e < E) atomicAdd(&cnt[ei[E + e]], 1);      // histogram over dst
}

__global__ void __launch_bounds__(1024)
k_scan(const int* __restrict__ cnt, int N, int* __restrict__ off,
       int* __restrict__ cursor, float* __restrict__ bv) {
    __shared__ int sums[1024];
    int t = threadIdx.x;
    int chunk = (N + 1023) >> 10;
    int lo = t * chunk;
    int hi = min(lo + chunk, N);
    int s = 0;
    for (int i = lo; i < hi; ++i) s += cnt[i];
    sums[t] = s;
    __syncthreads();
    for (int d = 1; d < 1024; d <<= 1) {
        int v = (t >= d) ? sums[t - d] : 0;
        __syncthreads();
        sums[t] += v;
        __syncthreads();
    }
    int run = (t == 0) ? 0 : sums[t - 1];
    for (int i = lo; i < hi; ++i) {
        off[i] = run;
        cursor[i] = run;
        int c = cnt[i];
        bv[i] = (c > 1) ? (-1.f / ((float)c - 1.f + EPSF)) : 0.f;
        run += c;
    }
    if (t == 1023) off[N] = sums[1023];
}

__global__ void k_fill(const int* __restrict__ ei, int E,
                       int* __restrict__ cursor, int* __restrict__ csr) {
    int e = blockIdx.x * blockDim.x + threadIdx.x;
    if (e < E) {
        int s = ei[e], d = ei[E + e];
        int p = atomicAdd(&cursor[d], 1);
        csr[p] = s;
    }
}

// ---------------- fused gather + node passes (one wave per node) ----------------
// Pass A: m0 = sum xp[s]; Xb = sum b[s] xp[s]; a1 = node1(xp, m0)
__global__ void __launch_bounds__(256)
k_passA(const float* __restrict__ xp, const float* __restrict__ bv,
        const int* __restrict__ off, const int* __restrict__ csr,
        const float* __restrict__ tab, float* __restrict__ Xb,
        float* __restrict__ a1, int N) {
    int tid = blockIdx.x * blockDim.x + threadIdx.x;
    int v = tid >> 6, l = tid & 63;
    if (v >= N) return;
    int beg = off[v], end = off[v + 1];
    float2 m0 = make_float2(0.f, 0.f), xb = make_float2(0.f, 0.f);
    for (int k = beg; k < end; ++k) {
        int s = csr[k];
        float2 tv = *(const float2*)&xp[(size_t)s * 128 + 2 * l];
        float b = bv[s];
        m0.x += tv.x; m0.y += tv.y;
        xb.x += b * tv.x; xb.y += b * tv.y;
    }
    size_t o = (size_t)v * 128 + 2 * l;
    *(float2*)&Xb[o] = xb;
    float2 xv = *(const float2*)&xp[o];
    int dg = end - beg;
    float L1r = tab[l], L1i = tab[64 + l], O1r = tab[128 + l], O1i = tab[192 + l];
    float Q = 1.f / ((float)dg - 1.f + EPSF);
    float2 t1 = cmul(O1r, O1i, xv);
    float2 t2 = cmul(L1r, L1i, m0);
    float2 a = make_float2(t1.x + Q * t2.x, t1.y + Q * t2.y);
    if (dg == 1) a = xv;
    *(float2*)&a1[o] = a;
}

// Pass B: A1 = sum a1[s]; Ab1 = sum b a1[s]; B = sum b; B2 = sum b^2; a2 = node2
__global__ void __launch_bounds__(256)
k_passB(const float* __restrict__ xp, const float* __restrict__ a1,
        const float* __restrict__ bv, const int* __restrict__ off,
        const int* __restrict__ csr, const float* __restrict__ tab,
        float* __restrict__ Ab1, float* __restrict__ Bv, float* __restrict__ B2v,
        float* __restrict__ a2, int N) {
    int tid = blockIdx.x * blockDim.x + threadIdx.x;
    int v = tid >> 6, l = tid & 63;
    if (v >= N) return;
    int beg = off[v], end = off[v + 1];
    float2 A1 = make_float2(0.f, 0.f), ab = make_float2(0.f, 0.f);
    float Bs = 0.f, B2s = 0.f;
    for (int k = beg; k < end; ++k) {
        int s = csr[k];
        float2 tv = *(const float2*)&a1[(size_t)s * 128 + 2 * l];
        float b = bv[s];
        A1.x += tv.x; A1.y += tv.y;
        ab.x += b * tv.x; ab.y += b * tv.y;
        Bs += b; B2s += b * b;
    }
    size_t o = (size_t)v * 128 + 2 * l;
    *(float2*)&Ab1[o] = ab;
    if (l == 0) { Bv[v] = Bs; B2v[v] = B2s; }
    float2 xv = *(const float2*)&xp[o];
    int dg = end - beg;
    float L1r = tab[l], L1i = tab[64 + l], O1r = tab[128 + l], O1i = tab[192 + l];
    float2 lx = cmul(L1r, L1i, xv);
    float2 m1 = make_float2(A1.x + Bs * lx.x, A1.y + Bs * lx.y);
    float Q = 1.f / ((float)dg - 1.f + EPSF);
    float2 t1 = cmul(O1r, O1i, xv);
    float2 lm = cmul(L1r, L1i, m1);
    float2 a = make_float2(t1.x + Q * lm.x, t1.y + Q * lm.y);
    if (dg == 1) a = xv;
    *(float2*)&a2[o] = a;
}

// Pass C: A2 = sum a2[s]; a3 = node3
__global__ void __launch_bounds__(256)
k_passC(const float* __restrict__ xp, const float* __restrict__ a2,
        const float* __restrict__ a1, const float* __restrict__ Xb,
        const float* __restrict__ bv, const float* __restrict__ Bv,
        const int* __restrict__ off, const int* __restrict__ csr,
        const float* __restrict__ tab, float* __restrict__ a3, int N) {
    int tid = blockIdx.x * blockDim.x + threadIdx.x;
    int v = tid >> 6, l = tid & 63;
    if (v >= N) return;
    int beg = off[v], end = off[v + 1];
    float2 A2 = make_float2(0.f, 0.f);
    for (int k = beg; k < end; ++k) {
        int s = csr[k];
        float2 tv = *(const float2*)&a2[(size_t)s * 128 + 2 * l];
        A2.x += tv.x; A2.y += tv.y;
    }
    size_t o = (size_t)v * 128 + 2 * l;
    float2 xv  = *(const float2*)&xp[o];
    float2 a1v = *(const float2*)&a1[o];
    float2 Xbv = *(const float2*)&Xb[o];
    int dg = end - beg;
    float Bs = Bv[v], bs = bv[v];
    float L1r = tab[l], L1i = tab[64 + l], O1r = tab[128 + l], O1i = tab[192 + l];
    float L2r = tab[256 + l], L2i = tab[320 + l];
    float2 la1 = cmul(L1r, L1i, a1v);
    float2 lxb = cmul(L2r, L2i, Xbv);
    float2 m2 = make_float2(A2.x + Bs * la1.x + bs * lxb.x,
                            A2.y + Bs * la1.y + bs * lxb.y);
    float Q = 1.f / ((float)dg - 1.f + EPSF);
    float2 t1 = cmul(O1r, O1i, xv);
    float2 lm = cmul(L1r, L1i, m2);
    float2 a = make_float2(t1.x + Q * lm.x, t1.y + Q * lm.y);
    if (dg == 1) a = xv;
    *(float2*)&a3[o] = a;
}

// Pass D: A3 = sum a3[s]; out = x_in + relu(node4)   (a2 aliases out -> no restrict)
__global__ void __launch_bounds__(256)
k_passD(const float* __restrict__ xin, const float* __restrict__ xp,
        const float* __restrict__ a3, const float* a2,
        const float* __restrict__ Ab1, const float* __restrict__ bv,
        const float* __restrict__ Bv, const float* __restrict__ B2v,
        const int* __restrict__ off, const int* __restrict__ csr,
        const float* __restrict__ tab, float* out, int N) {
    int tid = blockIdx.x * blockDim.x + threadIdx.x;
    int v = tid >> 6, l = tid & 63;
    if (v >= N) return;
    int beg = off[v], end = off[v + 1];
    float2 A3 = make_float2(0.f, 0.f);
    for (int k = beg; k < end; ++k) {
        int s = csr[k];
        float2 tv = *(const float2*)&a3[(size_t)s * 128 + 2 * l];
        A3.x += tv.x; A3.y += tv.y;
    }
    size_t o = (size_t)v * 128 + 2 * l;
    float2 xv  = *(const float2*)&xp[o];
    float2 a2v = *(const float2*)&a2[o];
    float2 Abv = *(const float2*)&Ab1[o];
    int dg = end - beg;
    float Bs = Bv[v], bs = bv[v], B2s = B2v[v];
    float L1r = tab[l], L1i = tab[64 + l], O1r = tab[128 + l], O1i = tab[192 + l];
    float L2r = tab[256 + l], L2i = tab[320 + l];
    float L3r = tab[384 + l], L3i = tab[448 + l];
    float2 la2 = cmul(L1r, L1i, a2v);
    float2 lab = cmul(L2r, L2i, Abv);
    float2 lx3 = cmul(L3r, L3i, xv);
    float bB2 = bs * B2s;
    float2 m3 = make_float2(A3.x + Bs * la2.x + bs * lab.x + bB2 * lx3.x,
                            A3.y + Bs * la2.y + bs * lab.y + bB2 * lx3.y);
    float2 g;
    if (dg == 0) {
        g = xv;
    } else {
        float inv = 1.f / ((float)dg + EPSF);
        float2 t1 = cmul(O1r, O1i, xv);
        float2 lm = cmul(L1r, L1i, m3);
        g = make_float2(t1.x + lm.x * inv, t1.y + lm.y * inv);
    }
    float2 xi = *(const float2*)&xin[o];
    float2 res = make_float2(xi.x + fmaxf(g.x, 0.f), xi.y + fmaxf(g.y, 0.f));
    *(float2*)&out[o] = res;
}

extern "C" void kernel_launch(void* const* d_in, const int* in_sizes, int n_in,
                              void* d_out, int out_size, void* d_ws, size_t ws_size,
                              hipStream_t stream) {
    const float* x   = (const float*)d_in[0];
    const int*   ei  = (const int*)d_in[1];
    const float* ldt = (const float*)d_in[2];
    const float* llr = (const float*)d_in[3];
    const float* lim = (const float*)d_in[4];
    const float* W1  = (const float*)d_in[5];
    const float* W2  = (const float*)d_in[6];
    const float* Wp  = (const float*)d_in[7];
    const float* bp  = (const float*)d_in[8];
    float* out = (float*)d_out;

    const int N = in_sizes[0] / 128;
    const int E = in_sizes[1] / 2;
    const size_t nd = (size_t)N * 128;

    float* ws  = (float*)d_ws;
    float* xp  = ws;            // post-MLP x
    float* Xb  = ws + nd;
    float* a1  = ws + 2 * nd;
    float* ab1 = ws + 3 * nd;
    float* a3  = ws + 4 * nd;
    float* a2  = out;           // a2 lives in d_out until k_passD overwrites it

    int*   cnt    = (int*)(ws + 5 * nd);   // N
    int*   off    = cnt + N;               // N+1
    int*   cursor = off + N + 1;           // N
    float* bv     = (float*)(cursor + N);  // N
    float* Bv     = bv + N;                // N
    float* B2v    = Bv + N;                // N
    float* tab    = B2v + N;               // 512
    int*   csr    = (int*)(tab + 512);     // E

    const int nodeBlocks = (int)(((size_t)N * 64 + 255) / 256);
    const int eBlocks    = (E + 255) / 256;

    hipMemsetAsync(cnt, 0, (size_t)N * sizeof(int), stream);
    k_lamtab<<<1, 64, 0, stream>>>(ldt, llr, lim, tab);
    k_mlp<<<(N + 63) / 64, 256, 0, stream>>>(x, W1, W2, Wp, bp, xp, N);
    k_hist<<<eBlocks, 256, 0, stream>>>(ei, E, cnt);
    k_scan<<<1, 1024, 0, stream>>>(cnt, N, off, cursor, bv);
    k_fill<<<eBlocks, 256, 0, stream>>>(ei, E, cursor, csr);

    k_passA<<<nodeBlocks, 256, 0, stream>>>(xp, bv, off, csr, tab, Xb, a1, N);
    k_passB<<<nodeBlocks, 256, 0, stream>>>(xp, a1, bv, off, csr, tab, ab1, Bv, B2v, a2, N);
    k_passC<<<nodeBlocks, 256, 0, stream>>>(xp, a2, a1, Xb, bv, Bv, off, csr, tab, a3, N);
    k_passD<<<nodeBlocks, 256, 0, stream>>>(x, xp, a3, a2, ab1, bv, Bv, B2v, off, csr, tab, out, N);
}

// Round 3
// 494.624 us; speedup vs baseline: 4.6849x; 1.1926x over previous
//
#include <hip/hip_runtime.h>

#define EPSF 1e-9f

typedef __bf16 bf16x8 __attribute__((ext_vector_type(8)));
typedef float  f32x4  __attribute__((ext_vector_type(4)));
typedef unsigned short ushort_t;
typedef ushort_t us8 __attribute__((ext_vector_type(8)));

__device__ __forceinline__ float2 cmul(float cr, float ci, float2 v) {
    return make_float2(cr * v.x - ci * v.y, ci * v.x + cr * v.y);
}

__device__ __forceinline__ ushort_t f2bf(float f) {
    unsigned int u = __float_as_uint(f);
    u += 0x7FFFu + ((u >> 16) & 1u);   // RNE
    return (ushort_t)(u >> 16);
}

// ---------------- lambda tables: L1, O1(one-minus), L2, L3 ----------------
__global__ void k_lamtab(const float* __restrict__ ldt, const float* __restrict__ llr,
                         const float* __restrict__ lim, float* __restrict__ tab) {
    int p = threadIdx.x;
    if (p >= 64) return;
    float dt  = expf(ldt[0]);
    float mag = expf(-expf(llr[p]) * dt);
    float ph  = lim[p] * dt;
    float c = cosf(ph), s = sinf(ph);
    float m2 = mag * mag, m3 = m2 * mag;
    float c2 = c * c - s * s, s2 = 2.f * c * s;
    float c3 = c2 * c - s2 * s, s3 = s2 * c + c2 * s;
    tab[p]        = c * mag;          tab[64 + p]  = s * mag;          // L1
    tab[128 + p]  = c * (1.f - mag);  tab[192 + p] = s * (1.f - mag);  // O1
    tab[256 + p]  = c2 * m2;          tab[320 + p] = s2 * m2;          // L2
    tab[384 + p]  = c3 * m3;          tab[448 + p] = s3 * m3;          // L3
}

// ---------------- prep: x -> bf16 A-fragment layout ----------------
// frag index tid = (mt*4 + s)*64 + l ; element j: x[mt*16 + (l&15)][s*32 + (l>>4)*8 + j]
__global__ void k_prepx(const float* __restrict__ x, ushort_t* __restrict__ xa, int Mt) {
    int tid = blockIdx.x * blockDim.x + threadIdx.x;
    if (tid >= Mt * 256) return;
    int l  = tid & 63;
    int s  = (tid >> 6) & 3;
    int mt = tid >> 8;
    int row = mt * 16 + (l & 15);
    int kb  = s * 32 + (l >> 4) * 8;
    const float* src = x + (size_t)row * 128 + kb;
    float4 v0 = *(const float4*)src;
    float4 v1 = *(const float4*)(src + 4);
    us8 d;
    d[0] = f2bf(v0.x); d[1] = f2bf(v0.y); d[2] = f2bf(v0.z); d[3] = f2bf(v0.w);
    d[4] = f2bf(v1.x); d[5] = f2bf(v1.y); d[6] = f2bf(v1.z); d[7] = f2bf(v1.w);
    *(us8*)(xa + (size_t)tid * 8) = d;
}

// ---------------- prep: W[K][ncols] -> bf16 B-fragment layout ----------------
// tid = (nt*nsteps + s)*64 + l ; element j: W[s*32 + (l>>4)*8 + j][nt*16 + (l&15)]
__global__ void k_prepw(const float* __restrict__ w, ushort_t* __restrict__ wb,
                        int ncols, int nsteps, int total) {
    int tid = blockIdx.x * blockDim.x + threadIdx.x;
    if (tid >= total) return;
    int l  = tid & 63;
    int s  = (tid >> 6) % nsteps;
    int nt = tid / (64 * nsteps);
    int col = nt * 16 + (l & 15);
    int kb  = s * 32 + (l >> 4) * 8;
    us8 d;
#pragma unroll
    for (int j = 0; j < 8; ++j) d[j] = f2bf(w[(size_t)(kb + j) * ncols + col]);
    *(us8*)(wb + (size_t)tid * 8) = d;
}

// ---------------- MFMA fused MLP: xp = (silu(xW1) * (xW2)) @ Wp + bp ----------------
// 4 waves/block, wave = one 16-row m-tile. N=256 processed in two halves.
__global__ void __launch_bounds__(256)
k_mlpf(const ushort_t* __restrict__ xa, const ushort_t* __restrict__ wb1,
       const ushort_t* __restrict__ wb2, const ushort_t* __restrict__ wpb,
       const float* __restrict__ bp, float* __restrict__ xp, int Mt) {
    __shared__ ushort_t hs[4][2048];   // per-wave 16x128 bf16 H tile (swizzled)
    const int wid = threadIdx.x >> 6, l = threadIdx.x & 63;
    const int mt = blockIdx.x * 4 + wid;
    if (mt >= Mt) return;
    const int llo = l & 15, lhi = l >> 4;
    ushort_t* hw = hs[wid];

    // A fragments for this wave's 16 rows (K=128 -> 4 ksteps)
    const bf16x8* Af = (const bf16x8*)(xa + (size_t)mt * 2048);
    bf16x8 af[4];
#pragma unroll
    for (int s = 0; s < 4; ++s) af[s] = Af[s * 64 + l];

    const bf16x8* B1 = (const bf16x8*)wb1;
    const bf16x8* B2 = (const bf16x8*)wb2;
    const bf16x8* BP = (const bf16x8*)wpb;

    const f32x4 zero = {0.f, 0.f, 0.f, 0.f};
    f32x4 acc3[8];
#pragma unroll
    for (int i = 0; i < 8; ++i) acc3[i] = zero;

#pragma unroll
    for (int half = 0; half < 2; ++half) {
        f32x4 acc1[8], acc2[8];
#pragma unroll
        for (int i = 0; i < 8; ++i) { acc1[i] = zero; acc2[i] = zero; }

#pragma unroll 2
        for (int nt = 0; nt < 8; ++nt) {
            int ntg = half * 8 + nt;
#pragma unroll
            for (int s = 0; s < 4; ++s) {
                bf16x8 b1 = B1[(ntg * 4 + s) * 64 + l];
                acc1[nt] = __builtin_amdgcn_mfma_f32_16x16x32_bf16(af[s], b1, acc1[nt], 0, 0, 0);
                bf16x8 b2 = B2[(ntg * 4 + s) * 64 + l];
                acc2[nt] = __builtin_amdgcn_mfma_f32_16x16x32_bf16(af[s], b2, acc2[nt], 0, 0, 0);
            }
        }

        // H = silu(g1) * g2 -> LDS (bf16, XOR-swizzled rows)
#pragma unroll
        for (int nt = 0; nt < 8; ++nt) {
#pragma unroll
            for (int i = 0; i < 4; ++i) {
                float g = acc1[nt][i];
                float hv = (g / (1.f + __expf(-g))) * acc2[nt][i];
                int r = 4 * lhi + i;
                int byte = (r << 8) + ((nt * 16 + llo) << 1);
                byte ^= (r & 7) << 4;
                hw[byte >> 1] = f2bf(hv);
            }
        }

        // GEMM3 partial: K-slice = this half's 128 cols of H
        bf16x8 hf[4];
#pragma unroll
        for (int s2 = 0; s2 < 4; ++s2) {
            int byte = (llo << 8) + (s2 << 6) + (lhi << 4);
            byte ^= (llo & 7) << 4;
            hf[s2] = *(const bf16x8*)((const char*)hw + byte);
        }
#pragma unroll
        for (int nt3 = 0; nt3 < 8; ++nt3) {
#pragma unroll
            for (int s2 = 0; s2 < 4; ++s2) {
                int sg = half * 4 + s2;
                bf16x8 bw = BP[(nt3 * 8 + sg) * 64 + l];
                acc3[nt3] = __builtin_amdgcn_mfma_f32_16x16x32_bf16(hf[s2], bw, acc3[nt3], 0, 0, 0);
            }
        }
    }

    // epilogue: + bias, store f32 (lanes 0..15 cover 16 consecutive cols -> 64B segments)
    const int row0 = mt * 16;
#pragma unroll
    for (int nt3 = 0; nt3 < 8; ++nt3) {
        float bpv = bp[nt3 * 16 + llo];
#pragma unroll
        for (int i = 0; i < 4; ++i) {
            int r = row0 + 4 * lhi + i;
            xp[(size_t)r * 128 + nt3 * 16 + llo] = acc3[nt3][i] + bpv;
        }
    }
}

// ---------------- CSR build (by dst). in-deg == out-deg for this edge list ----------------
__global__ void k_hist(const int* __restrict__ ei, int E, int* __restrict__ cnt) {
    int e = blockIdx.x * blockDim.x + threadIdx.x;
    if (e < E) atomicAdd(&cnt[ei[E + e]], 1);      // histogram over dst
}

__global__ void __launch_bounds__(1024)
k_scan(const int* __restrict__ cnt, int N, int* __restrict__ off,
       int* __restrict__ cursor, float* __restrict__ bv) {
    __shared__ int sums[1024];
    int t = threadIdx.x;
    int chunk = (N + 1023) >> 10;
    int lo = t * chunk;
    int hi = min(lo + chunk, N);
    int s = 0;
    for (int i = lo; i < hi; ++i) s += cnt[i];
    sums[t] = s;
    __syncthreads();
    for (int d = 1; d < 1024; d <<= 1) {
        int v = (t >= d) ? sums[t - d] : 0;
        __syncthreads();
        sums[t] += v;
        __syncthreads();
    }
    int run = (t == 0) ? 0 : sums[t - 1];
    for (int i = lo; i < hi; ++i) {
        off[i] = run;
        cursor[i] = run;
        int c = cnt[i];
        bv[i] = (c > 1) ? (-1.f / ((float)c - 1.f + EPSF)) : 0.f;
        run += c;
    }
    if (t == 1023) off[N] = sums[1023];
}

__global__ void k_fill(const int* __restrict__ ei, int E,
                       int* __restrict__ cursor, int* __restrict__ csr) {
    int e = blockIdx.x * blockDim.x + threadIdx.x;
    if (e < E) {
        int s = ei[e], d = ei[E + e];
        int p = atomicAdd(&cursor[d], 1);
        csr[p] = s;
    }
}

// ---------------- fused gather + node passes (one wave per node) ----------------
__global__ void __launch_bounds__(256)
k_passA(const float* __restrict__ xp, const float* __restrict__ bv,
        const int* __restrict__ off, const int* __restrict__ csr,
        const float* __restrict__ tab, float* __restrict__ Xb,
        float* __restrict__ a1, int N) {
    int tid = blockIdx.x * blockDim.x + threadIdx.x;
    int v = tid >> 6, l = tid & 63;
    if (v >= N) return;
    int beg = off[v], end = off[v + 1];
    float2 m0 = make_float2(0.f, 0.f), xb = make_float2(0.f, 0.f);
    for (int k = beg; k < end; ++k) {
        int s = csr[k];
        float2 tv = *(const float2*)&xp[(size_t)s * 128 + 2 * l];
        float b = bv[s];
        m0.x += tv.x; m0.y += tv.y;
        xb.x += b * tv.x; xb.y += b * tv.y;
    }
    size_t o = (size_t)v * 128 + 2 * l;
    *(float2*)&Xb[o] = xb;
    float2 xv = *(const float2*)&xp[o];
    int dg = end - beg;
    float L1r = tab[l], L1i = tab[64 + l], O1r = tab[128 + l], O1i = tab[192 + l];
    float Q = 1.f / ((float)dg - 1.f + EPSF);
    float2 t1 = cmul(O1r, O1i, xv);
    float2 t2 = cmul(L1r, L1i, m0);
    float2 a = make_float2(t1.x + Q * t2.x, t1.y + Q * t2.y);
    if (dg == 1) a = xv;
    *(float2*)&a1[o] = a;
}

__global__ void __launch_bounds__(256)
k_passB(const float* __restrict__ xp, const float* __restrict__ a1,
        const float* __restrict__ bv, const int* __restrict__ off,
        const int* __restrict__ csr, const float* __restrict__ tab,
        float* __restrict__ Ab1, float* __restrict__ Bv, float* __restrict__ B2v,
        float* __restrict__ a2, int N) {
    int tid = blockIdx.x * blockDim.x + threadIdx.x;
    int v = tid >> 6, l = tid & 63;
    if (v >= N) return;
    int beg = off[v], end = off[v + 1];
    float2 A1 = make_float2(0.f, 0.f), ab = make_float2(0.f, 0.f);
    float Bs = 0.f, B2s = 0.f;
    for (int k = beg; k < end; ++k) {
        int s = csr[k];
        float2 tv = *(const float2*)&a1[(size_t)s * 128 + 2 * l];
        float b = bv[s];
        A1.x += tv.x; A1.y += tv.y;
        ab.x += b * tv.x; ab.y += b * tv.y;
        Bs += b; B2s += b * b;
    }
    size_t o = (size_t)v * 128 + 2 * l;
    *(float2*)&Ab1[o] = ab;
    if (l == 0) { Bv[v] = Bs; B2v[v] = B2s; }
    float2 xv = *(const float2*)&xp[o];
    int dg = end - beg;
    float L1r = tab[l], L1i = tab[64 + l], O1r = tab[128 + l], O1i = tab[192 + l];
    float2 lx = cmul(L1r, L1i, xv);
    float2 m1 = make_float2(A1.x + Bs * lx.x, A1.y + Bs * lx.y);
    float Q = 1.f / ((float)dg - 1.f + EPSF);
    float2 t1 = cmul(O1r, O1i, xv);
    float2 lm = cmul(L1r, L1i, m1);
    float2 a = make_float2(t1.x + Q * lm.x, t1.y + Q * lm.y);
    if (dg == 1) a = xv;
    *(float2*)&a2[o] = a;
}

__global__ void __launch_bounds__(256)
k_passC(const float* __restrict__ xp, const float* __restrict__ a2,
        const float* __restrict__ a1, const float* __restrict__ Xb,
        const float* __restrict__ bv, const float* __restrict__ Bv,
        const int* __restrict__ off, const int* __restrict__ csr,
        const float* __restrict__ tab, float* __restrict__ a3, int N) {
    int tid = blockIdx.x * blockDim.x + threadIdx.x;
    int v = tid >> 6, l = tid & 63;
    if (v >= N) return;
    int beg = off[v], end = off[v + 1];
    float2 A2 = make_float2(0.f, 0.f);
    for (int k = beg; k < end; ++k) {
        int s = csr[k];
        float2 tv = *(const float2*)&a2[(size_t)s * 128 + 2 * l];
        A2.x += tv.x; A2.y += tv.y;
    }
    size_t o = (size_t)v * 128 + 2 * l;
    float2 xv  = *(const float2*)&xp[o];
    float2 a1v = *(const float2*)&a1[o];
    float2 Xbv = *(const float2*)&Xb[o];
    int dg = end - beg;
    float Bs = Bv[v], bs = bv[v];
    float L1r = tab[l], L1i = tab[64 + l], O1r = tab[128 + l], O1i = tab[192 + l];
    float L2r = tab[256 + l], L2i = tab[320 + l];
    float2 la1 = cmul(L1r, L1i, a1v);
    float2 lxb = cmul(L2r, L2i, Xbv);
    float2 m2 = make_float2(A2.x + Bs * la1.x + bs * lxb.x,
                            A2.y + Bs * la1.y + bs * lxb.y);
    float Q = 1.f / ((float)dg - 1.f + EPSF);
    float2 t1 = cmul(O1r, O1i, xv);
    float2 lm = cmul(L1r, L1i, m2);
    float2 a = make_float2(t1.x + Q * lm.x, t1.y + Q * lm.y);
    if (dg == 1) a = xv;
    *(float2*)&a3[o] = a;
}

__global__ void __launch_bounds__(256)
k_passD(const float* __restrict__ xin, const float* __restrict__ xp,
        const float* __restrict__ a3, const float* a2,
        const float* __restrict__ Ab1, const float* __restrict__ bv,
        const float* __restrict__ Bv, const float* __restrict__ B2v,
        const int* __restrict__ off, const int* __restrict__ csr,
        const float* __restrict__ tab, float* out, int N) {
    int tid = blockIdx.x * blockDim.x + threadIdx.x;
    int v = tid >> 6, l = tid & 63;
    if (v >= N) return;
    int beg = off[v], end = off[v + 1];
    float2 A3 = make_float2(0.f, 0.f);
    for (int k = beg; k < end; ++k) {
        int s = csr[k];
        float2 tv = *(const float2*)&a3[(size_t)s * 128 + 2 * l];
        A3.x += tv.x; A3.y += tv.y;
    }
    size_t o = (size_t)v * 128 + 2 * l;
    float2 xv  = *(const float2*)&xp[o];
    float2 a2v = *(const float2*)&a2[o];
    float2 Abv = *(const float2*)&Ab1[o];
    int dg = end - beg;
    float Bs = Bv[v], bs = bv[v], B2s = B2v[v];
    float L1r = tab[l], L1i = tab[64 + l], O1r = tab[128 + l], O1i = tab[192 + l];
    float L2r = tab[256 + l], L2i = tab[320 + l];
    float L3r = tab[384 + l], L3i = tab[448 + l];
    float2 la2 = cmul(L1r, L1i, a2v);
    float2 lab = cmul(L2r, L2i, Abv);
    float2 lx3 = cmul(L3r, L3i, xv);
    float bB2 = bs * B2s;
    float2 m3 = make_float2(A3.x + Bs * la2.x + bs * lab.x + bB2 * lx3.x,
                            A3.y + Bs * la2.y + bs * lab.y + bB2 * lx3.y);
    float2 g;
    if (dg == 0) {
        g = xv;
    } else {
        float inv = 1.f / ((float)dg + EPSF);
        float2 t1 = cmul(O1r, O1i, xv);
        float2 lm = cmul(L1r, L1i, m3);
        g = make_float2(t1.x + lm.x * inv, t1.y + lm.y * inv);
    }
    float2 xi = *(const float2*)&xin[o];
    float2 res = make_float2(xi.x + fmaxf(g.x, 0.f), xi.y + fmaxf(g.y, 0.f));
    *(float2*)&out[o] = res;
}

extern "C" void kernel_launch(void* const* d_in, const int* in_sizes, int n_in,
                              void* d_out, int out_size, void* d_ws, size_t ws_size,
                              hipStream_t stream) {
    const float* x   = (const float*)d_in[0];
    const int*   ei  = (const int*)d_in[1];
    const float* ldt = (const float*)d_in[2];
    const float* llr = (const float*)d_in[3];
    const float* lim = (const float*)d_in[4];
    const float* W1  = (const float*)d_in[5];
    const float* W2  = (const float*)d_in[6];
    const float* Wp  = (const float*)d_in[7];
    const float* bp  = (const float*)d_in[8];
    float* out = (float*)d_out;

    const int N = in_sizes[0] / 128;
    const int E = in_sizes[1] / 2;
    const size_t nd = (size_t)N * 128;
    const int Mt = (N + 15) / 16;          // 16-row m-tiles (N=50000 -> 3125 exact)

    float* ws  = (float*)d_ws;
    float* xp  = ws;            // post-MLP x
    float* Xb  = ws + nd;
    float* a1  = ws + 2 * nd;
    float* ab1 = ws + 3 * nd;
    float* a3  = ws + 4 * nd;
    float* a2  = out;           // a2 lives in d_out until k_passD overwrites it

    int*   cnt    = (int*)(ws + 5 * nd);   // N
    int*   off    = cnt + N;               // N+4 (padded, keeps 16B alignment)
    int*   cursor = off + N + 4;           // N
    float* bv     = (float*)(cursor + N);  // N
    float* Bv     = bv + N;                // N
    float* B2v    = Bv + N;                // N
    float* tab    = B2v + N;               // 512
    int*   csr    = (int*)(tab + 512);     // E
    ushort_t* xa  = (ushort_t*)(csr + E);  // Mt*2048 (bf16 A-frags)
    ushort_t* wb1 = xa + (size_t)Mt * 2048;   // 32768
    ushort_t* wb2 = wb1 + 32768;              // 32768
    ushort_t* wpb = wb2 + 32768;              // 32768

    const int nodeBlocks = (int)(((size_t)N * 64 + 255) / 256);
    const int eBlocks    = (E + 255) / 256;

    hipMemsetAsync(cnt, 0, (size_t)N * sizeof(int), stream);
    k_lamtab<<<1, 64, 0, stream>>>(ldt, llr, lim, tab);

    // bf16 fragment prep + MFMA MLP
    k_prepx<<<(Mt * 256 + 255) / 256, 256, 0, stream>>>(x, xa, Mt);
    k_prepw<<<16, 256, 0, stream>>>(W1, wb1, 256, 4, 16 * 4 * 64);
    k_prepw<<<16, 256, 0, stream>>>(W2, wb2, 256, 4, 16 * 4 * 64);
    k_prepw<<<16, 256, 0, stream>>>(Wp, wpb, 128, 8, 8 * 8 * 64);
    k_mlpf<<<(Mt + 3) / 4, 256, 0, stream>>>(xa, wb1, wb2, wpb, bp, xp, Mt);

    // CSR build
    k_hist<<<eBlocks, 256, 0, stream>>>(ei, E, cnt);
    k_scan<<<1, 1024, 0, stream>>>(cnt, N, off, cursor, bv);
    k_fill<<<eBlocks, 256, 0, stream>>>(ei, E, cursor, csr);

    // fused gather + node passes
    k_passA<<<nodeBlocks, 256, 0, stream>>>(xp, bv, off, csr, tab, Xb, a1, N);
    k_passB<<<nodeBlocks, 256, 0, stream>>>(xp, a1, bv, off, csr, tab, ab1, Bv, B2v, a2, N);
    k_passC<<<nodeBlocks, 256, 0, stream>>>(xp, a2, a1, Xb, bv, Bv, off, csr, tab, a3, N);
    k_passD<<<nodeBlocks, 256, 0, stream>>>(x, xp, a3, a2, ab1, bv, Bv, B2v, off, csr, tab, out, N);
}

// Round 4
// 364.609 us; speedup vs baseline: 6.3554x; 1.3566x over previous
//
#include <hip/hip_runtime.h>

#define EPSF 1e-9f

typedef __bf16 bf16x8 __attribute__((ext_vector_type(8)));
typedef float  f32x4  __attribute__((ext_vector_type(4)));
typedef unsigned short ushort_t;
typedef ushort_t us8 __attribute__((ext_vector_type(8)));

__device__ __forceinline__ float2 cmul(float cr, float ci, float2 v) {
    return make_float2(cr * v.x - ci * v.y, ci * v.x + cr * v.y);
}

__device__ __forceinline__ ushort_t f2bf(float f) {
    unsigned int u = __float_as_uint(f);
    u += 0x7FFFu + ((u >> 16) & 1u);   // RNE
    return (ushort_t)(u >> 16);
}

// ---------------- lambda tables: L1, O1(one-minus), L2, L3 ----------------
__global__ void k_lamtab(const float* __restrict__ ldt, const float* __restrict__ llr,
                         const float* __restrict__ lim, float* __restrict__ tab) {
    int p = threadIdx.x;
    if (p >= 64) return;
    float dt  = expf(ldt[0]);
    float mag = expf(-expf(llr[p]) * dt);
    float ph  = lim[p] * dt;
    float c = cosf(ph), s = sinf(ph);
    float m2 = mag * mag, m3 = m2 * mag;
    float c2 = c * c - s * s, s2 = 2.f * c * s;
    float c3 = c2 * c - s2 * s, s3 = s2 * c + c2 * s;
    tab[p]        = c * mag;          tab[64 + p]  = s * mag;          // L1
    tab[128 + p]  = c * (1.f - mag);  tab[192 + p] = s * (1.f - mag);  // O1
    tab[256 + p]  = c2 * m2;          tab[320 + p] = s2 * m2;          // L2
    tab[384 + p]  = c3 * m3;          tab[448 + p] = s3 * m3;          // L3
}

// ---------------- prep: W[K][ncols] -> bf16 B-fragment layout ----------------
// tid = (nt*nsteps + s)*64 + l ; element j: W[s*32 + (l>>4)*8 + j][nt*16 + (l&15)]
__global__ void k_prepw(const float* __restrict__ w, ushort_t* __restrict__ wb,
                        int ncols, int nsteps, int total) {
    int tid = blockIdx.x * blockDim.x + threadIdx.x;
    if (tid >= total) return;
    int l  = tid & 63;
    int s  = (tid >> 6) % nsteps;
    int nt = tid / (64 * nsteps);
    int col = nt * 16 + (l & 15);
    int kb  = s * 32 + (l >> 4) * 8;
    us8 d;
#pragma unroll
    for (int j = 0; j < 8; ++j) d[j] = f2bf(w[(size_t)(kb + j) * ncols + col]);
    *(us8*)(wb + (size_t)tid * 8) = d;
}

// ---------------- MFMA fused MLP: xp = (silu(xW1) * (xW2)) @ Wp + bp ----------------
// 4 waves/block, wave = one 16-row m-tile; x loaded+converted in-register.
__global__ void __launch_bounds__(256)
k_mlpf(const float* __restrict__ x, const ushort_t* __restrict__ wb1,
       const ushort_t* __restrict__ wb2, const ushort_t* __restrict__ wpb,
       const float* __restrict__ bp, float* __restrict__ xp, int Mt) {
    __shared__ ushort_t hs[4][2048];   // per-wave 16x128 bf16 H tile (swizzled)
    const int wid = threadIdx.x >> 6, l = threadIdx.x & 63;
    const int mt = blockIdx.x * 4 + wid;
    if (mt >= Mt) return;
    const int llo = l & 15, lhi = l >> 4;
    ushort_t* hw = hs[wid];

    // A fragments: row = mt*16 + (l&15), cols s*32 + (l>>4)*8 .. +8
    bf16x8 af[4];
    {
        const float* xr = x + (size_t)(mt * 16 + llo) * 128 + lhi * 8;
#pragma unroll
        for (int s = 0; s < 4; ++s) {
            float4 v0 = *(const float4*)(xr + s * 32);
            float4 v1 = *(const float4*)(xr + s * 32 + 4);
            us8 d;
            d[0] = f2bf(v0.x); d[1] = f2bf(v0.y); d[2] = f2bf(v0.z); d[3] = f2bf(v0.w);
            d[4] = f2bf(v1.x); d[5] = f2bf(v1.y); d[6] = f2bf(v1.z); d[7] = f2bf(v1.w);
            af[s] = *(bf16x8*)&d;
        }
    }

    const bf16x8* B1 = (const bf16x8*)wb1;
    const bf16x8* B2 = (const bf16x8*)wb2;
    const bf16x8* BP = (const bf16x8*)wpb;

    const f32x4 zero = {0.f, 0.f, 0.f, 0.f};
    f32x4 acc3[8];
#pragma unroll
    for (int i = 0; i < 8; ++i) acc3[i] = zero;

#pragma unroll
    for (int half = 0; half < 2; ++half) {
        f32x4 acc1[8], acc2[8];
#pragma unroll
        for (int i = 0; i < 8; ++i) { acc1[i] = zero; acc2[i] = zero; }

#pragma unroll 2
        for (int nt = 0; nt < 8; ++nt) {
            int ntg = half * 8 + nt;
#pragma unroll
            for (int s = 0; s < 4; ++s) {
                bf16x8 b1 = B1[(ntg * 4 + s) * 64 + l];
                acc1[nt] = __builtin_amdgcn_mfma_f32_16x16x32_bf16(af[s], b1, acc1[nt], 0, 0, 0);
                bf16x8 b2 = B2[(ntg * 4 + s) * 64 + l];
                acc2[nt] = __builtin_amdgcn_mfma_f32_16x16x32_bf16(af[s], b2, acc2[nt], 0, 0, 0);
            }
        }

        // H = silu(g1) * g2 -> LDS (bf16, XOR-swizzled rows)
#pragma unroll
        for (int nt = 0; nt < 8; ++nt) {
#pragma unroll
            for (int i = 0; i < 4; ++i) {
                float g = acc1[nt][i];
                float hv = (g / (1.f + __expf(-g))) * acc2[nt][i];
                int r = 4 * lhi + i;
                int byte = (r << 8) + ((nt * 16 + llo) << 1);
                byte ^= (r & 7) << 4;
                hw[byte >> 1] = f2bf(hv);
            }
        }

        // GEMM3 partial: K-slice = this half's 128 cols of H
        bf16x8 hf[4];
#pragma unroll
        for (int s2 = 0; s2 < 4; ++s2) {
            int byte = (llo << 8) + (s2 << 6) + (lhi << 4);
            byte ^= (llo & 7) << 4;
            hf[s2] = *(const bf16x8*)((const char*)hw + byte);
        }
#pragma unroll
        for (int nt3 = 0; nt3 < 8; ++nt3) {
#pragma unroll
            for (int s2 = 0; s2 < 4; ++s2) {
                int sg = half * 4 + s2;
                bf16x8 bw = BP[(nt3 * 8 + sg) * 64 + l];
                acc3[nt3] = __builtin_amdgcn_mfma_f32_16x16x32_bf16(hf[s2], bw, acc3[nt3], 0, 0, 0);
            }
        }
    }

    // epilogue: + bias, store f32
    const int row0 = mt * 16;
#pragma unroll
    for (int nt3 = 0; nt3 < 8; ++nt3) {
        float bpv = bp[nt3 * 16 + llo];
#pragma unroll
        for (int i = 0; i < 4; ++i) {
            int r = row0 + 4 * lhi + i;
            xp[(size_t)r * 128 + nt3 * 16 + llo] = acc3[nt3][i] + bpv;
        }
    }
}

// ---------------- CSR build (by dst). in-deg == out-deg for this edge list ----------------
__global__ void k_hist(const int* __restrict__ ei, int E, int* __restrict__ cnt) {
    int e = blockIdx.x * blockDim.x + threadIdx.x;
    if (e < E) atomicAdd(&cnt[ei[E + e]], 1);      // histogram over dst
}

// hierarchical scan: A) per-block sums
__global__ void __launch_bounds__(256)
k_scanA(const int* __restrict__ cnt, int N, int* __restrict__ bsum) {
    __shared__ int s[256];
    int t = threadIdx.x;
    int i = blockIdx.x * 256 + t;
    int v = (i < N) ? cnt[i] : 0;
    s[t] = v;
    __syncthreads();
#pragma unroll
    for (int d = 128; d > 0; d >>= 1) {
        if (t < d) s[t] += s[t + d];
        __syncthreads();
    }
    if (t == 0) bsum[blockIdx.x] = s[0];
}

// B) scan block sums (NB <= 1024), write exclusive prefixes + total to off[N]
__global__ void __launch_bounds__(1024)
k_scanB(const int* __restrict__ bsum, int NB, int* __restrict__ bpre,
        int* __restrict__ offN) {
    __shared__ int s[1024];
    int t = threadIdx.x;
    int v = (t < NB) ? bsum[t] : 0;
    s[t] = v;
    __syncthreads();
    for (int d = 1; d < 1024; d <<= 1) {
        int u = (t >= d) ? s[t - d] : 0;
        __syncthreads();
        s[t] += u;
        __syncthreads();
    }
    if (t < NB) bpre[t] = s[t] - v;          // exclusive
    if (t == NB - 1) *offN = s[t];           // total
}

// C) intra-block scan + block prefix -> off/cursor/bv
__global__ void __launch_bounds__(256)
k_scanC(const int* __restrict__ cnt, int N, const int* __restrict__ bpre,
        int* __restrict__ off, int* __restrict__ cursor, float* __restrict__ bv) {
    __shared__ int s[256];
    int t = threadIdx.x;
    int i = blockIdx.x * 256 + t;
    int v = (i < N) ? cnt[i] : 0;
    s[t] = v;
    __syncthreads();
    for (int d = 1; d < 256; d <<= 1) {
        int u = (t >= d) ? s[t - d] : 0;
        __syncthreads();
        s[t] += u;
        __syncthreads();
    }
    if (i < N) {
        int excl = bpre[blockIdx.x] + s[t] - v;
        off[i] = excl;
        cursor[i] = excl;
        bv[i] = (v > 1) ? (-1.f / ((float)v - 1.f + EPSF)) : 0.f;
    }
}

__global__ void k_fill(const int* __restrict__ ei, int E,
                       int* __restrict__ cursor, int* __restrict__ csr) {
    int e = blockIdx.x * blockDim.x + threadIdx.x;
    if (e < E) {
        int s = ei[e], d = ei[E + e];
        int p = atomicAdd(&cursor[d], 1);
        csr[p] = s;
    }
}

// ---------------- fused gather + node passes (one wave per node) ----------------
__global__ void __launch_bounds__(256)
k_passA(const float* __restrict__ xp, const float* __restrict__ bv,
        const int* __restrict__ off, const int* __restrict__ csr,
        const float* __restrict__ tab, float* __restrict__ Xb,
        float* __restrict__ a1, int N) {
    int tid = blockIdx.x * blockDim.x + threadIdx.x;
    int v = tid >> 6, l = tid & 63;
    if (v >= N) return;
    int beg = off[v], end = off[v + 1];
    float2 m0 = make_float2(0.f, 0.f), xb = make_float2(0.f, 0.f);
    for (int k = beg; k < end; ++k) {
        int s = csr[k];
        float2 tv = *(const float2*)&xp[(size_t)s * 128 + 2 * l];
        float b = bv[s];
        m0.x += tv.x; m0.y += tv.y;
        xb.x += b * tv.x; xb.y += b * tv.y;
    }
    size_t o = (size_t)v * 128 + 2 * l;
    *(float2*)&Xb[o] = xb;
    float2 xv = *(const float2*)&xp[o];
    int dg = end - beg;
    float L1r = tab[l], L1i = tab[64 + l], O1r = tab[128 + l], O1i = tab[192 + l];
    float Q = 1.f / ((float)dg - 1.f + EPSF);
    float2 t1 = cmul(O1r, O1i, xv);
    float2 t2 = cmul(L1r, L1i, m0);
    float2 a = make_float2(t1.x + Q * t2.x, t1.y + Q * t2.y);
    if (dg == 1) a = xv;
    *(float2*)&a1[o] = a;
}

__global__ void __launch_bounds__(256)
k_passB(const float* __restrict__ xp, const float* __restrict__ a1,
        const float* __restrict__ bv, const int* __restrict__ off,
        const int* __restrict__ csr, const float* __restrict__ tab,
        float* __restrict__ Ab1, float* __restrict__ Bv, float* __restrict__ B2v,
        float* __restrict__ a2, int N) {
    int tid = blockIdx.x * blockDim.x + threadIdx.x;
    int v = tid >> 6, l = tid & 63;
    if (v >= N) return;
    int beg = off[v], end = off[v + 1];
    float2 A1 = make_float2(0.f, 0.f), ab = make_float2(0.f, 0.f);
    float Bs = 0.f, B2s = 0.f;
    for (int k = beg; k < end; ++k) {
        int s = csr[k];
        float2 tv = *(const float2*)&a1[(size_t)s * 128 + 2 * l];
        float b = bv[s];
        A1.x += tv.x; A1.y += tv.y;
        ab.x += b * tv.x; ab.y += b * tv.y;
        Bs += b; B2s += b * b;
    }
    size_t o = (size_t)v * 128 + 2 * l;
    *(float2*)&Ab1[o] = ab;
    if (l == 0) { Bv[v] = Bs; B2v[v] = B2s; }
    float2 xv = *(const float2*)&xp[o];
    int dg = end - beg;
    float L1r = tab[l], L1i = tab[64 + l], O1r = tab[128 + l], O1i = tab[192 + l];
    float2 lx = cmul(L1r, L1i, xv);
    float2 m1 = make_float2(A1.x + Bs * lx.x, A1.y + Bs * lx.y);
    float Q = 1.f / ((float)dg - 1.f + EPSF);
    float2 t1 = cmul(O1r, O1i, xv);
    float2 lm = cmul(L1r, L1i, m1);
    float2 a = make_float2(t1.x + Q * lm.x, t1.y + Q * lm.y);
    if (dg == 1) a = xv;
    *(float2*)&a2[o] = a;
}

__global__ void __launch_bounds__(256)
k_passC(const float* __restrict__ xp, const float* __restrict__ a2,
        const float* __restrict__ a1, const float* __restrict__ Xb,
        const float* __restrict__ bv, const float* __restrict__ Bv,
        const int* __restrict__ off, const int* __restrict__ csr,
        const float* __restrict__ tab, float* __restrict__ a3, int N) {
    int tid = blockIdx.x * blockDim.x + threadIdx.x;
    int v = tid >> 6, l = tid & 63;
    if (v >= N) return;
    int beg = off[v], end = off[v + 1];
    float2 A2 = make_float2(0.f, 0.f);
    for (int k = beg; k < end; ++k) {
        int s = csr[k];
        float2 tv = *(const float2*)&a2[(size_t)s * 128 + 2 * l];
        A2.x += tv.x; A2.y += tv.y;
    }
    size_t o = (size_t)v * 128 + 2 * l;
    float2 xv  = *(const float2*)&xp[o];
    float2 a1v = *(const float2*)&a1[o];
    float2 Xbv = *(const float2*)&Xb[o];
    int dg = end - beg;
    float Bs = Bv[v], bs = bv[v];
    float L1r = tab[l], L1i = tab[64 + l], O1r = tab[128 + l], O1i = tab[192 + l];
    float L2r = tab[256 + l], L2i = tab[320 + l];
    float2 la1 = cmul(L1r, L1i, a1v);
    float2 lxb = cmul(L2r, L2i, Xbv);
    float2 m2 = make_float2(A2.x + Bs * la1.x + bs * lxb.x,
                            A2.y + Bs * la1.y + bs * lxb.y);
    float Q = 1.f / ((float)dg - 1.f + EPSF);
    float2 t1 = cmul(O1r, O1i, xv);
    float2 lm = cmul(L1r, L1i, m2);
    float2 a = make_float2(t1.x + Q * lm.x, t1.y + Q * lm.y);
    if (dg == 1) a = xv;
    *(float2*)&a3[o] = a;
}

__global__ void __launch_bounds__(256)
k_passD(const float* __restrict__ xin, const float* __restrict__ xp,
        const float* __restrict__ a3, const float* a2,
        const float* __restrict__ Ab1, const float* __restrict__ bv,
        const float* __restrict__ Bv, const float* __restrict__ B2v,
        const int* __restrict__ off, const int* __restrict__ csr,
        const float* __restrict__ tab, float* out, int N) {
    int tid = blockIdx.x * blockDim.x + threadIdx.x;
    int v = tid >> 6, l = tid & 63;
    if (v >= N) return;
    int beg = off[v], end = off[v + 1];
    float2 A3 = make_float2(0.f, 0.f);
    for (int k = beg; k < end; ++k) {
        int s = csr[k];
        float2 tv = *(const float2*)&a3[(size_t)s * 128 + 2 * l];
        A3.x += tv.x; A3.y += tv.y;
    }
    size_t o = (size_t)v * 128 + 2 * l;
    float2 xv  = *(const float2*)&xp[o];
    float2 a2v = *(const float2*)&a2[o];
    float2 Abv = *(const float2*)&Ab1[o];
    int dg = end - beg;
    float Bs = Bv[v], bs = bv[v], B2s = B2v[v];
    float L1r = tab[l], L1i = tab[64 + l], O1r = tab[128 + l], O1i = tab[192 + l];
    float L2r = tab[256 + l], L2i = tab[320 + l];
    float L3r = tab[384 + l], L3i = tab[448 + l];
    float2 la2 = cmul(L1r, L1i, a2v);
    float2 lab = cmul(L2r, L2i, Abv);
    float2 lx3 = cmul(L3r, L3i, xv);
    float bB2 = bs * B2s;
    float2 m3 = make_float2(A3.x + Bs * la2.x + bs * lab.x + bB2 * lx3.x,
                            A3.y + Bs * la2.y + bs * lab.y + bB2 * lx3.y);
    float2 g;
    if (dg == 0) {
        g = xv;
    } else {
        float inv = 1.f / ((float)dg + EPSF);
        float2 t1 = cmul(O1r, O1i, xv);
        float2 lm = cmul(L1r, L1i, m3);
        g = make_float2(t1.x + lm.x * inv, t1.y + lm.y * inv);
    }
    float2 xi = *(const float2*)&xin[o];
    float2 res = make_float2(xi.x + fmaxf(g.x, 0.f), xi.y + fmaxf(g.y, 0.f));
    *(float2*)&out[o] = res;
}

extern "C" void kernel_launch(void* const* d_in, const int* in_sizes, int n_in,
                              void* d_out, int out_size, void* d_ws, size_t ws_size,
                              hipStream_t stream) {
    const float* x   = (const float*)d_in[0];
    const int*   ei  = (const int*)d_in[1];
    const float* ldt = (const float*)d_in[2];
    const float* llr = (const float*)d_in[3];
    const float* lim = (const float*)d_in[4];
    const float* W1  = (const float*)d_in[5];
    const float* W2  = (const float*)d_in[6];
    const float* Wp  = (const float*)d_in[7];
    const float* bp  = (const float*)d_in[8];
    float* out = (float*)d_out;

    const int N = in_sizes[0] / 128;
    const int E = in_sizes[1] / 2;
    const size_t nd = (size_t)N * 128;
    const int Mt = (N + 15) / 16;          // 16-row m-tiles (N=50000 -> 3125 exact)
    const int NB = (N + 255) / 256;        // scan blocks

    float* ws  = (float*)d_ws;
    float* xp  = ws;            // post-MLP x
    float* Xb  = ws + nd;
    float* a1  = ws + 2 * nd;
    float* ab1 = ws + 3 * nd;
    float* a3  = ws + 4 * nd;
    float* a2  = out;           // a2 lives in d_out until k_passD overwrites it

    int*   cnt    = (int*)(ws + 5 * nd);   // N
    int*   off    = cnt + N;               // N+4 (padded)
    int*   cursor = off + N + 4;           // N
    float* bv     = (float*)(cursor + N);  // N
    float* Bv     = bv + N;                // N
    float* B2v    = Bv + N;                // N
    float* tab    = B2v + N;               // 512
    int*   bsum   = (int*)(tab + 512);     // NB
    int*   bpre   = bsum + NB;             // NB
    int*   csr    = bpre + NB;             // E
    ushort_t* wb1 = (ushort_t*)(csr + E);  // 32768
    ushort_t* wb2 = wb1 + 32768;           // 32768
    ushort_t* wpb = wb2 + 32768;           // 32768

    const int nodeBlocks = (int)(((size_t)N * 64 + 255) / 256);
    const int eBlocks    = (E + 255) / 256;

    hipMemsetAsync(cnt, 0, (size_t)N * sizeof(int), stream);
    k_lamtab<<<1, 64, 0, stream>>>(ldt, llr, lim, tab);

    // bf16 weight prep + MFMA MLP (x converted in-kernel)
    k_prepw<<<16, 256, 0, stream>>>(W1, wb1, 256, 4, 16 * 4 * 64);
    k_prepw<<<16, 256, 0, stream>>>(W2, wb2, 256, 4, 16 * 4 * 64);
    k_prepw<<<16, 256, 0, stream>>>(Wp, wpb, 128, 8, 8 * 8 * 64);
    k_mlpf<<<(Mt + 3) / 4, 256, 0, stream>>>(x, wb1, wb2, wpb, bp, xp, Mt);

    // CSR build (hierarchical scan)
    k_hist<<<eBlocks, 256, 0, stream>>>(ei, E, cnt);
    k_scanA<<<NB, 256, 0, stream>>>(cnt, N, bsum);
    k_scanB<<<1, 1024, 0, stream>>>(bsum, NB, bpre, &off[N]);
    k_scanC<<<NB, 256, 0, stream>>>(cnt, N, bpre, off, cursor, bv);
    k_fill<<<eBlocks, 256, 0, stream>>>(ei, E, cursor, csr);

    // fused gather + node passes
    k_passA<<<nodeBlocks, 256, 0, stream>>>(xp, bv, off, csr, tab, Xb, a1, N);
    k_passB<<<nodeBlocks, 256, 0, stream>>>(xp, a1, bv, off, csr, tab, ab1, Bv, B2v, a2, N);
    k_passC<<<nodeBlocks, 256, 0, stream>>>(xp, a2, a1, Xb, bv, Bv, off, csr, tab, a3, N);
    k_passD<<<nodeBlocks, 256, 0, stream>>>(x, xp, a3, a2, ab1, bv, Bv, B2v, off, csr, tab, out, N);
}

// Round 5
// 332.492 us; speedup vs baseline: 6.9693x; 1.0966x over previous
//
#include <hip/hip_runtime.h>

#define EPSF 1e-9f

typedef __bf16 bf16x8 __attribute__((ext_vector_type(8)));
typedef float  f32x4  __attribute__((ext_vector_type(4)));
typedef unsigned short ushort_t;
typedef ushort_t us8 __attribute__((ext_vector_type(8)));

__device__ __forceinline__ float2 cmul(float cr, float ci, float2 v) {
    return make_float2(cr * v.x - ci * v.y, ci * v.x + cr * v.y);
}

__device__ __forceinline__ ushort_t f2bf(float f) {
    unsigned int u = __float_as_uint(f);
    u += 0x7FFFu + ((u >> 16) & 1u);   // RNE
    return (ushort_t)(u >> 16);
}

// ---------------- lambda tables: L1, O1(one-minus), L2, L3 ----------------
__global__ void k_lamtab(const float* __restrict__ ldt, const float* __restrict__ llr,
                         const float* __restrict__ lim, float* __restrict__ tab) {
    int p = threadIdx.x;
    if (p >= 64) return;
    float dt  = expf(ldt[0]);
    float mag = expf(-expf(llr[p]) * dt);
    float ph  = lim[p] * dt;
    float c = cosf(ph), s = sinf(ph);
    float m2 = mag * mag, m3 = m2 * mag;
    float c2 = c * c - s * s, s2 = 2.f * c * s;
    float c3 = c2 * c - s2 * s, s3 = s2 * c + c2 * s;
    tab[p]        = c * mag;          tab[64 + p]  = s * mag;          // L1
    tab[128 + p]  = c * (1.f - mag);  tab[192 + p] = s * (1.f - mag);  // O1
    tab[256 + p]  = c2 * m2;          tab[320 + p] = s2 * m2;          // L2
    tab[384 + p]  = c3 * m3;          tab[448 + p] = s3 * m3;          // L3
}

// ---------------- prep: W[K][ncols] -> bf16 B-fragment layout ----------------
__global__ void k_prepw(const float* __restrict__ w, ushort_t* __restrict__ wb,
                        int ncols, int nsteps, int total) {
    int tid = blockIdx.x * blockDim.x + threadIdx.x;
    if (tid >= total) return;
    int l  = tid & 63;
    int s  = (tid >> 6) % nsteps;
    int nt = tid / (64 * nsteps);
    int col = nt * 16 + (l & 15);
    int kb  = s * 32 + (l >> 4) * 8;
    us8 d;
#pragma unroll
    for (int j = 0; j < 8; ++j) d[j] = f2bf(w[(size_t)(kb + j) * ncols + col]);
    *(us8*)(wb + (size_t)tid * 8) = d;
}

// ---------------- MFMA fused MLP: xp = (silu(xW1) * (xW2)) @ Wp + bp ----------------
// 4 waves/block; each wave owns TWO 16-row m-tiles -> B-fragments reused 2x,
// acc1/acc2 are nt-scoped (only acc3[8][2] persists).
__global__ void __launch_bounds__(256)
k_mlpf(const float* __restrict__ x, const ushort_t* __restrict__ wb1,
       const ushort_t* __restrict__ wb2, const ushort_t* __restrict__ wpb,
       const float* __restrict__ bp, float* __restrict__ xp, int Mt) {
    __shared__ ushort_t hs[4][2][2048];   // per-wave, per-mtile 16x128 bf16 H (swizzled)
    const int wid = threadIdx.x >> 6, l = threadIdx.x & 63;
    const int pair = blockIdx.x * 4 + wid;
    const int mt0 = pair * 2;
    if (mt0 >= Mt) return;
    const bool has1 = (mt0 + 1) < Mt;
    const int llo = l & 15, lhi = l >> 4;

    // A fragments for both m-tiles (K=128 -> 4 ksteps)
    bf16x8 af[2][4];
#pragma unroll
    for (int m = 0; m < 2; ++m) {
        int mt = (m == 1 && !has1) ? mt0 : (mt0 + m);   // clamp tail
        const float* xr = x + (size_t)(mt * 16 + llo) * 128 + lhi * 8;
#pragma unroll
        for (int s = 0; s < 4; ++s) {
            float4 v0 = *(const float4*)(xr + s * 32);
            float4 v1 = *(const float4*)(xr + s * 32 + 4);
            us8 d;
            d[0] = f2bf(v0.x); d[1] = f2bf(v0.y); d[2] = f2bf(v0.z); d[3] = f2bf(v0.w);
            d[4] = f2bf(v1.x); d[5] = f2bf(v1.y); d[6] = f2bf(v1.z); d[7] = f2bf(v1.w);
            af[m][s] = *(bf16x8*)&d;
        }
    }

    const bf16x8* B1 = (const bf16x8*)wb1;
    const bf16x8* B2 = (const bf16x8*)wb2;
    const bf16x8* BP = (const bf16x8*)wpb;

    const f32x4 zero = {0.f, 0.f, 0.f, 0.f};
    f32x4 acc3[8][2];
#pragma unroll
    for (int i = 0; i < 8; ++i) { acc3[i][0] = zero; acc3[i][1] = zero; }

#pragma unroll
    for (int half = 0; half < 2; ++half) {
        // GEMM1/2 + silu -> H tiles for this half's 128 output cols
#pragma unroll 2
        for (int nt = 0; nt < 8; ++nt) {
            int ntg = half * 8 + nt;
            bf16x8 b1[4], b2[4];
#pragma unroll
            for (int s = 0; s < 4; ++s) {
                b1[s] = B1[(ntg * 4 + s) * 64 + l];
                b2[s] = B2[(ntg * 4 + s) * 64 + l];
            }
#pragma unroll
            for (int m = 0; m < 2; ++m) {
                f32x4 a1 = zero, a2 = zero;
#pragma unroll
                for (int s = 0; s < 4; ++s) {
                    a1 = __builtin_amdgcn_mfma_f32_16x16x32_bf16(af[m][s], b1[s], a1, 0, 0, 0);
                    a2 = __builtin_amdgcn_mfma_f32_16x16x32_bf16(af[m][s], b2[s], a2, 0, 0, 0);
                }
#pragma unroll
                for (int i = 0; i < 4; ++i) {
                    float g = a1[i];
                    float hv = (g / (1.f + __expf(-g))) * a2[i];
                    int r = 4 * lhi + i;
                    int byte = (r << 8) + ((nt * 16 + llo) << 1);
                    byte ^= (r & 7) << 4;
                    hs[wid][m][byte >> 1] = f2bf(hv);
                }
            }
        }

        // GEMM3 partial: K-slice = this half's 128 cols of H
        bf16x8 hf[2][4];
#pragma unroll
        for (int m = 0; m < 2; ++m)
#pragma unroll
            for (int s2 = 0; s2 < 4; ++s2) {
                int byte = (llo << 8) + (s2 << 6) + (lhi << 4);
                byte ^= (llo & 7) << 4;
                hf[m][s2] = *(const bf16x8*)((const char*)hs[wid][m] + byte);
            }
#pragma unroll 2
        for (int nt3 = 0; nt3 < 8; ++nt3) {
#pragma unroll
            for (int s2 = 0; s2 < 4; ++s2) {
                bf16x8 bw = BP[(nt3 * 8 + half * 4 + s2) * 64 + l];
                acc3[nt3][0] = __builtin_amdgcn_mfma_f32_16x16x32_bf16(hf[0][s2], bw, acc3[nt3][0], 0, 0, 0);
                acc3[nt3][1] = __builtin_amdgcn_mfma_f32_16x16x32_bf16(hf[1][s2], bw, acc3[nt3][1], 0, 0, 0);
            }
        }
    }

    // epilogue: + bias, store f32 (guard tail m-tile)
#pragma unroll
    for (int m = 0; m < 2; ++m) {
        if (m == 1 && !has1) break;
        const int row0 = (mt0 + m) * 16;
#pragma unroll
        for (int nt3 = 0; nt3 < 8; ++nt3) {
            float bpv = bp[nt3 * 16 + llo];
#pragma unroll
            for (int i = 0; i < 4; ++i) {
                int r = row0 + 4 * lhi + i;
                xp[(size_t)r * 128 + nt3 * 16 + llo] = acc3[nt3][m][i] + bpv;
            }
        }
    }
}

// ---------------- CSR build (by dst). in-deg == out-deg for this edge list ----------------
__global__ void k_hist(const int* __restrict__ ei, int E, int* __restrict__ cnt) {
    int e = blockIdx.x * blockDim.x + threadIdx.x;
    if (e < E) atomicAdd(&cnt[ei[E + e]], 1);      // histogram over dst
}

// hierarchical scan: A) per-block sums
__global__ void __launch_bounds__(256)
k_scanA(const int* __restrict__ cnt, int N, int* __restrict__ bsum) {
    __shared__ int s[256];
    int t = threadIdx.x;
    int i = blockIdx.x * 256 + t;
    int v = (i < N) ? cnt[i] : 0;
    s[t] = v;
    __syncthreads();
#pragma unroll
    for (int d = 128; d > 0; d >>= 1) {
        if (t < d) s[t] += s[t + d];
        __syncthreads();
    }
    if (t == 0) bsum[blockIdx.x] = s[0];
}

// B) scan block sums (NB <= 1024), write exclusive prefixes + total to off[N]
__global__ void __launch_bounds__(1024)
k_scanB(const int* __restrict__ bsum, int NB, int* __restrict__ bpre,
        int* __restrict__ offN) {
    __shared__ int s[1024];
    int t = threadIdx.x;
    int v = (t < NB) ? bsum[t] : 0;
    s[t] = v;
    __syncthreads();
    for (int d = 1; d < 1024; d <<= 1) {
        int u = (t >= d) ? s[t - d] : 0;
        __syncthreads();
        s[t] += u;
        __syncthreads();
    }
    if (t < NB) bpre[t] = s[t] - v;          // exclusive
    if (t == NB - 1) *offN = s[t];           // total
}

// C) intra-block scan + block prefix -> off/cursor/bv
__global__ void __launch_bounds__(256)
k_scanC(const int* __restrict__ cnt, int N, const int* __restrict__ bpre,
        int* __restrict__ off, int* __restrict__ cursor, float* __restrict__ bv) {
    __shared__ int s[256];
    int t = threadIdx.x;
    int i = blockIdx.x * 256 + t;
    int v = (i < N) ? cnt[i] : 0;
    s[t] = v;
    __syncthreads();
    for (int d = 1; d < 256; d <<= 1) {
        int u = (t >= d) ? s[t - d] : 0;
        __syncthreads();
        s[t] += u;
        __syncthreads();
    }
    if (i < N) {
        int excl = bpre[blockIdx.x] + s[t] - v;
        off[i] = excl;
        cursor[i] = excl;
        bv[i] = (v > 1) ? (-1.f / ((float)v - 1.f + EPSF)) : 0.f;
    }
}

__global__ void k_fill(const int* __restrict__ ei, int E,
                       int* __restrict__ cursor, int* __restrict__ csr) {
    int e = blockIdx.x * blockDim.x + threadIdx.x;
    if (e < E) {
        int s = ei[e], d = ei[E + e];
        int p = atomicAdd(&cursor[d], 1);
        csr[p] = s;
    }
}

// ---------------- fused gather + node passes (one wave per node) ----------------
__global__ void __launch_bounds__(256)
k_passA(const float* __restrict__ xp, const float* __restrict__ bv,
        const int* __restrict__ off, const int* __restrict__ csr,
        const float* __restrict__ tab, float* __restrict__ Xb,
        float* __restrict__ a1, int N) {
    int tid = blockIdx.x * blockDim.x + threadIdx.x;
    int v = tid >> 6, l = tid & 63;
    if (v >= N) return;
    int beg = off[v], end = off[v + 1];
    float2 m0 = make_float2(0.f, 0.f), xb = make_float2(0.f, 0.f);
    for (int k = beg; k < end; ++k) {
        int s = csr[k];
        float2 tv = *(const float2*)&xp[(size_t)s * 128 + 2 * l];
        float b = bv[s];
        m0.x += tv.x; m0.y += tv.y;
        xb.x += b * tv.x; xb.y += b * tv.y;
    }
    size_t o = (size_t)v * 128 + 2 * l;
    *(float2*)&Xb[o] = xb;
    float2 xv = *(const float2*)&xp[o];
    int dg = end - beg;
    float L1r = tab[l], L1i = tab[64 + l], O1r = tab[128 + l], O1i = tab[192 + l];
    float Q = 1.f / ((float)dg - 1.f + EPSF);
    float2 t1 = cmul(O1r, O1i, xv);
    float2 t2 = cmul(L1r, L1i, m0);
    float2 a = make_float2(t1.x + Q * t2.x, t1.y + Q * t2.y);
    if (dg == 1) a = xv;
    *(float2*)&a1[o] = a;
}

__global__ void __launch_bounds__(256)
k_passB(const float* __restrict__ xp, const float* __restrict__ a1,
        const float* __restrict__ bv, const int* __restrict__ off,
        const int* __restrict__ csr, const float* __restrict__ tab,
        float* __restrict__ Ab1, float* __restrict__ Bv, float* __restrict__ B2v,
        float* __restrict__ a2, int N) {
    int tid = blockIdx.x * blockDim.x + threadIdx.x;
    int v = tid >> 6, l = tid & 63;
    if (v >= N) return;
    int beg = off[v], end = off[v + 1];
    float2 A1 = make_float2(0.f, 0.f), ab = make_float2(0.f, 0.f);
    float Bs = 0.f, B2s = 0.f;
    for (int k = beg; k < end; ++k) {
        int s = csr[k];
        float2 tv = *(const float2*)&a1[(size_t)s * 128 + 2 * l];
        float b = bv[s];
        A1.x += tv.x; A1.y += tv.y;
        ab.x += b * tv.x; ab.y += b * tv.y;
        Bs += b; B2s += b * b;
    }
    size_t o = (size_t)v * 128 + 2 * l;
    *(float2*)&Ab1[o] = ab;
    if (l == 0) { Bv[v] = Bs; B2v[v] = B2s; }
    float2 xv = *(const float2*)&xp[o];
    int dg = end - beg;
    float L1r = tab[l], L1i = tab[64 + l], O1r = tab[128 + l], O1i = tab[192 + l];
    float2 lx = cmul(L1r, L1i, xv);
    float2 m1 = make_float2(A1.x + Bs * lx.x, A1.y + Bs * lx.y);
    float Q = 1.f / ((float)dg - 1.f + EPSF);
    float2 t1 = cmul(O1r, O1i, xv);
    float2 lm = cmul(L1r, L1i, m1);
    float2 a = make_float2(t1.x + Q * lm.x, t1.y + Q * lm.y);
    if (dg == 1) a = xv;
    *(float2*)&a2[o] = a;
}

__global__ void __launch_bounds__(256)
k_passC(const float* __restrict__ xp, const float* __restrict__ a2,
        const float* __restrict__ a1, const float* __restrict__ Xb,
        const float* __restrict__ bv, const float* __restrict__ Bv,
        const int* __restrict__ off, const int* __restrict__ csr,
        const float* __restrict__ tab, float* __restrict__ a3, int N) {
    int tid = blockIdx.x * blockDim.x + threadIdx.x;
    int v = tid >> 6, l = tid & 63;
    if (v >= N) return;
    int beg = off[v], end = off[v + 1];
    float2 A2 = make_float2(0.f, 0.f);
    for (int k = beg; k < end; ++k) {
        int s = csr[k];
        float2 tv = *(const float2*)&a2[(size_t)s * 128 + 2 * l];
        A2.x += tv.x; A2.y += tv.y;
    }
    size_t o = (size_t)v * 128 + 2 * l;
    float2 xv  = *(const float2*)&xp[o];
    float2 a1v = *(const float2*)&a1[o];
    float2 Xbv = *(const float2*)&Xb[o];
    int dg = end - beg;
    float Bs = Bv[v], bs = bv[v];
    float L1r = tab[l], L1i = tab[64 + l], O1r = tab[128 + l], O1i = tab[192 + l];
    float L2r = tab[256 + l], L2i = tab[320 + l];
    float2 la1 = cmul(L1r, L1i, a1v);
    float2 lxb = cmul(L2r, L2i, Xbv);
    float2 m2 = make_float2(A2.x + Bs * la1.x + bs * lxb.x,
                            A2.y + Bs * la1.y + bs * lxb.y);
    float Q = 1.f / ((float)dg - 1.f + EPSF);
    float2 t1 = cmul(O1r, O1i, xv);
    float2 lm = cmul(L1r, L1i, m2);
    float2 a = make_float2(t1.x + Q * lm.x, t1.y + Q * lm.y);
    if (dg == 1) a = xv;
    *(float2*)&a3[o] = a;
}

__global__ void __launch_bounds__(256)
k_passD(const float* __restrict__ xin, const float* __restrict__ xp,
        const float* __restrict__ a3, const float* a2,
        const float* __restrict__ Ab1, const float* __restrict__ bv,
        const float* __restrict__ Bv, const float* __restrict__ B2v,
        const int* __restrict__ off, const int* __restrict__ csr,
        const float* __restrict__ tab, float* out, int N) {
    int tid = blockIdx.x * blockDim.x + threadIdx.x;
    int v = tid >> 6, l = tid & 63;
    if (v >= N) return;
    int beg = off[v], end = off[v + 1];
    float2 A3 = make_float2(0.f, 0.f);
    for (int k = beg; k < end; ++k) {
        int s = csr[k];
        float2 tv = *(const float2*)&a3[(size_t)s * 128 + 2 * l];
        A3.x += tv.x; A3.y += tv.y;
    }
    size_t o = (size_t)v * 128 + 2 * l;
    float2 xv  = *(const float2*)&xp[o];
    float2 a2v = *(const float2*)&a2[o];
    float2 Abv = *(const float2*)&Ab1[o];
    int dg = end - beg;
    float Bs = Bv[v], bs = bv[v], B2s = B2v[v];
    float L1r = tab[l], L1i = tab[64 + l], O1r = tab[128 + l], O1i = tab[192 + l];
    float L2r = tab[256 + l], L2i = tab[320 + l];
    float L3r = tab[384 + l], L3i = tab[448 + l];
    float2 la2 = cmul(L1r, L1i, a2v);
    float2 lab = cmul(L2r, L2i, Abv);
    float2 lx3 = cmul(L3r, L3i, xv);
    float bB2 = bs * B2s;
    float2 m3 = make_float2(A3.x + Bs * la2.x + bs * lab.x + bB2 * lx3.x,
                            A3.y + Bs * la2.y + bs * lab.y + bB2 * lx3.y);
    float2 g;
    if (dg == 0) {
        g = xv;
    } else {
        float inv = 1.f / ((float)dg + EPSF);
        float2 t1 = cmul(O1r, O1i, xv);
        float2 lm = cmul(L1r, L1i, m3);
        g = make_float2(t1.x + lm.x * inv, t1.y + lm.y * inv);
    }
    float2 xi = *(const float2*)&xin[o];
    float2 res = make_float2(xi.x + fmaxf(g.x, 0.f), xi.y + fmaxf(g.y, 0.f));
    *(float2*)&out[o] = res;
}

extern "C" void kernel_launch(void* const* d_in, const int* in_sizes, int n_in,
                              void* d_out, int out_size, void* d_ws, size_t ws_size,
                              hipStream_t stream) {
    const float* x   = (const float*)d_in[0];
    const int*   ei  = (const int*)d_in[1];
    const float* ldt = (const float*)d_in[2];
    const float* llr = (const float*)d_in[3];
    const float* lim = (const float*)d_in[4];
    const float* W1  = (const float*)d_in[5];
    const float* W2  = (const float*)d_in[6];
    const float* Wp  = (const float*)d_in[7];
    const float* bp  = (const float*)d_in[8];
    float* out = (float*)d_out;

    const int N = in_sizes[0] / 128;
    const int E = in_sizes[1] / 2;
    const size_t nd = (size_t)N * 128;
    const int Mt = (N + 15) / 16;          // 16-row m-tiles (N=50000 -> 3125)
    const int Mt2 = (Mt + 1) / 2;          // m-tile pairs per wave
    const int NB = (N + 255) / 256;        // scan blocks

    float* ws  = (float*)d_ws;
    float* xp  = ws;            // post-MLP x
    float* Xb  = ws + nd;
    float* a1  = ws + 2 * nd;
    float* ab1 = ws + 3 * nd;
    float* a3  = ws + 4 * nd;
    float* a2  = out;           // a2 lives in d_out until k_passD overwrites it

    int*   cnt    = (int*)(ws + 5 * nd);   // N
    int*   off    = cnt + N;               // N+4 (padded)
    int*   cursor = off + N + 4;           // N
    float* bv     = (float*)(cursor + N);  // N
    float* Bv     = bv + N;                // N
    float* B2v    = Bv + N;                // N
    float* tab    = B2v + N;               // 512
    int*   bsum   = (int*)(tab + 512);     // NB
    int*   bpre   = bsum + NB;             // NB
    int*   csr    = bpre + NB;             // E
    ushort_t* wb1 = (ushort_t*)(csr + E);  // 32768
    ushort_t* wb2 = wb1 + 32768;           // 32768
    ushort_t* wpb = wb2 + 32768;           // 32768

    const int nodeBlocks = (int)(((size_t)N * 64 + 255) / 256);
    const int eBlocks    = (E + 255) / 256;

    hipMemsetAsync(cnt, 0, (size_t)N * sizeof(int), stream);
    k_lamtab<<<1, 64, 0, stream>>>(ldt, llr, lim, tab);

    // bf16 weight prep + MFMA MLP (x converted in-kernel)
    k_prepw<<<16, 256, 0, stream>>>(W1, wb1, 256, 4, 16 * 4 * 64);
    k_prepw<<<16, 256, 0, stream>>>(W2, wb2, 256, 4, 16 * 4 * 64);
    k_prepw<<<16, 256, 0, stream>>>(Wp, wpb, 128, 8, 8 * 8 * 64);
    k_mlpf<<<(Mt2 + 3) / 4, 256, 0, stream>>>(x, wb1, wb2, wpb, bp, xp, Mt);

    // CSR build (hierarchical scan)
    k_hist<<<eBlocks, 256, 0, stream>>>(ei, E, cnt);
    k_scanA<<<NB, 256, 0, stream>>>(cnt, N, bsum);
    k_scanB<<<1, 1024, 0, stream>>>(bsum, NB, bpre, &off[N]);
    k_scanC<<<NB, 256, 0, stream>>>(cnt, N, bpre, off, cursor, bv);
    k_fill<<<eBlocks, 256, 0, stream>>>(ei, E, cursor, csr);

    // fused gather + node passes
    k_passA<<<nodeBlocks, 256, 0, stream>>>(xp, bv, off, csr, tab, Xb, a1, N);
    k_passB<<<nodeBlocks, 256, 0, stream>>>(xp, a1, bv, off, csr, tab, ab1, Bv, B2v, a2, N);
    k_passC<<<nodeBlocks, 256, 0, stream>>>(xp, a2, a1, Xb, bv, Bv, off, csr, tab, a3, N);
    k_passD<<<nodeBlocks, 256, 0, stream>>>(x, xp, a3, a2, ab1, bv, Bv, B2v, off, csr, tab, out, N);
}

// Round 6
// 316.077 us; speedup vs baseline: 7.3313x; 1.0519x over previous
//
#include <hip/hip_runtime.h>

#define EPSF 1e-9f

typedef __bf16 bf16x8 __attribute__((ext_vector_type(8)));
typedef float  f32x4  __attribute__((ext_vector_type(4)));
typedef unsigned short ushort_t;
typedef ushort_t us8 __attribute__((ext_vector_type(8)));

__device__ __forceinline__ float2 cmul(float cr, float ci, float2 v) {
    return make_float2(cr * v.x - ci * v.y, ci * v.x + cr * v.y);
}

__device__ __forceinline__ ushort_t f2bf(float f) {
    unsigned int u = __float_as_uint(f);
    u += 0x7FFFu + ((u >> 16) & 1u);   // RNE
    return (ushort_t)(u >> 16);
}

// ---------------- lambda tables: L1, O1(one-minus), L2, L3 ----------------
__global__ void k_lamtab(const float* __restrict__ ldt, const float* __restrict__ llr,
                         const float* __restrict__ lim, float* __restrict__ tab) {
    int p = threadIdx.x;
    if (p >= 64) return;
    float dt  = expf(ldt[0]);
    float mag = expf(-expf(llr[p]) * dt);
    float ph  = lim[p] * dt;
    float c = cosf(ph), s = sinf(ph);
    float m2 = mag * mag, m3 = m2 * mag;
    float c2 = c * c - s * s, s2 = 2.f * c * s;
    float c3 = c2 * c - s2 * s, s3 = s2 * c + c2 * s;
    tab[p]        = c * mag;          tab[64 + p]  = s * mag;          // L1
    tab[128 + p]  = c * (1.f - mag);  tab[192 + p] = s * (1.f - mag);  // O1
    tab[256 + p]  = c2 * m2;          tab[320 + p] = s2 * m2;          // L2
    tab[384 + p]  = c3 * m3;          tab[448 + p] = s3 * m3;          // L3
}

// ---------------- prep: W[K][ncols] -> bf16 B-fragment layout ----------------
__global__ void k_prepw(const float* __restrict__ w, ushort_t* __restrict__ wb,
                        int ncols, int nsteps, int total) {
    int tid = blockIdx.x * blockDim.x + threadIdx.x;
    if (tid >= total) return;
    int l  = tid & 63;
    int s  = (tid >> 6) % nsteps;
    int nt = tid / (64 * nsteps);
    int col = nt * 16 + (l & 15);
    int kb  = s * 32 + (l >> 4) * 8;
    us8 d;
#pragma unroll
    for (int j = 0; j < 8; ++j) d[j] = f2bf(w[(size_t)(kb + j) * ncols + col]);
    *(us8*)(wb + (size_t)tid * 8) = d;
}

// ---------------- MFMA fused MLP: xp = (silu(xW1) * (xW2)) @ Wp + bp ----------------
// Phase-split: (1) full 16x256 H -> LDS, (2) GEMM3 with per-nt3 accumulators.
// No accumulator lives across phases -> no spill. 2 m-tiles/wave for B reuse.
__global__ void __launch_bounds__(256)
k_mlpf(const float* __restrict__ x, const ushort_t* __restrict__ wb1,
       const ushort_t* __restrict__ wb2, const ushort_t* __restrict__ wpb,
       const float* __restrict__ bp, float* __restrict__ xp, int Mt) {
    __shared__ ushort_t hs[4][2][4096];   // 64KB: per-wave, per-mtile 16x256 bf16 H (swizzled)
    const int wid = threadIdx.x >> 6, l = threadIdx.x & 63;
    const int pair = blockIdx.x * 4 + wid;
    const int mt0 = pair * 2;
    if (mt0 >= Mt) return;
    const bool has1 = (mt0 + 1) < Mt;
    const int llo = l & 15, lhi = l >> 4;

    // A fragments for both m-tiles (K=128 -> 4 ksteps)
    bf16x8 af[2][4];
#pragma unroll
    for (int m = 0; m < 2; ++m) {
        int mt = (m == 1 && !has1) ? mt0 : (mt0 + m);   // clamp tail
        const float* xr = x + (size_t)(mt * 16 + llo) * 128 + lhi * 8;
#pragma unroll
        for (int s = 0; s < 4; ++s) {
            float4 v0 = *(const float4*)(xr + s * 32);
            float4 v1 = *(const float4*)(xr + s * 32 + 4);
            us8 d;
            d[0] = f2bf(v0.x); d[1] = f2bf(v0.y); d[2] = f2bf(v0.z); d[3] = f2bf(v0.w);
            d[4] = f2bf(v1.x); d[5] = f2bf(v1.y); d[6] = f2bf(v1.z); d[7] = f2bf(v1.w);
            af[m][s] = *(bf16x8*)&d;
        }
    }

    const bf16x8* B1 = (const bf16x8*)wb1;
    const bf16x8* B2 = (const bf16x8*)wb2;
    const bf16x8* BP = (const bf16x8*)wpb;
    const f32x4 zero = {0.f, 0.f, 0.f, 0.f};

    // ---- Phase 1: GEMM1/2 + silu -> full H tile (16x256 per m) ----
#pragma unroll 2
    for (int nt = 0; nt < 16; ++nt) {
        bf16x8 b1[4], b2[4];
#pragma unroll
        for (int s = 0; s < 4; ++s) {
            b1[s] = B1[(nt * 4 + s) * 64 + l];
            b2[s] = B2[(nt * 4 + s) * 64 + l];
        }
#pragma unroll
        for (int m = 0; m < 2; ++m) {
            f32x4 a1 = zero, a2 = zero;
#pragma unroll
            for (int s = 0; s < 4; ++s) {
                a1 = __builtin_amdgcn_mfma_f32_16x16x32_bf16(af[m][s], b1[s], a1, 0, 0, 0);
                a2 = __builtin_amdgcn_mfma_f32_16x16x32_bf16(af[m][s], b2[s], a2, 0, 0, 0);
            }
#pragma unroll
            for (int i = 0; i < 4; ++i) {
                float g = a1[i];
                float hv = (g / (1.f + __expf(-g))) * a2[i];
                int r = 4 * lhi + i;
                int byte = (r << 9) + ((nt * 16 + llo) << 1);  // row stride 512B (256 bf16)
                byte ^= (r & 7) << 4;
                hs[wid][m][byte >> 1] = f2bf(hv);
            }
        }
    }

    // ---- Phase 2: GEMM3 over full K=256, per-nt3 accumulators + fused store ----
#pragma unroll 2
    for (int nt3 = 0; nt3 < 8; ++nt3) {
        f32x4 acc0 = zero, acc1 = zero;
#pragma unroll
        for (int sg = 0; sg < 8; ++sg) {
            bf16x8 bw = BP[(nt3 * 8 + sg) * 64 + l];
            int byte = (llo << 9) + (sg << 6) + (lhi << 4);
            byte ^= (llo & 7) << 4;
            bf16x8 h0 = *(const bf16x8*)((const char*)hs[wid][0] + byte);
            acc0 = __builtin_amdgcn_mfma_f32_16x16x32_bf16(h0, bw, acc0, 0, 0, 0);
            bf16x8 h1 = *(const bf16x8*)((const char*)hs[wid][1] + byte);
            acc1 = __builtin_amdgcn_mfma_f32_16x16x32_bf16(h1, bw, acc1, 0, 0, 0);
        }
        float bpv = bp[nt3 * 16 + llo];
        {
            const int row0 = mt0 * 16;
#pragma unroll
            for (int i = 0; i < 4; ++i) {
                int r = row0 + 4 * lhi + i;
                xp[(size_t)r * 128 + nt3 * 16 + llo] = acc0[i] + bpv;
            }
        }
        if (has1) {
            const int row0 = (mt0 + 1) * 16;
#pragma unroll
            for (int i = 0; i < 4; ++i) {
                int r = row0 + 4 * lhi + i;
                xp[(size_t)r * 128 + nt3 * 16 + llo] = acc1[i] + bpv;
            }
        }
    }
}

// ---------------- CSR build (by dst). in-deg == out-deg for this edge list ----------------
__global__ void k_hist(const int* __restrict__ ei, int E, int* __restrict__ cnt) {
    int e = blockIdx.x * blockDim.x + threadIdx.x;
    if (e < E) atomicAdd(&cnt[ei[E + e]], 1);      // histogram over dst
}

// hierarchical scan: A) per-block sums
__global__ void __launch_bounds__(256)
k_scanA(const int* __restrict__ cnt, int N, int* __restrict__ bsum) {
    __shared__ int s[256];
    int t = threadIdx.x;
    int i = blockIdx.x * 256 + t;
    int v = (i < N) ? cnt[i] : 0;
    s[t] = v;
    __syncthreads();
#pragma unroll
    for (int d = 128; d > 0; d >>= 1) {
        if (t < d) s[t] += s[t + d];
        __syncthreads();
    }
    if (t == 0) bsum[blockIdx.x] = s[0];
}

// B) scan block sums (NB <= 1024), write exclusive prefixes + total to off[N]
__global__ void __launch_bounds__(1024)
k_scanB(const int* __restrict__ bsum, int NB, int* __restrict__ bpre,
        int* __restrict__ offN) {
    __shared__ int s[1024];
    int t = threadIdx.x;
    int v = (t < NB) ? bsum[t] : 0;
    s[t] = v;
    __syncthreads();
    for (int d = 1; d < 1024; d <<= 1) {
        int u = (t >= d) ? s[t - d] : 0;
        __syncthreads();
        s[t] += u;
        __syncthreads();
    }
    if (t < NB) bpre[t] = s[t] - v;          // exclusive
    if (t == NB - 1) *offN = s[t];           // total
}

// C) intra-block scan + block prefix -> off/cursor/bv
__global__ void __launch_bounds__(256)
k_scanC(const int* __restrict__ cnt, int N, const int* __restrict__ bpre,
        int* __restrict__ off, int* __restrict__ cursor, float* __restrict__ bv) {
    __shared__ int s[256];
    int t = threadIdx.x;
    int i = blockIdx.x * 256 + t;
    int v = (i < N) ? cnt[i] : 0;
    s[t] = v;
    __syncthreads();
    for (int d = 1; d < 256; d <<= 1) {
        int u = (t >= d) ? s[t - d] : 0;
        __syncthreads();
        s[t] += u;
        __syncthreads();
    }
    if (i < N) {
        int excl = bpre[blockIdx.x] + s[t] - v;
        off[i] = excl;
        cursor[i] = excl;
        bv[i] = (v > 1) ? (-1.f / ((float)v - 1.f + EPSF)) : 0.f;
    }
}

__global__ void k_fill(const int* __restrict__ ei, int E,
                       int* __restrict__ cursor, int* __restrict__ csr) {
    int e = blockIdx.x * blockDim.x + threadIdx.x;
    if (e < E) {
        int s = ei[e], d = ei[E + e];
        int p = atomicAdd(&cursor[d], 1);
        csr[p] = s;
    }
}

// ---------------- fused gather + node passes (one wave per node) ----------------
__global__ void __launch_bounds__(256)
k_passA(const float* __restrict__ xp, const float* __restrict__ bv,
        const int* __restrict__ off, const int* __restrict__ csr,
        const float* __restrict__ tab, float* __restrict__ Xb,
        float* __restrict__ a1, int N) {
    int tid = blockIdx.x * blockDim.x + threadIdx.x;
    int v = tid >> 6, l = tid & 63;
    if (v >= N) return;
    int beg = off[v], end = off[v + 1];
    float2 m0 = make_float2(0.f, 0.f), xb = make_float2(0.f, 0.f);
    for (int k = beg; k < end; ++k) {
        int s = csr[k];
        float2 tv = *(const float2*)&xp[(size_t)s * 128 + 2 * l];
        float b = bv[s];
        m0.x += tv.x; m0.y += tv.y;
        xb.x += b * tv.x; xb.y += b * tv.y;
    }
    size_t o = (size_t)v * 128 + 2 * l;
    *(float2*)&Xb[o] = xb;
    float2 xv = *(const float2*)&xp[o];
    int dg = end - beg;
    float L1r = tab[l], L1i = tab[64 + l], O1r = tab[128 + l], O1i = tab[192 + l];
    float Q = 1.f / ((float)dg - 1.f + EPSF);
    float2 t1 = cmul(O1r, O1i, xv);
    float2 t2 = cmul(L1r, L1i, m0);
    float2 a = make_float2(t1.x + Q * t2.x, t1.y + Q * t2.y);
    if (dg == 1) a = xv;
    *(float2*)&a1[o] = a;
}

__global__ void __launch_bounds__(256)
k_passB(const float* __restrict__ xp, const float* __restrict__ a1,
        const float* __restrict__ bv, const int* __restrict__ off,
        const int* __restrict__ csr, const float* __restrict__ tab,
        float* __restrict__ Ab1, float* __restrict__ Bv, float* __restrict__ B2v,
        float* __restrict__ a2, int N) {
    int tid = blockIdx.x * blockDim.x + threadIdx.x;
    int v = tid >> 6, l = tid & 63;
    if (v >= N) return;
    int beg = off[v], end = off[v + 1];
    float2 A1 = make_float2(0.f, 0.f), ab = make_float2(0.f, 0.f);
    float Bs = 0.f, B2s = 0.f;
    for (int k = beg; k < end; ++k) {
        int s = csr[k];
        float2 tv = *(const float2*)&a1[(size_t)s * 128 + 2 * l];
        float b = bv[s];
        A1.x += tv.x; A1.y += tv.y;
        ab.x += b * tv.x; ab.y += b * tv.y;
        Bs += b; B2s += b * b;
    }
    size_t o = (size_t)v * 128 + 2 * l;
    *(float2*)&Ab1[o] = ab;
    if (l == 0) { Bv[v] = Bs; B2v[v] = B2s; }
    float2 xv = *(const float2*)&xp[o];
    int dg = end - beg;
    float L1r = tab[l], L1i = tab[64 + l], O1r = tab[128 + l], O1i = tab[192 + l];
    float2 lx = cmul(L1r, L1i, xv);
    float2 m1 = make_float2(A1.x + Bs * lx.x, A1.y + Bs * lx.y);
    float Q = 1.f / ((float)dg - 1.f + EPSF);
    float2 t1 = cmul(O1r, O1i, xv);
    float2 lm = cmul(L1r, L1i, m1);
    float2 a = make_float2(t1.x + Q * lm.x, t1.y + Q * lm.y);
    if (dg == 1) a = xv;
    *(float2*)&a2[o] = a;
}

__global__ void __launch_bounds__(256)
k_passC(const float* __restrict__ xp, const float* __restrict__ a2,
        const float* __restrict__ a1, const float* __restrict__ Xb,
        const float* __restrict__ bv, const float* __restrict__ Bv,
        const int* __restrict__ off, const int* __restrict__ csr,
        const float* __restrict__ tab, float* __restrict__ a3, int N) {
    int tid = blockIdx.x * blockDim.x + threadIdx.x;
    int v = tid >> 6, l = tid & 63;
    if (v >= N) return;
    int beg = off[v], end = off[v + 1];
    float2 A2 = make_float2(0.f, 0.f);
    for (int k = beg; k < end; ++k) {
        int s = csr[k];
        float2 tv = *(const float2*)&a2[(size_t)s * 128 + 2 * l];
        A2.x += tv.x; A2.y += tv.y;
    }
    size_t o = (size_t)v * 128 + 2 * l;
    float2 xv  = *(const float2*)&xp[o];
    float2 a1v = *(const float2*)&a1[o];
    float2 Xbv = *(const float2*)&Xb[o];
    int dg = end - beg;
    float Bs = Bv[v], bs = bv[v];
    float L1r = tab[l], L1i = tab[64 + l], O1r = tab[128 + l], O1i = tab[192 + l];
    float L2r = tab[256 + l], L2i = tab[320 + l];
    float2 la1 = cmul(L1r, L1i, a1v);
    float2 lxb = cmul(L2r, L2i, Xbv);
    float2 m2 = make_float2(A2.x + Bs * la1.x + bs * lxb.x,
                            A2.y + Bs * la1.y + bs * lxb.y);
    float Q = 1.f / ((float)dg - 1.f + EPSF);
    float2 t1 = cmul(O1r, O1i, xv);
    float2 lm = cmul(L1r, L1i, m2);
    float2 a = make_float2(t1.x + Q * lm.x, t1.y + Q * lm.y);
    if (dg == 1) a = xv;
    *(float2*)&a3[o] = a;
}

__global__ void __launch_bounds__(256)
k_passD(const float* __restrict__ xin, const float* __restrict__ xp,
        const float* __restrict__ a3, const float* a2,
        const float* __restrict__ Ab1, const float* __restrict__ bv,
        const float* __restrict__ Bv, const float* __restrict__ B2v,
        const int* __restrict__ off, const int* __restrict__ csr,
        const float* __restrict__ tab, float* out, int N) {
    int tid = blockIdx.x * blockDim.x + threadIdx.x;
    int v = tid >> 6, l = tid & 63;
    if (v >= N) return;
    int beg = off[v], end = off[v + 1];
    float2 A3 = make_float2(0.f, 0.f);
    for (int k = beg; k < end; ++k) {
        int s = csr[k];
        float2 tv = *(const float2*)&a3[(size_t)s * 128 + 2 * l];
        A3.x += tv.x; A3.y += tv.y;
    }
    size_t o = (size_t)v * 128 + 2 * l;
    float2 xv  = *(const float2*)&xp[o];
    float2 a2v = *(const float2*)&a2[o];
    float2 Abv = *(const float2*)&Ab1[o];
    int dg = end - beg;
    float Bs = Bv[v], bs = bv[v], B2s = B2v[v];
    float L1r = tab[l], L1i = tab[64 + l], O1r = tab[128 + l], O1i = tab[192 + l];
    float L2r = tab[256 + l], L2i = tab[320 + l];
    float L3r = tab[384 + l], L3i = tab[448 + l];
    float2 la2 = cmul(L1r, L1i, a2v);
    float2 lab = cmul(L2r, L2i, Abv);
    float2 lx3 = cmul(L3r, L3i, xv);
    float bB2 = bs * B2s;
    float2 m3 = make_float2(A3.x + Bs * la2.x + bs * lab.x + bB2 * lx3.x,
                            A3.y + Bs * la2.y + bs * lab.y + bB2 * lx3.y);
    float2 g;
    if (dg == 0) {
        g = xv;
    } else {
        float inv = 1.f / ((float)dg + EPSF);
        float2 t1 = cmul(O1r, O1i, xv);
        float2 lm = cmul(L1r, L1i, m3);
        g = make_float2(t1.x + lm.x * inv, t1.y + lm.y * inv);
    }
    float2 xi = *(const float2*)&xin[o];
    float2 res = make_float2(xi.x + fmaxf(g.x, 0.f), xi.y + fmaxf(g.y, 0.f));
    *(float2*)&out[o] = res;
}

extern "C" void kernel_launch(void* const* d_in, const int* in_sizes, int n_in,
                              void* d_out, int out_size, void* d_ws, size_t ws_size,
                              hipStream_t stream) {
    const float* x   = (const float*)d_in[0];
    const int*   ei  = (const int*)d_in[1];
    const float* ldt = (const float*)d_in[2];
    const float* llr = (const float*)d_in[3];
    const float* lim = (const float*)d_in[4];
    const float* W1  = (const float*)d_in[5];
    const float* W2  = (const float*)d_in[6];
    const float* Wp  = (const float*)d_in[7];
    const float* bp  = (const float*)d_in[8];
    float* out = (float*)d_out;

    const int N = in_sizes[0] / 128;
    const int E = in_sizes[1] / 2;
    const size_t nd = (size_t)N * 128;
    const int Mt = (N + 15) / 16;          // 16-row m-tiles (N=50000 -> 3125)
    const int Mt2 = (Mt + 1) / 2;          // m-tile pairs per wave
    const int NB = (N + 255) / 256;        // scan blocks

    float* ws  = (float*)d_ws;
    float* xp  = ws;            // post-MLP x
    float* Xb  = ws + nd;
    float* a1  = ws + 2 * nd;
    float* ab1 = ws + 3 * nd;
    float* a3  = ws + 4 * nd;
    float* a2  = out;           // a2 lives in d_out until k_passD overwrites it

    int*   cnt    = (int*)(ws + 5 * nd);   // N
    int*   off    = cnt + N;               // N+4 (padded)
    int*   cursor = off + N + 4;           // N
    float* bv     = (float*)(cursor + N);  // N
    float* Bv     = bv + N;                // N
    float* B2v    = Bv + N;                // N
    float* tab    = B2v + N;               // 512
    int*   bsum   = (int*)(tab + 512);     // NB
    int*   bpre   = bsum + NB;             // NB
    int*   csr    = bpre + NB;             // E
    ushort_t* wb1 = (ushort_t*)(csr + E);  // 32768
    ushort_t* wb2 = wb1 + 32768;           // 32768
    ushort_t* wpb = wb2 + 32768;           // 32768

    const int nodeBlocks = (int)(((size_t)N * 64 + 255) / 256);
    const int eBlocks    = (E + 255) / 256;

    hipMemsetAsync(cnt, 0, (size_t)N * sizeof(int), stream);
    k_lamtab<<<1, 64, 0, stream>>>(ldt, llr, lim, tab);

    // bf16 weight prep + MFMA MLP (x converted in-kernel)
    k_prepw<<<16, 256, 0, stream>>>(W1, wb1, 256, 4, 16 * 4 * 64);
    k_prepw<<<16, 256, 0, stream>>>(W2, wb2, 256, 4, 16 * 4 * 64);
    k_prepw<<<16, 256, 0, stream>>>(Wp, wpb, 128, 8, 8 * 8 * 64);
    k_mlpf<<<(Mt2 + 3) / 4, 256, 0, stream>>>(x, wb1, wb2, wpb, bp, xp, Mt);

    // CSR build (hierarchical scan)
    k_hist<<<eBlocks, 256, 0, stream>>>(ei, E, cnt);
    k_scanA<<<NB, 256, 0, stream>>>(cnt, N, bsum);
    k_scanB<<<1, 1024, 0, stream>>>(bsum, NB, bpre, &off[N]);
    k_scanC<<<NB, 256, 0, stream>>>(cnt, N, bpre, off, cursor, bv);
    k_fill<<<eBlocks, 256, 0, stream>>>(ei, E, cursor, csr);

    // fused gather + node passes
    k_passA<<<nodeBlocks, 256, 0, stream>>>(xp, bv, off, csr, tab, Xb, a1, N);
    k_passB<<<nodeBlocks, 256, 0, stream>>>(xp, a1, bv, off, csr, tab, ab1, Bv, B2v, a2, N);
    k_passC<<<nodeBlocks, 256, 0, stream>>>(xp, a2, a1, Xb, bv, Bv, off, csr, tab, a3, N);
    k_passD<<<nodeBlocks, 256, 0, stream>>>(x, xp, a3, a2, ab1, bv, Bv, B2v, off, csr, tab, out, N);
}

// Round 7
// 245.517 us; speedup vs baseline: 9.4382x; 1.2874x over previous
//
#include <hip/hip_runtime.h>

#define EPSF 1e-9f

typedef __bf16 bf16x8 __attribute__((ext_vector_type(8)));
typedef float  f32x4  __attribute__((ext_vector_type(4)));
typedef unsigned short ushort_t;
typedef unsigned int uint_t;
typedef ushort_t us8 __attribute__((ext_vector_type(8)));

__device__ __forceinline__ float2 cmul(float cr, float ci, float2 v) {
    return make_float2(cr * v.x - ci * v.y, ci * v.x + cr * v.y);
}

__device__ __forceinline__ ushort_t f2bf(float f) {
    unsigned int u = __float_as_uint(f);
    u += 0x7FFFu + ((u >> 16) & 1u);   // RNE
    return (ushort_t)(u >> 16);
}

// packed pair helpers: low 16 bits = element 2l, high = 2l+1
__device__ __forceinline__ float2 bfu2(uint_t u) {
    return make_float2(__uint_as_float(u << 16), __uint_as_float(u & 0xFFFF0000u));
}
__device__ __forceinline__ uint_t packbf(float2 v) {
    return ((uint_t)f2bf(v.y) << 16) | (uint_t)f2bf(v.x);
}

// ---------------- lambda tables: L1, O1(one-minus), L2, L3 ----------------
__global__ void k_lamtab(const float* __restrict__ ldt, const float* __restrict__ llr,
                         const float* __restrict__ lim, float* __restrict__ tab) {
    int p = threadIdx.x;
    if (p >= 64) return;
    float dt  = expf(ldt[0]);
    float mag = expf(-expf(llr[p]) * dt);
    float ph  = lim[p] * dt;
    float c = cosf(ph), s = sinf(ph);
    float m2 = mag * mag, m3 = m2 * mag;
    float c2 = c * c - s * s, s2 = 2.f * c * s;
    float c3 = c2 * c - s2 * s, s3 = s2 * c + c2 * s;
    tab[p]        = c * mag;          tab[64 + p]  = s * mag;          // L1
    tab[128 + p]  = c * (1.f - mag);  tab[192 + p] = s * (1.f - mag);  // O1
    tab[256 + p]  = c2 * m2;          tab[320 + p] = s2 * m2;          // L2
    tab[384 + p]  = c3 * m3;          tab[448 + p] = s3 * m3;          // L3
}

// ---------------- prep: W[K][ncols] -> bf16 B-fragment layout ----------------
__global__ void k_prepw(const float* __restrict__ w, ushort_t* __restrict__ wb,
                        int ncols, int nsteps, int total) {
    int tid = blockIdx.x * blockDim.x + threadIdx.x;
    if (tid >= total) return;
    int l  = tid & 63;
    int s  = (tid >> 6) % nsteps;
    int nt = tid / (64 * nsteps);
    int col = nt * 16 + (l & 15);
    int kb  = s * 32 + (l >> 4) * 8;
    us8 d;
#pragma unroll
    for (int j = 0; j < 8; ++j) d[j] = f2bf(w[(size_t)(kb + j) * ncols + col]);
    *(us8*)(wb + (size_t)tid * 8) = d;
}

// ---------------- MFMA fused MLP: xp = (silu(xW1) * (xW2)) @ Wp + bp ----------------
__global__ void __launch_bounds__(256)
k_mlpf(const float* __restrict__ x, const ushort_t* __restrict__ wb1,
       const ushort_t* __restrict__ wb2, const ushort_t* __restrict__ wpb,
       const float* __restrict__ bp, float* __restrict__ xp,
       ushort_t* __restrict__ xpb, int Mt) {
    __shared__ ushort_t hs[4][2][4096];   // 64KB: per-wave, per-mtile 16x256 bf16 H (swizzled)
    const int wid = threadIdx.x >> 6, l = threadIdx.x & 63;
    const int pair = blockIdx.x * 4 + wid;
    const int mt0 = pair * 2;
    if (mt0 >= Mt) return;
    const bool has1 = (mt0 + 1) < Mt;
    const int llo = l & 15, lhi = l >> 4;

    // A fragments for both m-tiles (K=128 -> 4 ksteps)
    bf16x8 af[2][4];
#pragma unroll
    for (int m = 0; m < 2; ++m) {
        int mt = (m == 1 && !has1) ? mt0 : (mt0 + m);   // clamp tail
        const float* xr = x + (size_t)(mt * 16 + llo) * 128 + lhi * 8;
#pragma unroll
        for (int s = 0; s < 4; ++s) {
            float4 v0 = *(const float4*)(xr + s * 32);
            float4 v1 = *(const float4*)(xr + s * 32 + 4);
            us8 d;
            d[0] = f2bf(v0.x); d[1] = f2bf(v0.y); d[2] = f2bf(v0.z); d[3] = f2bf(v0.w);
            d[4] = f2bf(v1.x); d[5] = f2bf(v1.y); d[6] = f2bf(v1.z); d[7] = f2bf(v1.w);
            af[m][s] = *(bf16x8*)&d;
        }
    }

    const bf16x8* B1 = (const bf16x8*)wb1;
    const bf16x8* B2 = (const bf16x8*)wb2;
    const bf16x8* BP = (const bf16x8*)wpb;
    const f32x4 zero = {0.f, 0.f, 0.f, 0.f};

    // ---- Phase 1: GEMM1/2 + silu -> full H tile (16x256 per m) ----
#pragma unroll 2
    for (int nt = 0; nt < 16; ++nt) {
        bf16x8 b1[4], b2[4];
#pragma unroll
        for (int s = 0; s < 4; ++s) {
            b1[s] = B1[(nt * 4 + s) * 64 + l];
            b2[s] = B2[(nt * 4 + s) * 64 + l];
        }
#pragma unroll
        for (int m = 0; m < 2; ++m) {
            f32x4 a1 = zero, a2 = zero;
#pragma unroll
            for (int s = 0; s < 4; ++s) {
                a1 = __builtin_amdgcn_mfma_f32_16x16x32_bf16(af[m][s], b1[s], a1, 0, 0, 0);
                a2 = __builtin_amdgcn_mfma_f32_16x16x32_bf16(af[m][s], b2[s], a2, 0, 0, 0);
            }
#pragma unroll
            for (int i = 0; i < 4; ++i) {
                float g = a1[i];
                float hv = (g / (1.f + __expf(-g))) * a2[i];
                int r = 4 * lhi + i;
                int byte = (r << 9) + ((nt * 16 + llo) << 1);  // row stride 512B (256 bf16)
                byte ^= (r & 7) << 4;
                hs[wid][m][byte >> 1] = f2bf(hv);
            }
        }
    }

    // ---- Phase 2: GEMM3 over full K=256, per-nt3 accumulators + fused store ----
#pragma unroll 2
    for (int nt3 = 0; nt3 < 8; ++nt3) {
        f32x4 acc0 = zero, acc1 = zero;
#pragma unroll
        for (int sg = 0; sg < 8; ++sg) {
            bf16x8 bw = BP[(nt3 * 8 + sg) * 64 + l];
            int byte = (llo << 9) + (sg << 6) + (lhi << 4);
            byte ^= (llo & 7) << 4;
            bf16x8 h0 = *(const bf16x8*)((const char*)hs[wid][0] + byte);
            acc0 = __builtin_amdgcn_mfma_f32_16x16x32_bf16(h0, bw, acc0, 0, 0, 0);
            bf16x8 h1 = *(const bf16x8*)((const char*)hs[wid][1] + byte);
            acc1 = __builtin_amdgcn_mfma_f32_16x16x32_bf16(h1, bw, acc1, 0, 0, 0);
        }
        float bpv = bp[nt3 * 16 + llo];
        {
            const int row0 = mt0 * 16;
#pragma unroll
            for (int i = 0; i < 4; ++i) {
                int r = row0 + 4 * lhi + i;
                float v = acc0[i] + bpv;
                xp[(size_t)r * 128 + nt3 * 16 + llo] = v;
                xpb[(size_t)r * 128 + nt3 * 16 + llo] = f2bf(v);
            }
        }
        if (has1) {
            const int row0 = (mt0 + 1) * 16;
#pragma unroll
            for (int i = 0; i < 4; ++i) {
                int r = row0 + 4 * lhi + i;
                float v = acc1[i] + bpv;
                xp[(size_t)r * 128 + nt3 * 16 + llo] = v;
                xpb[(size_t)r * 128 + nt3 * 16 + llo] = f2bf(v);
            }
        }
    }
}

// ---------------- CSR build (by dst). in-deg == out-deg for this edge list ----------------
__global__ void k_hist(const int* __restrict__ ei, int E, int* __restrict__ cnt) {
    int e = blockIdx.x * blockDim.x + threadIdx.x;
    if (e < E) atomicAdd(&cnt[ei[E + e]], 1);      // histogram over dst
}

__global__ void __launch_bounds__(256)
k_scanA(const int* __restrict__ cnt, int N, int* __restrict__ bsum) {
    __shared__ int s[256];
    int t = threadIdx.x;
    int i = blockIdx.x * 256 + t;
    int v = (i < N) ? cnt[i] : 0;
    s[t] = v;
    __syncthreads();
#pragma unroll
    for (int d = 128; d > 0; d >>= 1) {
        if (t < d) s[t] += s[t + d];
        __syncthreads();
    }
    if (t == 0) bsum[blockIdx.x] = s[0];
}

__global__ void __launch_bounds__(1024)
k_scanB(const int* __restrict__ bsum, int NB, int* __restrict__ bpre,
        int* __restrict__ offN) {
    __shared__ int s[1024];
    int t = threadIdx.x;
    int v = (t < NB) ? bsum[t] : 0;
    s[t] = v;
    __syncthreads();
    for (int d = 1; d < 1024; d <<= 1) {
        int u = (t >= d) ? s[t - d] : 0;
        __syncthreads();
        s[t] += u;
        __syncthreads();
    }
    if (t < NB) bpre[t] = s[t] - v;          // exclusive
    if (t == NB - 1) *offN = s[t];           // total
}

__global__ void __launch_bounds__(256)
k_scanC(const int* __restrict__ cnt, int N, const int* __restrict__ bpre,
        int* __restrict__ off, int* __restrict__ cursor, float* __restrict__ bv) {
    __shared__ int s[256];
    int t = threadIdx.x;
    int i = blockIdx.x * 256 + t;
    int v = (i < N) ? cnt[i] : 0;
    s[t] = v;
    __syncthreads();
    for (int d = 1; d < 256; d <<= 1) {
        int u = (t >= d) ? s[t - d] : 0;
        __syncthreads();
        s[t] += u;
        __syncthreads();
    }
    if (i < N) {
        int excl = bpre[blockIdx.x] + s[t] - v;
        off[i] = excl;
        cursor[i] = excl;
        bv[i] = (v > 1) ? (-1.f / ((float)v - 1.f + EPSF)) : 0.f;
    }
}

__global__ void k_fill(const int* __restrict__ ei, int E,
                       int* __restrict__ cursor, int* __restrict__ csr) {
    int e = blockIdx.x * blockDim.x + threadIdx.x;
    if (e < E) {
        int s = ei[e], d = ei[E + e];
        int p = atomicAdd(&cursor[d], 1);
        csr[p] = s;
    }
}

// ---------------- fused gather + node passes (one wave per node, bf16 tables) ----------------
__global__ void __launch_bounds__(256)
k_passA(const float* __restrict__ xp, const ushort_t* __restrict__ xpb,
        const float* __restrict__ bv, const int* __restrict__ off,
        const int* __restrict__ csr, const float* __restrict__ tab,
        float* __restrict__ Xb, ushort_t* __restrict__ a1b, int N) {
    int tid = blockIdx.x * blockDim.x + threadIdx.x;
    int v = tid >> 6, l = tid & 63;
    if (v >= N) return;
    int beg = off[v], end = off[v + 1];
    float2 m0 = make_float2(0.f, 0.f), xb = make_float2(0.f, 0.f);
    const uint_t* tb = (const uint_t*)xpb;
    int k = beg;
    for (; k + 1 < end; k += 2) {
        int s0 = csr[k], s1 = csr[k + 1];
        uint_t u0 = tb[(size_t)s0 * 64 + l];
        uint_t u1 = tb[(size_t)s1 * 64 + l];
        float b0 = bv[s0], b1 = bv[s1];
        float2 t0 = bfu2(u0), t1v = bfu2(u1);
        m0.x += t0.x + t1v.x;        m0.y += t0.y + t1v.y;
        xb.x += b0 * t0.x + b1 * t1v.x;
        xb.y += b0 * t0.y + b1 * t1v.y;
    }
    if (k < end) {
        int s0 = csr[k];
        float2 t0 = bfu2(tb[(size_t)s0 * 64 + l]);
        float b0 = bv[s0];
        m0.x += t0.x; m0.y += t0.y;
        xb.x += b0 * t0.x; xb.y += b0 * t0.y;
    }
    size_t o = (size_t)v * 128 + 2 * l;
    *(float2*)&Xb[o] = xb;
    float2 xv = *(const float2*)&xp[o];
    int dg = end - beg;
    float L1r = tab[l], L1i = tab[64 + l], O1r = tab[128 + l], O1i = tab[192 + l];
    float Q = 1.f / ((float)dg - 1.f + EPSF);
    float2 t1 = cmul(O1r, O1i, xv);
    float2 t2 = cmul(L1r, L1i, m0);
    float2 a = make_float2(t1.x + Q * t2.x, t1.y + Q * t2.y);
    if (dg == 1) a = xv;
    ((uint_t*)a1b)[(size_t)v * 64 + l] = packbf(a);
}

__global__ void __launch_bounds__(256)
k_passB(const float* __restrict__ xp, const ushort_t* __restrict__ a1b,
        const float* __restrict__ bv, const int* __restrict__ off,
        const int* __restrict__ csr, const float* __restrict__ tab,
        float* __restrict__ Ab1, float* __restrict__ Bv, float* __restrict__ B2v,
        ushort_t* __restrict__ a2b, int N) {
    int tid = blockIdx.x * blockDim.x + threadIdx.x;
    int v = tid >> 6, l = tid & 63;
    if (v >= N) return;
    int beg = off[v], end = off[v + 1];
    float2 A1 = make_float2(0.f, 0.f), ab = make_float2(0.f, 0.f);
    float Bs = 0.f, B2s = 0.f;
    const uint_t* tb = (const uint_t*)a1b;
    int k = beg;
    for (; k + 1 < end; k += 2) {
        int s0 = csr[k], s1 = csr[k + 1];
        uint_t u0 = tb[(size_t)s0 * 64 + l];
        uint_t u1 = tb[(size_t)s1 * 64 + l];
        float b0 = bv[s0], b1 = bv[s1];
        float2 t0 = bfu2(u0), t1v = bfu2(u1);
        A1.x += t0.x + t1v.x;  A1.y += t0.y + t1v.y;
        ab.x += b0 * t0.x + b1 * t1v.x;
        ab.y += b0 * t0.y + b1 * t1v.y;
        Bs += b0 + b1; B2s += b0 * b0 + b1 * b1;
    }
    if (k < end) {
        int s0 = csr[k];
        float2 t0 = bfu2(tb[(size_t)s0 * 64 + l]);
        float b0 = bv[s0];
        A1.x += t0.x; A1.y += t0.y;
        ab.x += b0 * t0.x; ab.y += b0 * t0.y;
        Bs += b0; B2s += b0 * b0;
    }
    size_t o = (size_t)v * 128 + 2 * l;
    *(float2*)&Ab1[o] = ab;
    if (l == 0) { Bv[v] = Bs; B2v[v] = B2s; }
    float2 xv = *(const float2*)&xp[o];
    int dg = end - beg;
    float L1r = tab[l], L1i = tab[64 + l], O1r = tab[128 + l], O1i = tab[192 + l];
    float2 lx = cmul(L1r, L1i, xv);
    float2 m1 = make_float2(A1.x + Bs * lx.x, A1.y + Bs * lx.y);
    float Q = 1.f / ((float)dg - 1.f + EPSF);
    float2 t1 = cmul(O1r, O1i, xv);
    float2 lm = cmul(L1r, L1i, m1);
    float2 a = make_float2(t1.x + Q * lm.x, t1.y + Q * lm.y);
    if (dg == 1) a = xv;
    ((uint_t*)a2b)[(size_t)v * 64 + l] = packbf(a);
}

__global__ void __launch_bounds__(256)
k_passC(const float* __restrict__ xp, const ushort_t* __restrict__ a2b,
        const ushort_t* __restrict__ a1b, const float* __restrict__ Xb,
        const float* __restrict__ bv, const float* __restrict__ Bv,
        const int* __restrict__ off, const int* __restrict__ csr,
        const float* __restrict__ tab, ushort_t* __restrict__ a3b, int N) {
    int tid = blockIdx.x * blockDim.x + threadIdx.x;
    int v = tid >> 6, l = tid & 63;
    if (v >= N) return;
    int beg = off[v], end = off[v + 1];
    float2 A2 = make_float2(0.f, 0.f);
    const uint_t* tb = (const uint_t*)a2b;
    int k = beg;
    for (; k + 1 < end; k += 2) {
        int s0 = csr[k], s1 = csr[k + 1];
        float2 t0 = bfu2(tb[(size_t)s0 * 64 + l]);
        float2 t1v = bfu2(tb[(size_t)s1 * 64 + l]);
        A2.x += t0.x + t1v.x; A2.y += t0.y + t1v.y;
    }
    if (k < end) {
        float2 t0 = bfu2(tb[(size_t)csr[k] * 64 + l]);
        A2.x += t0.x; A2.y += t0.y;
    }
    size_t o = (size_t)v * 128 + 2 * l;
    float2 xv  = *(const float2*)&xp[o];
    float2 a1v = bfu2(((const uint_t*)a1b)[(size_t)v * 64 + l]);
    float2 Xbv = *(const float2*)&Xb[o];
    int dg = end - beg;
    float Bs = Bv[v], bs = bv[v];
    float L1r = tab[l], L1i = tab[64 + l], O1r = tab[128 + l], O1i = tab[192 + l];
    float L2r = tab[256 + l], L2i = tab[320 + l];
    float2 la1 = cmul(L1r, L1i, a1v);
    float2 lxb = cmul(L2r, L2i, Xbv);
    float2 m2 = make_float2(A2.x + Bs * la1.x + bs * lxb.x,
                            A2.y + Bs * la1.y + bs * lxb.y);
    float Q = 1.f / ((float)dg - 1.f + EPSF);
    float2 t1 = cmul(O1r, O1i, xv);
    float2 lm = cmul(L1r, L1i, m2);
    float2 a = make_float2(t1.x + Q * lm.x, t1.y + Q * lm.y);
    if (dg == 1) a = xv;
    ((uint_t*)a3b)[(size_t)v * 64 + l] = packbf(a);
}

__global__ void __launch_bounds__(256)
k_passD(const float* __restrict__ xin, const float* __restrict__ xp,
        const ushort_t* __restrict__ a3b, const ushort_t* __restrict__ a2b,
        const float* __restrict__ Ab1, const float* __restrict__ bv,
        const float* __restrict__ Bv, const float* __restrict__ B2v,
        const int* __restrict__ off, const int* __restrict__ csr,
        const float* __restrict__ tab, float* __restrict__ out, int N) {
    int tid = blockIdx.x * blockDim.x + threadIdx.x;
    int v = tid >> 6, l = tid & 63;
    if (v >= N) return;
    int beg = off[v], end = off[v + 1];
    float2 A3 = make_float2(0.f, 0.f);
    const uint_t* tb = (const uint_t*)a3b;
    int k = beg;
    for (; k + 1 < end; k += 2) {
        int s0 = csr[k], s1 = csr[k + 1];
        float2 t0 = bfu2(tb[(size_t)s0 * 64 + l]);
        float2 t1v = bfu2(tb[(size_t)s1 * 64 + l]);
        A3.x += t0.x + t1v.x; A3.y += t0.y + t1v.y;
    }
    if (k < end) {
        float2 t0 = bfu2(tb[(size_t)csr[k] * 64 + l]);
        A3.x += t0.x; A3.y += t0.y;
    }
    size_t o = (size_t)v * 128 + 2 * l;
    float2 xv  = *(const float2*)&xp[o];
    float2 a2v = bfu2(((const uint_t*)a2b)[(size_t)v * 64 + l]);
    float2 Abv = *(const float2*)&Ab1[o];
    int dg = end - beg;
    float Bs = Bv[v], bs = bv[v], B2s = B2v[v];
    float L1r = tab[l], L1i = tab[64 + l], O1r = tab[128 + l], O1i = tab[192 + l];
    float L2r = tab[256 + l], L2i = tab[320 + l];
    float L3r = tab[384 + l], L3i = tab[448 + l];
    float2 la2 = cmul(L1r, L1i, a2v);
    float2 lab = cmul(L2r, L2i, Abv);
    float2 lx3 = cmul(L3r, L3i, xv);
    float bB2 = bs * B2s;
    float2 m3 = make_float2(A3.x + Bs * la2.x + bs * lab.x + bB2 * lx3.x,
                            A3.y + Bs * la2.y + bs * lab.y + bB2 * lx3.y);
    float2 g;
    if (dg == 0) {
        g = xv;
    } else {
        float inv = 1.f / ((float)dg + EPSF);
        float2 t1 = cmul(O1r, O1i, xv);
        float2 lm = cmul(L1r, L1i, m3);
        g = make_float2(t1.x + lm.x * inv, t1.y + lm.y * inv);
    }
    float2 xi = *(const float2*)&xin[o];
    float2 res = make_float2(xi.x + fmaxf(g.x, 0.f), xi.y + fmaxf(g.y, 0.f));
    *(float2*)&out[o] = res;
}

extern "C" void kernel_launch(void* const* d_in, const int* in_sizes, int n_in,
                              void* d_out, int out_size, void* d_ws, size_t ws_size,
                              hipStream_t stream) {
    const float* x   = (const float*)d_in[0];
    const int*   ei  = (const int*)d_in[1];
    const float* ldt = (const float*)d_in[2];
    const float* llr = (const float*)d_in[3];
    const float* lim = (const float*)d_in[4];
    const float* W1  = (const float*)d_in[5];
    const float* W2  = (const float*)d_in[6];
    const float* Wp  = (const float*)d_in[7];
    const float* bp  = (const float*)d_in[8];
    float* out = (float*)d_out;

    const int N = in_sizes[0] / 128;
    const int E = in_sizes[1] / 2;
    const size_t nd = (size_t)N * 128;
    const int Mt = (N + 15) / 16;          // 16-row m-tiles
    const int Mt2 = (Mt + 1) / 2;          // m-tile pairs per wave
    const int NB = (N + 255) / 256;        // scan blocks

    float* ws  = (float*)d_ws;
    float* xp  = ws;                       // post-MLP x (f32, self-reads)
    float* Xb  = ws + nd;                  // f32
    float* ab1 = ws + 2 * nd;              // f32
    ushort_t* xpb = (ushort_t*)(ws + 3 * nd);  // bf16 gather tables
    ushort_t* a1b = xpb + nd;
    ushort_t* a2b = a1b + nd;
    ushort_t* a3b = a2b + nd;

    int*   cnt    = (int*)(a3b + nd);      // N
    int*   off    = cnt + N;               // N+4 (padded)
    int*   cursor = off + N + 4;           // N
    float* bv     = (float*)(cursor + N);  // N
    float* Bv     = bv + N;                // N
    float* B2v    = Bv + N;                // N
    float* tab    = B2v + N;               // 512
    int*   bsum   = (int*)(tab + 512);     // NB
    int*   bpre   = bsum + NB;             // NB
    int*   csr    = bpre + NB;             // E
    ushort_t* wb1 = (ushort_t*)(csr + E);  // 32768
    ushort_t* wb2 = wb1 + 32768;           // 32768
    ushort_t* wpb = wb2 + 32768;           // 32768

    const int nodeBlocks = (int)(((size_t)N * 64 + 255) / 256);
    const int eBlocks    = (E + 255) / 256;

    hipMemsetAsync(cnt, 0, (size_t)N * sizeof(int), stream);
    k_lamtab<<<1, 64, 0, stream>>>(ldt, llr, lim, tab);

    // bf16 weight prep + MFMA MLP (x converted in-kernel)
    k_prepw<<<16, 256, 0, stream>>>(W1, wb1, 256, 4, 16 * 4 * 64);
    k_prepw<<<16, 256, 0, stream>>>(W2, wb2, 256, 4, 16 * 4 * 64);
    k_prepw<<<16, 256, 0, stream>>>(Wp, wpb, 128, 8, 8 * 8 * 64);
    k_mlpf<<<(Mt2 + 3) / 4, 256, 0, stream>>>(x, wb1, wb2, wpb, bp, xp, xpb, Mt);

    // CSR build (hierarchical scan)
    k_hist<<<eBlocks, 256, 0, stream>>>(ei, E, cnt);
    k_scanA<<<NB, 256, 0, stream>>>(cnt, N, bsum);
    k_scanB<<<1, 1024, 0, stream>>>(bsum, NB, bpre, &off[N]);
    k_scanC<<<NB, 256, 0, stream>>>(cnt, N, bpre, off, cursor, bv);
    k_fill<<<eBlocks, 256, 0, stream>>>(ei, E, cursor, csr);

    // fused gather + node passes (bf16 message tables)
    k_passA<<<nodeBlocks, 256, 0, stream>>>(xp, xpb, bv, off, csr, tab, Xb, a1b, N);
    k_passB<<<nodeBlocks, 256, 0, stream>>>(xp, a1b, bv, off, csr, tab, ab1, Bv, B2v, a2b, N);
    k_passC<<<nodeBlocks, 256, 0, stream>>>(xp, a2b, a1b, Xb, bv, Bv, off, csr, tab, a3b, N);
    k_passD<<<nodeBlocks, 256, 0, stream>>>(x, xp, a3b, a2b, ab1, bv, Bv, B2v, off, csr, tab, out, N);
}

// Round 8
// 241.549 us; speedup vs baseline: 9.5933x; 1.0164x over previous
//
#include <hip/hip_runtime.h>

#define EPSF 1e-9f

typedef __bf16 bf16x8 __attribute__((ext_vector_type(8)));
typedef float  f32x4  __attribute__((ext_vector_type(4)));
typedef unsigned short ushort_t;
typedef unsigned int uint_t;
typedef ushort_t us8 __attribute__((ext_vector_type(8)));

__device__ __forceinline__ float2 cmul(float cr, float ci, float2 v) {
    return make_float2(cr * v.x - ci * v.y, ci * v.x + cr * v.y);
}

__device__ __forceinline__ ushort_t f2bf(float f) {
    unsigned int u = __float_as_uint(f);
    u += 0x7FFFu + ((u >> 16) & 1u);   // RNE
    return (ushort_t)(u >> 16);
}

// packed pair helpers: low 16 bits = element 2l, high = 2l+1
__device__ __forceinline__ float2 bfu2(uint_t u) {
    return make_float2(__uint_as_float(u << 16), __uint_as_float(u & 0xFFFF0000u));
}
__device__ __forceinline__ uint_t packbf(float2 v) {
    return ((uint_t)f2bf(v.y) << 16) | (uint_t)f2bf(v.x);
}

// ---------------- lambda tables: L1, O1(one-minus), L2, L3 ----------------
__global__ void k_lamtab(const float* __restrict__ ldt, const float* __restrict__ llr,
                         const float* __restrict__ lim, float* __restrict__ tab) {
    int p = threadIdx.x;
    if (p >= 64) return;
    float dt  = expf(ldt[0]);
    float mag = expf(-expf(llr[p]) * dt);
    float ph  = lim[p] * dt;
    float c = cosf(ph), s = sinf(ph);
    float m2 = mag * mag, m3 = m2 * mag;
    float c2 = c * c - s * s, s2 = 2.f * c * s;
    float c3 = c2 * c - s2 * s, s3 = s2 * c + c2 * s;
    tab[p]        = c * mag;          tab[64 + p]  = s * mag;          // L1
    tab[128 + p]  = c * (1.f - mag);  tab[192 + p] = s * (1.f - mag);  // O1
    tab[256 + p]  = c2 * m2;          tab[320 + p] = s2 * m2;          // L2
    tab[384 + p]  = c3 * m3;          tab[448 + p] = s3 * m3;          // L3
}

// ---------------- prep: W[K][ncols] -> bf16 B-fragment layout ----------------
__global__ void k_prepw(const float* __restrict__ w, ushort_t* __restrict__ wb,
                        int ncols, int nsteps, int total) {
    int tid = blockIdx.x * blockDim.x + threadIdx.x;
    if (tid >= total) return;
    int l  = tid & 63;
    int s  = (tid >> 6) % nsteps;
    int nt = tid / (64 * nsteps);
    int col = nt * 16 + (l & 15);
    int kb  = s * 32 + (l >> 4) * 8;
    us8 d;
#pragma unroll
    for (int j = 0; j < 8; ++j) d[j] = f2bf(w[(size_t)(kb + j) * ncols + col]);
    *(us8*)(wb + (size_t)tid * 8) = d;
}

// ---------------- MFMA fused MLP -> bf16 xpb only ----------------
// 4 waves/block, 2 m-tiles/wave (B-frag reuse). One 8KB H buffer per wave,
// time-shared: m0 H -> LDS, m1 H -> 32 packed uints (fully unrolled, const idx),
// phase2a (m0) -> unpack m1 -> phase2b (m1). LDS 32KB/block -> 4 blocks/CU.
__global__ void __launch_bounds__(256)
k_mlpf(const float* __restrict__ x, const ushort_t* __restrict__ wb1,
       const ushort_t* __restrict__ wb2, const ushort_t* __restrict__ wpb,
       const float* __restrict__ bp, ushort_t* __restrict__ xpb, int Mt) {
    __shared__ ushort_t hs[4][4096];   // 32KB total
    const int wid = threadIdx.x >> 6, l = threadIdx.x & 63;
    const int pair = blockIdx.x * 4 + wid;
    const int mt0 = pair * 2;
    if (mt0 >= Mt) return;
    const bool has1 = (mt0 + 1) < Mt;
    const int llo = l & 15, lhi = l >> 4;
    ushort_t* hw = hs[wid];

    // A fragments for both m-tiles (K=128 -> 4 ksteps)
    bf16x8 af[2][4];
#pragma unroll
    for (int m = 0; m < 2; ++m) {
        int mt = (m == 1 && !has1) ? mt0 : (mt0 + m);   // clamp tail
        const float* xr = x + (size_t)(mt * 16 + llo) * 128 + lhi * 8;
#pragma unroll
        for (int s = 0; s < 4; ++s) {
            float4 v0 = *(const float4*)(xr + s * 32);
            float4 v1 = *(const float4*)(xr + s * 32 + 4);
            us8 d;
            d[0] = f2bf(v0.x); d[1] = f2bf(v0.y); d[2] = f2bf(v0.z); d[3] = f2bf(v0.w);
            d[4] = f2bf(v1.x); d[5] = f2bf(v1.y); d[6] = f2bf(v1.z); d[7] = f2bf(v1.w);
            af[m][s] = *(bf16x8*)&d;
        }
    }

    const bf16x8* B1 = (const bf16x8*)wb1;
    const bf16x8* B2 = (const bf16x8*)wb2;
    const bf16x8* BP = (const bf16x8*)wpb;
    const f32x4 zero = {0.f, 0.f, 0.f, 0.f};

    // ---- Phase 1: GEMM1/2 + silu. m0 -> LDS, m1 -> packed regs ----
    uint_t hpk[32];
#pragma unroll
    for (int nt = 0; nt < 16; ++nt) {
        bf16x8 b1[4], b2[4];
#pragma unroll
        for (int s = 0; s < 4; ++s) {
            b1[s] = B1[(nt * 4 + s) * 64 + l];
            b2[s] = B2[(nt * 4 + s) * 64 + l];
        }
        {   // m0 -> LDS
            f32x4 a1 = zero, a2 = zero;
#pragma unroll
            for (int s = 0; s < 4; ++s) {
                a1 = __builtin_amdgcn_mfma_f32_16x16x32_bf16(af[0][s], b1[s], a1, 0, 0, 0);
                a2 = __builtin_amdgcn_mfma_f32_16x16x32_bf16(af[0][s], b2[s], a2, 0, 0, 0);
            }
#pragma unroll
            for (int i = 0; i < 4; ++i) {
                float g = a1[i];
                float hv = (g / (1.f + __expf(-g))) * a2[i];
                int r = 4 * lhi + i;
                int byte = (r << 9) + ((nt * 16 + llo) << 1);
                byte ^= (r & 7) << 4;
                hw[byte >> 1] = f2bf(hv);
            }
        }
        {   // m1 -> packed regs (const indices via full unroll)
            f32x4 a1 = zero, a2 = zero;
#pragma unroll
            for (int s = 0; s < 4; ++s) {
                a1 = __builtin_amdgcn_mfma_f32_16x16x32_bf16(af[1][s], b1[s], a1, 0, 0, 0);
                a2 = __builtin_amdgcn_mfma_f32_16x16x32_bf16(af[1][s], b2[s], a2, 0, 0, 0);
            }
#pragma unroll
            for (int p = 0; p < 2; ++p) {
                float g0 = a1[2 * p],     h0 = (g0 / (1.f + __expf(-g0))) * a2[2 * p];
                float g1 = a1[2 * p + 1], h1 = (g1 / (1.f + __expf(-g1))) * a2[2 * p + 1];
                hpk[nt * 2 + p] = ((uint_t)f2bf(h1) << 16) | (uint_t)f2bf(h0);
            }
        }
    }

    // ---- Phase 2a: GEMM3 for m0 ----
#pragma unroll 2
    for (int nt3 = 0; nt3 < 8; ++nt3) {
        f32x4 acc = zero;
#pragma unroll
        for (int sg = 0; sg < 8; ++sg) {
            bf16x8 bw = BP[(nt3 * 8 + sg) * 64 + l];
            int byte = (llo << 9) + (sg << 6) + (lhi << 4);
            byte ^= (llo & 7) << 4;
            bf16x8 h0 = *(const bf16x8*)((const char*)hw + byte);
            acc = __builtin_amdgcn_mfma_f32_16x16x32_bf16(h0, bw, acc, 0, 0, 0);
        }
        float bpv = bp[nt3 * 16 + llo];
        const int row0 = mt0 * 16;
#pragma unroll
        for (int i = 0; i < 4; ++i) {
            int r = row0 + 4 * lhi + i;
            xpb[(size_t)r * 128 + nt3 * 16 + llo] = f2bf(acc[i] + bpv);
        }
    }

    if (has1) {
        // unpack m1 H into the same buffer (compiler orders LDS RAW/WAR via waits)
#pragma unroll
        for (int nt = 0; nt < 16; ++nt) {
#pragma unroll
            for (int p = 0; p < 2; ++p) {
                uint_t u = hpk[nt * 2 + p];
                int r0 = 4 * lhi + 2 * p;
                int b0 = (r0 << 9) + ((nt * 16 + llo) << 1);
                b0 ^= (r0 & 7) << 4;
                hw[b0 >> 1] = (ushort_t)(u & 0xFFFFu);
                int r1 = r0 + 1;
                int b1_ = (r1 << 9) + ((nt * 16 + llo) << 1);
                b1_ ^= (r1 & 7) << 4;
                hw[b1_ >> 1] = (ushort_t)(u >> 16);
            }
        }
        // ---- Phase 2b: GEMM3 for m1 ----
#pragma unroll 2
        for (int nt3 = 0; nt3 < 8; ++nt3) {
            f32x4 acc = zero;
#pragma unroll
            for (int sg = 0; sg < 8; ++sg) {
                bf16x8 bw = BP[(nt3 * 8 + sg) * 64 + l];
                int byte = (llo << 9) + (sg << 6) + (lhi << 4);
                byte ^= (llo & 7) << 4;
                bf16x8 h1 = *(const bf16x8*)((const char*)hw + byte);
                acc = __builtin_amdgcn_mfma_f32_16x16x32_bf16(h1, bw, acc, 0, 0, 0);
            }
            float bpv = bp[nt3 * 16 + llo];
            const int row0 = (mt0 + 1) * 16;
#pragma unroll
            for (int i = 0; i < 4; ++i) {
                int r = row0 + 4 * lhi + i;
                xpb[(size_t)r * 128 + nt3 * 16 + llo] = f2bf(acc[i] + bpv);
            }
        }
    }
}

// ---------------- CSR build (by dst). in-deg == out-deg for this edge list ----------------
__global__ void k_hist(const int* __restrict__ ei, int E, int* __restrict__ cnt) {
    int e = blockIdx.x * blockDim.x + threadIdx.x;
    if (e < E) atomicAdd(&cnt[ei[E + e]], 1);      // histogram over dst
}

__global__ void __launch_bounds__(256)
k_scanA(const int* __restrict__ cnt, int N, int* __restrict__ bsum) {
    __shared__ int s[256];
    int t = threadIdx.x;
    int i = blockIdx.x * 256 + t;
    int v = (i < N) ? cnt[i] : 0;
    s[t] = v;
    __syncthreads();
#pragma unroll
    for (int d = 128; d > 0; d >>= 1) {
        if (t < d) s[t] += s[t + d];
        __syncthreads();
    }
    if (t == 0) bsum[blockIdx.x] = s[0];
}

__global__ void __launch_bounds__(1024)
k_scanB(const int* __restrict__ bsum, int NB, int* __restrict__ bpre,
        int* __restrict__ offN) {
    __shared__ int s[1024];
    int t = threadIdx.x;
    int v = (t < NB) ? bsum[t] : 0;
    s[t] = v;
    __syncthreads();
    for (int d = 1; d < 1024; d <<= 1) {
        int u = (t >= d) ? s[t - d] : 0;
        __syncthreads();
        s[t] += u;
        __syncthreads();
    }
    if (t < NB) bpre[t] = s[t] - v;          // exclusive
    if (t == NB - 1) *offN = s[t];           // total
}

__global__ void __launch_bounds__(256)
k_scanC(const int* __restrict__ cnt, int N, const int* __restrict__ bpre,
        int* __restrict__ off, int* __restrict__ cursor, float* __restrict__ bv) {
    __shared__ int s[256];
    int t = threadIdx.x;
    int i = blockIdx.x * 256 + t;
    int v = (i < N) ? cnt[i] : 0;
    s[t] = v;
    __syncthreads();
    for (int d = 1; d < 256; d <<= 1) {
        int u = (t >= d) ? s[t - d] : 0;
        __syncthreads();
        s[t] += u;
        __syncthreads();
    }
    if (i < N) {
        int excl = bpre[blockIdx.x] + s[t] - v;
        off[i] = excl;
        cursor[i] = excl;
        bv[i] = (v > 1) ? (-1.f / ((float)v - 1.f + EPSF)) : 0.f;
    }
}

__global__ void k_fill(const int* __restrict__ ei, int E,
                       int* __restrict__ cursor, int* __restrict__ csr) {
    int e = blockIdx.x * blockDim.x + threadIdx.x;
    if (e < E) {
        int s = ei[e], d = ei[E + e];
        int p = atomicAdd(&cursor[d], 1);
        csr[p] = s;
    }
}

// ---------------- fused gather + node passes (one wave per node, all-bf16 tables) ----------------
__global__ void __launch_bounds__(256)
k_passA(const ushort_t* __restrict__ xpb, const float* __restrict__ bv,
        const int* __restrict__ off, const int* __restrict__ csr,
        const float* __restrict__ tab, ushort_t* __restrict__ Xbb,
        ushort_t* __restrict__ a1b, int N) {
    int tid = blockIdx.x * blockDim.x + threadIdx.x;
    int v = tid >> 6, l = tid & 63;
    if (v >= N) return;
    int beg = off[v], end = off[v + 1];
    float2 m0 = make_float2(0.f, 0.f), xb = make_float2(0.f, 0.f);
    const uint_t* tb = (const uint_t*)xpb;
    int k = beg;
    for (; k + 1 < end; k += 2) {
        int s0 = csr[k], s1 = csr[k + 1];
        uint_t u0 = tb[(size_t)s0 * 64 + l];
        uint_t u1 = tb[(size_t)s1 * 64 + l];
        float b0 = bv[s0], b1 = bv[s1];
        float2 t0 = bfu2(u0), t1v = bfu2(u1);
        m0.x += t0.x + t1v.x;        m0.y += t0.y + t1v.y;
        xb.x += b0 * t0.x + b1 * t1v.x;
        xb.y += b0 * t0.y + b1 * t1v.y;
    }
    if (k < end) {
        int s0 = csr[k];
        float2 t0 = bfu2(tb[(size_t)s0 * 64 + l]);
        float b0 = bv[s0];
        m0.x += t0.x; m0.y += t0.y;
        xb.x += b0 * t0.x; xb.y += b0 * t0.y;
    }
    ((uint_t*)Xbb)[(size_t)v * 64 + l] = packbf(xb);
    float2 xv = bfu2(tb[(size_t)v * 64 + l]);
    int dg = end - beg;
    float L1r = tab[l], L1i = tab[64 + l], O1r = tab[128 + l], O1i = tab[192 + l];
    float Q = 1.f / ((float)dg - 1.f + EPSF);
    float2 t1 = cmul(O1r, O1i, xv);
    float2 t2 = cmul(L1r, L1i, m0);
    float2 a = make_float2(t1.x + Q * t2.x, t1.y + Q * t2.y);
    if (dg == 1) a = xv;
    ((uint_t*)a1b)[(size_t)v * 64 + l] = packbf(a);
}

__global__ void __launch_bounds__(256)
k_passB(const ushort_t* __restrict__ xpb, const ushort_t* __restrict__ a1b,
        const float* __restrict__ bv, const int* __restrict__ off,
        const int* __restrict__ csr, const float* __restrict__ tab,
        ushort_t* __restrict__ ab1b, float* __restrict__ Bv, float* __restrict__ B2v,
        ushort_t* __restrict__ a2b, int N) {
    int tid = blockIdx.x * blockDim.x + threadIdx.x;
    int v = tid >> 6, l = tid & 63;
    if (v >= N) return;
    int beg = off[v], end = off[v + 1];
    float2 A1 = make_float2(0.f, 0.f), ab = make_float2(0.f, 0.f);
    float Bs = 0.f, B2s = 0.f;
    const uint_t* tb = (const uint_t*)a1b;
    int k = beg;
    for (; k + 1 < end; k += 2) {
        int s0 = csr[k], s1 = csr[k + 1];
        uint_t u0 = tb[(size_t)s0 * 64 + l];
        uint_t u1 = tb[(size_t)s1 * 64 + l];
        float b0 = bv[s0], b1 = bv[s1];
        float2 t0 = bfu2(u0), t1v = bfu2(u1);
        A1.x += t0.x + t1v.x;  A1.y += t0.y + t1v.y;
        ab.x += b0 * t0.x + b1 * t1v.x;
        ab.y += b0 * t0.y + b1 * t1v.y;
        Bs += b0 + b1; B2s += b0 * b0 + b1 * b1;
    }
    if (k < end) {
        int s0 = csr[k];
        float2 t0 = bfu2(tb[(size_t)s0 * 64 + l]);
        float b0 = bv[s0];
        A1.x += t0.x; A1.y += t0.y;
        ab.x += b0 * t0.x; ab.y += b0 * t0.y;
        Bs += b0; B2s += b0 * b0;
    }
    ((uint_t*)ab1b)[(size_t)v * 64 + l] = packbf(ab);
    if (l == 0) { Bv[v] = Bs; B2v[v] = B2s; }
    float2 xv = bfu2(((const uint_t*)xpb)[(size_t)v * 64 + l]);
    int dg = end - beg;
    float L1r = tab[l], L1i = tab[64 + l], O1r = tab[128 + l], O1i = tab[192 + l];
    float2 lx = cmul(L1r, L1i, xv);
    float2 m1 = make_float2(A1.x + Bs * lx.x, A1.y + Bs * lx.y);
    float Q = 1.f / ((float)dg - 1.f + EPSF);
    float2 t1 = cmul(O1r, O1i, xv);
    float2 lm = cmul(L1r, L1i, m1);
    float2 a = make_float2(t1.x + Q * lm.x, t1.y + Q * lm.y);
    if (dg == 1) a = xv;
    ((uint_t*)a2b)[(size_t)v * 64 + l] = packbf(a);
}

__global__ void __launch_bounds__(256)
k_passC(const ushort_t* __restrict__ xpb, const ushort_t* __restrict__ a2b,
        const ushort_t* __restrict__ a1b, const ushort_t* __restrict__ Xbb,
        const float* __restrict__ bv, const float* __restrict__ Bv,
        const int* __restrict__ off, const int* __restrict__ csr,
        const float* __restrict__ tab, ushort_t* __restrict__ a3b, int N) {
    int tid = blockIdx.x * blockDim.x + threadIdx.x;
    int v = tid >> 6, l = tid & 63;
    if (v >= N) return;
    int beg = off[v], end = off[v + 1];
    float2 A2 = make_float2(0.f, 0.f);
    const uint_t* tb = (const uint_t*)a2b;
    int k = beg;
    for (; k + 1 < end; k += 2) {
        int s0 = csr[k], s1 = csr[k + 1];
        float2 t0 = bfu2(tb[(size_t)s0 * 64 + l]);
        float2 t1v = bfu2(tb[(size_t)s1 * 64 + l]);
        A2.x += t0.x + t1v.x; A2.y += t0.y + t1v.y;
    }
    if (k < end) {
        float2 t0 = bfu2(tb[(size_t)csr[k] * 64 + l]);
        A2.x += t0.x; A2.y += t0.y;
    }
    float2 xv  = bfu2(((const uint_t*)xpb)[(size_t)v * 64 + l]);
    float2 a1v = bfu2(((const uint_t*)a1b)[(size_t)v * 64 + l]);
    float2 Xbv = bfu2(((const uint_t*)Xbb)[(size_t)v * 64 + l]);
    int dg = end - beg;
    float Bs = Bv[v], bs = bv[v];
    float L1r = tab[l], L1i = tab[64 + l], O1r = tab[128 + l], O1i = tab[192 + l];
    float L2r = tab[256 + l], L2i = tab[320 + l];
    float2 la1 = cmul(L1r, L1i, a1v);
    float2 lxb = cmul(L2r, L2i, Xbv);
    float2 m2 = make_float2(A2.x + Bs * la1.x + bs * lxb.x,
                            A2.y + Bs * la1.y + bs * lxb.y);
    float Q = 1.f / ((float)dg - 1.f + EPSF);
    float2 t1 = cmul(O1r, O1i, xv);
    float2 lm = cmul(L1r, L1i, m2);
    float2 a = make_float2(t1.x + Q * lm.x, t1.y + Q * lm.y);
    if (dg == 1) a = xv;
    ((uint_t*)a3b)[(size_t)v * 64 + l] = packbf(a);
}

__global__ void __launch_bounds__(256)
k_passD(const float* __restrict__ xin, const ushort_t* __restrict__ xpb,
        const ushort_t* __restrict__ a3b, const ushort_t* __restrict__ a2b,
        const ushort_t* __restrict__ ab1b, const float* __restrict__ bv,
        const float* __restrict__ Bv, const float* __restrict__ B2v,
        const int* __restrict__ off, const int* __restrict__ csr,
        const float* __restrict__ tab, float* __restrict__ out, int N) {
    int tid = blockIdx.x * blockDim.x + threadIdx.x;
    int v = tid >> 6, l = tid & 63;
    if (v >= N) return;
    int beg = off[v], end = off[v + 1];
    float2 A3 = make_float2(0.f, 0.f);
    const uint_t* tb = (const uint_t*)a3b;
    int k = beg;
    for (; k + 1 < end; k += 2) {
        int s0 = csr[k], s1 = csr[k + 1];
        float2 t0 = bfu2(tb[(size_t)s0 * 64 + l]);
        float2 t1v = bfu2(tb[(size_t)s1 * 64 + l]);
        A3.x += t0.x + t1v.x; A3.y += t0.y + t1v.y;
    }
    if (k < end) {
        float2 t0 = bfu2(tb[(size_t)csr[k] * 64 + l]);
        A3.x += t0.x; A3.y += t0.y;
    }
    size_t o = (size_t)v * 128 + 2 * l;
    float2 xv  = bfu2(((const uint_t*)xpb)[(size_t)v * 64 + l]);
    float2 a2v = bfu2(((const uint_t*)a2b)[(size_t)v * 64 + l]);
    float2 Abv = bfu2(((const uint_t*)ab1b)[(size_t)v * 64 + l]);
    int dg = end - beg;
    float Bs = Bv[v], bs = bv[v], B2s = B2v[v];
    float L1r = tab[l], L1i = tab[64 + l], O1r = tab[128 + l], O1i = tab[192 + l];
    float L2r = tab[256 + l], L2i = tab[320 + l];
    float L3r = tab[384 + l], L3i = tab[448 + l];
    float2 la2 = cmul(L1r, L1i, a2v);
    float2 lab = cmul(L2r, L2i, Abv);
    float2 lx3 = cmul(L3r, L3i, xv);
    float bB2 = bs * B2s;
    float2 m3 = make_float2(A3.x + Bs * la2.x + bs * lab.x + bB2 * lx3.x,
                            A3.y + Bs * la2.y + bs * lab.y + bB2 * lx3.y);
    float2 g;
    if (dg == 0) {
        g = xv;
    } else {
        float inv = 1.f / ((float)dg + EPSF);
        float2 t1 = cmul(O1r, O1i, xv);
        float2 lm = cmul(L1r, L1i, m3);
        g = make_float2(t1.x + lm.x * inv, t1.y + lm.y * inv);
    }
    float2 xi = *(const float2*)&xin[o];
    float2 res = make_float2(xi.x + fmaxf(g.x, 0.f), xi.y + fmaxf(g.y, 0.f));
    *(float2*)&out[o] = res;
}

extern "C" void kernel_launch(void* const* d_in, const int* in_sizes, int n_in,
                              void* d_out, int out_size, void* d_ws, size_t ws_size,
                              hipStream_t stream) {
    const float* x   = (const float*)d_in[0];
    const int*   ei  = (const int*)d_in[1];
    const float* ldt = (const float*)d_in[2];
    const float* llr = (const float*)d_in[3];
    const float* lim = (const float*)d_in[4];
    const float* W1  = (const float*)d_in[5];
    const float* W2  = (const float*)d_in[6];
    const float* Wp  = (const float*)d_in[7];
    const float* bp  = (const float*)d_in[8];
    float* out = (float*)d_out;

    const int N = in_sizes[0] / 128;
    const int E = in_sizes[1] / 2;
    const size_t nd = (size_t)N * 128;
    const int Mt = (N + 15) / 16;          // 16-row m-tiles
    const int Mt2 = (Mt + 1) / 2;          // m-tile pairs per wave
    const int NB = (N + 255) / 256;        // scan blocks

    ushort_t* xpb  = (ushort_t*)d_ws;      // all-bf16 node tables
    ushort_t* a1b  = xpb + nd;
    ushort_t* a2b  = a1b + nd;
    ushort_t* a3b  = a2b + nd;
    ushort_t* Xbb  = a3b + nd;
    ushort_t* ab1b = Xbb + nd;

    int*   cnt    = (int*)(ab1b + nd);     // N
    int*   off    = cnt + N;               // N+4 (padded)
    int*   cursor = off + N + 4;           // N
    float* bv     = (float*)(cursor + N);  // N
    float* Bv     = bv + N;                // N
    float* B2v    = Bv + N;                // N
    float* tab    = B2v + N;               // 512
    int*   bsum   = (int*)(tab + 512);     // NB
    int*   bpre   = bsum + NB;             // NB
    int*   csr    = bpre + NB;             // E
    ushort_t* wb1 = (ushort_t*)(csr + E);  // 32768
    ushort_t* wb2 = wb1 + 32768;           // 32768
    ushort_t* wpb = wb2 + 32768;           // 32768

    const int nodeBlocks = (int)(((size_t)N * 64 + 255) / 256);
    const int eBlocks    = (E + 255) / 256;

    hipMemsetAsync(cnt, 0, (size_t)N * sizeof(int), stream);
    k_lamtab<<<1, 64, 0, stream>>>(ldt, llr, lim, tab);

    // bf16 weight prep + MFMA MLP (x converted in-kernel)
    k_prepw<<<16, 256, 0, stream>>>(W1, wb1, 256, 4, 16 * 4 * 64);
    k_prepw<<<16, 256, 0, stream>>>(W2, wb2, 256, 4, 16 * 4 * 64);
    k_prepw<<<16, 256, 0, stream>>>(Wp, wpb, 128, 8, 8 * 8 * 64);
    k_mlpf<<<(Mt2 + 3) / 4, 256, 0, stream>>>(x, wb1, wb2, wpb, bp, xpb, Mt);

    // CSR build (hierarchical scan)
    k_hist<<<eBlocks, 256, 0, stream>>>(ei, E, cnt);
    k_scanA<<<NB, 256, 0, stream>>>(cnt, N, bsum);
    k_scanB<<<1, 1024, 0, stream>>>(bsum, NB, bpre, &off[N]);
    k_scanC<<<NB, 256, 0, stream>>>(cnt, N, bpre, off, cursor, bv);
    k_fill<<<eBlocks, 256, 0, stream>>>(ei, E, cursor, csr);

    // fused gather + node passes (all-bf16 tables)
    k_passA<<<nodeBlocks, 256, 0, stream>>>(xpb, bv, off, csr, tab, Xbb, a1b, N);
    k_passB<<<nodeBlocks, 256, 0, stream>>>(xpb, a1b, bv, off, csr, tab, ab1b, Bv, B2v, a2b, N);
    k_passC<<<nodeBlocks, 256, 0, stream>>>(xpb, a2b, a1b, Xbb, bv, Bv, off, csr, tab, a3b, N);
    k_passD<<<nodeBlocks, 256, 0, stream>>>(x, xpb, a3b, a2b, ab1b, bv, Bv, B2v, off, csr, tab, out, N);
}

// Round 9
// 238.598 us; speedup vs baseline: 9.7119x; 1.0124x over previous
//
#include <hip/hip_runtime.h>

#define EPSF 1e-9f

typedef __bf16 bf16x8 __attribute__((ext_vector_type(8)));
typedef float  f32x4  __attribute__((ext_vector_type(4)));
typedef unsigned short ushort_t;
typedef unsigned int uint_t;
typedef ushort_t us8 __attribute__((ext_vector_type(8)));

__device__ __forceinline__ float2 cmul(float cr, float ci, float2 v) {
    return make_float2(cr * v.x - ci * v.y, ci * v.x + cr * v.y);
}

__device__ __forceinline__ ushort_t f2bf(float f) {
    unsigned int u = __float_as_uint(f);
    u += 0x7FFFu + ((u >> 16) & 1u);   // RNE
    return (ushort_t)(u >> 16);
}

// packed pair helpers: low 16 bits = element 2l, high = 2l+1
__device__ __forceinline__ float2 bfu2(uint_t u) {
    return make_float2(__uint_as_float(u << 16), __uint_as_float(u & 0xFFFF0000u));
}
__device__ __forceinline__ uint_t packbf(float2 v) {
    return ((uint_t)f2bf(v.y) << 16) | (uint_t)f2bf(v.x);
}

// ---------------- lambda tables: L1, O1(one-minus), L2, L3 ----------------
__global__ void k_lamtab(const float* __restrict__ ldt, const float* __restrict__ llr,
                         const float* __restrict__ lim, float* __restrict__ tab) {
    int p = threadIdx.x;
    if (p >= 64) return;
    float dt  = expf(ldt[0]);
    float mag = expf(-expf(llr[p]) * dt);
    float ph  = lim[p] * dt;
    float c = cosf(ph), s = sinf(ph);
    float m2 = mag * mag, m3 = m2 * mag;
    float c2 = c * c - s * s, s2 = 2.f * c * s;
    float c3 = c2 * c - s2 * s, s3 = s2 * c + c2 * s;
    tab[p]        = c * mag;          tab[64 + p]  = s * mag;          // L1
    tab[128 + p]  = c * (1.f - mag);  tab[192 + p] = s * (1.f - mag);  // O1
    tab[256 + p]  = c2 * m2;          tab[320 + p] = s2 * m2;          // L2
    tab[384 + p]  = c3 * m3;          tab[448 + p] = s3 * m3;          // L3
}

// ---------------- prep: W[K][ncols] -> bf16 B-fragment layout ----------------
__global__ void k_prepw(const float* __restrict__ w, ushort_t* __restrict__ wb,
                        int ncols, int nsteps, int total) {
    int tid = blockIdx.x * blockDim.x + threadIdx.x;
    if (tid >= total) return;
    int l  = tid & 63;
    int s  = (tid >> 6) % nsteps;
    int nt = tid / (64 * nsteps);
    int col = nt * 16 + (l & 15);
    int kb  = s * 32 + (l >> 4) * 8;
    us8 d;
#pragma unroll
    for (int j = 0; j < 8; ++j) d[j] = f2bf(w[(size_t)(kb + j) * ncols + col]);
    *(us8*)(wb + (size_t)tid * 8) = d;
}

// ---------------- MFMA fused MLP -> bf16 xpb (round-7 structure, bf16-only store) ----------------
__global__ void __launch_bounds__(256)
k_mlpf(const float* __restrict__ x, const ushort_t* __restrict__ wb1,
       const ushort_t* __restrict__ wb2, const ushort_t* __restrict__ wpb,
       const float* __restrict__ bp, ushort_t* __restrict__ xpb, int Mt) {
    __shared__ ushort_t hs[4][2][4096];   // 64KB: per-wave, per-mtile 16x256 bf16 H (swizzled)
    const int wid = threadIdx.x >> 6, l = threadIdx.x & 63;
    const int pair = blockIdx.x * 4 + wid;
    const int mt0 = pair * 2;
    if (mt0 >= Mt) return;
    const bool has1 = (mt0 + 1) < Mt;
    const int llo = l & 15, lhi = l >> 4;

    // A fragments for both m-tiles (K=128 -> 4 ksteps)
    bf16x8 af[2][4];
#pragma unroll
    for (int m = 0; m < 2; ++m) {
        int mt = (m == 1 && !has1) ? mt0 : (mt0 + m);   // clamp tail
        const float* xr = x + (size_t)(mt * 16 + llo) * 128 + lhi * 8;
#pragma unroll
        for (int s = 0; s < 4; ++s) {
            float4 v0 = *(const float4*)(xr + s * 32);
            float4 v1 = *(const float4*)(xr + s * 32 + 4);
            us8 d;
            d[0] = f2bf(v0.x); d[1] = f2bf(v0.y); d[2] = f2bf(v0.z); d[3] = f2bf(v0.w);
            d[4] = f2bf(v1.x); d[5] = f2bf(v1.y); d[6] = f2bf(v1.z); d[7] = f2bf(v1.w);
            af[m][s] = *(bf16x8*)&d;
        }
    }

    const bf16x8* B1 = (const bf16x8*)wb1;
    const bf16x8* B2 = (const bf16x8*)wb2;
    const bf16x8* BP = (const bf16x8*)wpb;
    const f32x4 zero = {0.f, 0.f, 0.f, 0.f};

    // ---- Phase 1: GEMM1/2 + silu -> full H tiles (16x256 per m) ----
#pragma unroll 2
    for (int nt = 0; nt < 16; ++nt) {
        bf16x8 b1[4], b2[4];
#pragma unroll
        for (int s = 0; s < 4; ++s) {
            b1[s] = B1[(nt * 4 + s) * 64 + l];
            b2[s] = B2[(nt * 4 + s) * 64 + l];
        }
#pragma unroll
        for (int m = 0; m < 2; ++m) {
            f32x4 a1 = zero, a2 = zero;
#pragma unroll
            for (int s = 0; s < 4; ++s) {
                a1 = __builtin_amdgcn_mfma_f32_16x16x32_bf16(af[m][s], b1[s], a1, 0, 0, 0);
                a2 = __builtin_amdgcn_mfma_f32_16x16x32_bf16(af[m][s], b2[s], a2, 0, 0, 0);
            }
#pragma unroll
            for (int i = 0; i < 4; ++i) {
                float g = a1[i];
                float hv = (g / (1.f + __expf(-g))) * a2[i];
                int r = 4 * lhi + i;
                int byte = (r << 9) + ((nt * 16 + llo) << 1);  // row stride 512B (256 bf16)
                byte ^= (r & 7) << 4;
                hs[wid][m][byte >> 1] = f2bf(hv);
            }
        }
    }

    // ---- Phase 2: GEMM3 over full K=256, per-nt3 accumulators + fused bf16 store ----
#pragma unroll 2
    for (int nt3 = 0; nt3 < 8; ++nt3) {
        f32x4 acc0 = zero, acc1 = zero;
#pragma unroll
        for (int sg = 0; sg < 8; ++sg) {
            bf16x8 bw = BP[(nt3 * 8 + sg) * 64 + l];
            int byte = (llo << 9) + (sg << 6) + (lhi << 4);
            byte ^= (llo & 7) << 4;
            bf16x8 h0 = *(const bf16x8*)((const char*)hs[wid][0] + byte);
            acc0 = __builtin_amdgcn_mfma_f32_16x16x32_bf16(h0, bw, acc0, 0, 0, 0);
            bf16x8 h1 = *(const bf16x8*)((const char*)hs[wid][1] + byte);
            acc1 = __builtin_amdgcn_mfma_f32_16x16x32_bf16(h1, bw, acc1, 0, 0, 0);
        }
        float bpv = bp[nt3 * 16 + llo];
        {
            const int row0 = mt0 * 16;
#pragma unroll
            for (int i = 0; i < 4; ++i) {
                int r = row0 + 4 * lhi + i;
                xpb[(size_t)r * 128 + nt3 * 16 + llo] = f2bf(acc0[i] + bpv);
            }
        }
        if (has1) {
            const int row0 = (mt0 + 1) * 16;
#pragma unroll
            for (int i = 0; i < 4; ++i) {
                int r = row0 + 4 * lhi + i;
                xpb[(size_t)r * 128 + nt3 * 16 + llo] = f2bf(acc1[i] + bpv);
            }
        }
    }
}

// ---------------- CSR build (by dst). in-deg == out-deg for this edge list ----------------
__global__ void k_hist(const int* __restrict__ ei, int E, int* __restrict__ cnt) {
    int e = blockIdx.x * blockDim.x + threadIdx.x;
    if (e < E) atomicAdd(&cnt[ei[E + e]], 1);      // histogram over dst
}

__global__ void __launch_bounds__(256)
k_scanA(const int* __restrict__ cnt, int N, int* __restrict__ bsum) {
    __shared__ int s[256];
    int t = threadIdx.x;
    int i = blockIdx.x * 256 + t;
    int v = (i < N) ? cnt[i] : 0;
    s[t] = v;
    __syncthreads();
#pragma unroll
    for (int d = 128; d > 0; d >>= 1) {
        if (t < d) s[t] += s[t + d];
        __syncthreads();
    }
    if (t == 0) bsum[blockIdx.x] = s[0];
}

__global__ void __launch_bounds__(1024)
k_scanB(const int* __restrict__ bsum, int NB, int* __restrict__ bpre,
        int* __restrict__ offN) {
    __shared__ int s[1024];
    int t = threadIdx.x;
    int v = (t < NB) ? bsum[t] : 0;
    s[t] = v;
    __syncthreads();
    for (int d = 1; d < 1024; d <<= 1) {
        int u = (t >= d) ? s[t - d] : 0;
        __syncthreads();
        s[t] += u;
        __syncthreads();
    }
    if (t < NB) bpre[t] = s[t] - v;          // exclusive
    if (t == NB - 1) *offN = s[t];           // total
}

__global__ void __launch_bounds__(256)
k_scanC(const int* __restrict__ cnt, int N, const int* __restrict__ bpre,
        int* __restrict__ off, int* __restrict__ cursor, float* __restrict__ bv) {
    __shared__ int s[256];
    int t = threadIdx.x;
    int i = blockIdx.x * 256 + t;
    int v = (i < N) ? cnt[i] : 0;
    s[t] = v;
    __syncthreads();
    for (int d = 1; d < 256; d <<= 1) {
        int u = (t >= d) ? s[t - d] : 0;
        __syncthreads();
        s[t] += u;
        __syncthreads();
    }
    if (i < N) {
        int excl = bpre[blockIdx.x] + s[t] - v;
        off[i] = excl;
        cursor[i] = excl;
        bv[i] = (v > 1) ? (-1.f / ((float)v - 1.f + EPSF)) : 0.f;
    }
}

__global__ void k_fill(const int* __restrict__ ei, int E,
                       int* __restrict__ cursor, int* __restrict__ csr) {
    int e = blockIdx.x * blockDim.x + threadIdx.x;
    if (e < E) {
        int s = ei[e], d = ei[E + e];
        int p = atomicAdd(&cursor[d], 1);
        csr[p] = s;
    }
}

// ---------------- fused gather + node passes (one wave per node, all-bf16 tables) ----------------
__global__ void __launch_bounds__(256)
k_passA(const ushort_t* __restrict__ xpb, const float* __restrict__ bv,
        const int* __restrict__ off, const int* __restrict__ csr,
        const float* __restrict__ tab, ushort_t* __restrict__ Xbb,
        ushort_t* __restrict__ a1b, int N) {
    int tid = blockIdx.x * blockDim.x + threadIdx.x;
    int v = tid >> 6, l = tid & 63;
    if (v >= N) return;
    int beg = off[v], end = off[v + 1];
    float2 m0 = make_float2(0.f, 0.f), xb = make_float2(0.f, 0.f);
    const uint_t* tb = (const uint_t*)xpb;
    int k = beg;
    for (; k + 1 < end; k += 2) {
        int s0 = csr[k], s1 = csr[k + 1];
        uint_t u0 = tb[(size_t)s0 * 64 + l];
        uint_t u1 = tb[(size_t)s1 * 64 + l];
        float b0 = bv[s0], b1 = bv[s1];
        float2 t0 = bfu2(u0), t1v = bfu2(u1);
        m0.x += t0.x + t1v.x;        m0.y += t0.y + t1v.y;
        xb.x += b0 * t0.x + b1 * t1v.x;
        xb.y += b0 * t0.y + b1 * t1v.y;
    }
    if (k < end) {
        int s0 = csr[k];
        float2 t0 = bfu2(tb[(size_t)s0 * 64 + l]);
        float b0 = bv[s0];
        m0.x += t0.x; m0.y += t0.y;
        xb.x += b0 * t0.x; xb.y += b0 * t0.y;
    }
    ((uint_t*)Xbb)[(size_t)v * 64 + l] = packbf(xb);
    float2 xv = bfu2(tb[(size_t)v * 64 + l]);
    int dg = end - beg;
    float L1r = tab[l], L1i = tab[64 + l], O1r = tab[128 + l], O1i = tab[192 + l];
    float Q = 1.f / ((float)dg - 1.f + EPSF);
    float2 t1 = cmul(O1r, O1i, xv);
    float2 t2 = cmul(L1r, L1i, m0);
    float2 a = make_float2(t1.x + Q * t2.x, t1.y + Q * t2.y);
    if (dg == 1) a = xv;
    ((uint_t*)a1b)[(size_t)v * 64 + l] = packbf(a);
}

__global__ void __launch_bounds__(256)
k_passB(const ushort_t* __restrict__ xpb, const ushort_t* __restrict__ a1b,
        const float* __restrict__ bv, const int* __restrict__ off,
        const int* __restrict__ csr, const float* __restrict__ tab,
        ushort_t* __restrict__ ab1b, float* __restrict__ Bv, float* __restrict__ B2v,
        ushort_t* __restrict__ a2b, int N) {
    int tid = blockIdx.x * blockDim.x + threadIdx.x;
    int v = tid >> 6, l = tid & 63;
    if (v >= N) return;
    int beg = off[v], end = off[v + 1];
    float2 A1 = make_float2(0.f, 0.f), ab = make_float2(0.f, 0.f);
    float Bs = 0.f, B2s = 0.f;
    const uint_t* tb = (const uint_t*)a1b;
    int k = beg;
    for (; k + 1 < end; k += 2) {
        int s0 = csr[k], s1 = csr[k + 1];
        uint_t u0 = tb[(size_t)s0 * 64 + l];
        uint_t u1 = tb[(size_t)s1 * 64 + l];
        float b0 = bv[s0], b1 = bv[s1];
        float2 t0 = bfu2(u0), t1v = bfu2(u1);
        A1.x += t0.x + t1v.x;  A1.y += t0.y + t1v.y;
        ab.x += b0 * t0.x + b1 * t1v.x;
        ab.y += b0 * t0.y + b1 * t1v.y;
        Bs += b0 + b1; B2s += b0 * b0 + b1 * b1;
    }
    if (k < end) {
        int s0 = csr[k];
        float2 t0 = bfu2(tb[(size_t)s0 * 64 + l]);
        float b0 = bv[s0];
        A1.x += t0.x; A1.y += t0.y;
        ab.x += b0 * t0.x; ab.y += b0 * t0.y;
        Bs += b0; B2s += b0 * b0;
    }
    ((uint_t*)ab1b)[(size_t)v * 64 + l] = packbf(ab);
    if (l == 0) { Bv[v] = Bs; B2v[v] = B2s; }
    float2 xv = bfu2(((const uint_t*)xpb)[(size_t)v * 64 + l]);
    int dg = end - beg;
    float L1r = tab[l], L1i = tab[64 + l], O1r = tab[128 + l], O1i = tab[192 + l];
    float2 lx = cmul(L1r, L1i, xv);
    float2 m1 = make_float2(A1.x + Bs * lx.x, A1.y + Bs * lx.y);
    float Q = 1.f / ((float)dg - 1.f + EPSF);
    float2 t1 = cmul(O1r, O1i, xv);
    float2 lm = cmul(L1r, L1i, m1);
    float2 a = make_float2(t1.x + Q * lm.x, t1.y + Q * lm.y);
    if (dg == 1) a = xv;
    ((uint_t*)a2b)[(size_t)v * 64 + l] = packbf(a);
}

__global__ void __launch_bounds__(256)
k_passC(const ushort_t* __restrict__ xpb, const ushort_t* __restrict__ a2b,
        const ushort_t* __restrict__ a1b, const ushort_t* __restrict__ Xbb,
        const float* __restrict__ bv, const float* __restrict__ Bv,
        const int* __restrict__ off, const int* __restrict__ csr,
        const float* __restrict__ tab, ushort_t* __restrict__ a3b, int N) {
    int tid = blockIdx.x * blockDim.x + threadIdx.x;
    int v = tid >> 6, l = tid & 63;
    if (v >= N) return;
    int beg = off[v], end = off[v + 1];
    float2 A2 = make_float2(0.f, 0.f);
    const uint_t* tb = (const uint_t*)a2b;
    int k = beg;
    for (; k + 1 < end; k += 2) {
        int s0 = csr[k], s1 = csr[k + 1];
        float2 t0 = bfu2(tb[(size_t)s0 * 64 + l]);
        float2 t1v = bfu2(tb[(size_t)s1 * 64 + l]);
        A2.x += t0.x + t1v.x; A2.y += t0.y + t1v.y;
    }
    if (k < end) {
        float2 t0 = bfu2(tb[(size_t)csr[k] * 64 + l]);
        A2.x += t0.x; A2.y += t0.y;
    }
    float2 xv  = bfu2(((const uint_t*)xpb)[(size_t)v * 64 + l]);
    float2 a1v = bfu2(((const uint_t*)a1b)[(size_t)v * 64 + l]);
    float2 Xbv = bfu2(((const uint_t*)Xbb)[(size_t)v * 64 + l]);
    int dg = end - beg;
    float Bs = Bv[v], bs = bv[v];
    float L1r = tab[l], L1i = tab[64 + l], O1r = tab[128 + l], O1i = tab[192 + l];
    float L2r = tab[256 + l], L2i = tab[320 + l];
    float2 la1 = cmul(L1r, L1i, a1v);
    float2 lxb = cmul(L2r, L2i, Xbv);
    float2 m2 = make_float2(A2.x + Bs * la1.x + bs * lxb.x,
                            A2.y + Bs * la1.y + bs * lxb.y);
    float Q = 1.f / ((float)dg - 1.f + EPSF);
    float2 t1 = cmul(O1r, O1i, xv);
    float2 lm = cmul(L1r, L1i, m2);
    float2 a = make_float2(t1.x + Q * lm.x, t1.y + Q * lm.y);
    if (dg == 1) a = xv;
    ((uint_t*)a3b)[(size_t)v * 64 + l] = packbf(a);
}

__global__ void __launch_bounds__(256)
k_passD(const float* __restrict__ xin, const ushort_t* __restrict__ xpb,
        const ushort_t* __restrict__ a3b, const ushort_t* __restrict__ a2b,
        const ushort_t* __restrict__ ab1b, const float* __restrict__ bv,
        const float* __restrict__ Bv, const float* __restrict__ B2v,
        const int* __restrict__ off, const int* __restrict__ csr,
        const float* __restrict__ tab, float* __restrict__ out, int N) {
    int tid = blockIdx.x * blockDim.x + threadIdx.x;
    int v = tid >> 6, l = tid & 63;
    if (v >= N) return;
    int beg = off[v], end = off[v + 1];
    float2 A3 = make_float2(0.f, 0.f);
    const uint_t* tb = (const uint_t*)a3b;
    int k = beg;
    for (; k + 1 < end; k += 2) {
        int s0 = csr[k], s1 = csr[k + 1];
        float2 t0 = bfu2(tb[(size_t)s0 * 64 + l]);
        float2 t1v = bfu2(tb[(size_t)s1 * 64 + l]);
        A3.x += t0.x + t1v.x; A3.y += t0.y + t1v.y;
    }
    if (k < end) {
        float2 t0 = bfu2(tb[(size_t)csr[k] * 64 + l]);
        A3.x += t0.x; A3.y += t0.y;
    }
    size_t o = (size_t)v * 128 + 2 * l;
    float2 xv  = bfu2(((const uint_t*)xpb)[(size_t)v * 64 + l]);
    float2 a2v = bfu2(((const uint_t*)a2b)[(size_t)v * 64 + l]);
    float2 Abv = bfu2(((const uint_t*)ab1b)[(size_t)v * 64 + l]);
    int dg = end - beg;
    float Bs = Bv[v], bs = bv[v], B2s = B2v[v];
    float L1r = tab[l], L1i = tab[64 + l], O1r = tab[128 + l], O1i = tab[192 + l];
    float L2r = tab[256 + l], L2i = tab[320 + l];
    float L3r = tab[384 + l], L3i = tab[448 + l];
    float2 la2 = cmul(L1r, L1i, a2v);
    float2 lab = cmul(L2r, L2i, Abv);
    float2 lx3 = cmul(L3r, L3i, xv);
    float bB2 = bs * B2s;
    float2 m3 = make_float2(A3.x + Bs * la2.x + bs * lab.x + bB2 * lx3.x,
                            A3.y + Bs * la2.y + bs * lab.y + bB2 * lx3.y);
    float2 g;
    if (dg == 0) {
        g = xv;
    } else {
        float inv = 1.f / ((float)dg + EPSF);
        float2 t1 = cmul(O1r, O1i, xv);
        float2 lm = cmul(L1r, L1i, m3);
        g = make_float2(t1.x + lm.x * inv, t1.y + lm.y * inv);
    }
    float2 xi = *(const float2*)&xin[o];
    float2 res = make_float2(xi.x + fmaxf(g.x, 0.f), xi.y + fmaxf(g.y, 0.f));
    *(float2*)&out[o] = res;
}

extern "C" void kernel_launch(void* const* d_in, const int* in_sizes, int n_in,
                              void* d_out, int out_size, void* d_ws, size_t ws_size,
                              hipStream_t stream) {
    const float* x   = (const float*)d_in[0];
    const int*   ei  = (const int*)d_in[1];
    const float* ldt = (const float*)d_in[2];
    const float* llr = (const float*)d_in[3];
    const float* lim = (const float*)d_in[4];
    const float* W1  = (const float*)d_in[5];
    const float* W2  = (const float*)d_in[6];
    const float* Wp  = (const float*)d_in[7];
    const float* bp  = (const float*)d_in[8];
    float* out = (float*)d_out;

    const int N = in_sizes[0] / 128;
    const int E = in_sizes[1] / 2;
    const size_t nd = (size_t)N * 128;
    const int Mt = (N + 15) / 16;          // 16-row m-tiles
    const int Mt2 = (Mt + 1) / 2;          // m-tile pairs per wave
    const int NB = (N + 255) / 256;        // scan blocks

    ushort_t* xpb  = (ushort_t*)d_ws;      // all-bf16 node tables
    ushort_t* a1b  = xpb + nd;
    ushort_t* a2b  = a1b + nd;
    ushort_t* a3b  = a2b + nd;
    ushort_t* Xbb  = a3b + nd;
    ushort_t* ab1b = Xbb + nd;

    int*   cnt    = (int*)(ab1b + nd);     // N
    int*   off    = cnt + N;               // N+4 (padded)
    int*   cursor = off + N + 4;           // N
    float* bv     = (float*)(cursor + N);  // N
    float* Bv     = bv + N;                // N
    float* B2v    = Bv + N;                // N
    float* tab    = B2v + N;               // 512
    int*   bsum   = (int*)(tab + 512);     // NB
    int*   bpre   = bsum + NB;             // NB
    int*   csr    = bpre + NB;             // E
    ushort_t* wb1 = (ushort_t*)(csr + E);  // 32768
    ushort_t* wb2 = wb1 + 32768;           // 32768
    ushort_t* wpb = wb2 + 32768;           // 32768

    const int nodeBlocks = (int)(((size_t)N * 64 + 255) / 256);
    const int eBlocks    = (E + 255) / 256;

    hipMemsetAsync(cnt, 0, (size_t)N * sizeof(int), stream);
    k_lamtab<<<1, 64, 0, stream>>>(ldt, llr, lim, tab);

    // bf16 weight prep + MFMA MLP (x converted in-kernel)
    k_prepw<<<16, 256, 0, stream>>>(W1, wb1, 256, 4, 16 * 4 * 64);
    k_prepw<<<16, 256, 0, stream>>>(W2, wb2, 256, 4, 16 * 4 * 64);
    k_prepw<<<16, 256, 0, stream>>>(Wp, wpb, 128, 8, 8 * 8 * 64);
    k_mlpf<<<(Mt2 + 3) / 4, 256, 0, stream>>>(x, wb1, wb2, wpb, bp, xpb, Mt);

    // CSR build (hierarchical scan)
    k_hist<<<eBlocks, 256, 0, stream>>>(ei, E, cnt);
    k_scanA<<<NB, 256, 0, stream>>>(cnt, N, bsum);
    k_scanB<<<1, 1024, 0, stream>>>(bsum, NB, bpre, &off[N]);
    k_scanC<<<NB, 256, 0, stream>>>(cnt, N, bpre, off, cursor, bv);
    k_fill<<<eBlocks, 256, 0, stream>>>(ei, E, cursor, csr);

    // fused gather + node passes (all-bf16 tables)
    k_passA<<<nodeBlocks, 256, 0, stream>>>(xpb, bv, off, csr, tab, Xbb, a1b, N);
    k_passB<<<nodeBlocks, 256, 0, stream>>>(xpb, a1b, bv, off, csr, tab, ab1b, Bv, B2v, a2b, N);
    k_passC<<<nodeBlocks, 256, 0, stream>>>(xpb, a2b, a1b, Xbb, bv, Bv, off, csr, tab, a3b, N);
    k_passD<<<nodeBlocks, 256, 0, stream>>>(x, xpb, a3b, a2b, ab1b, bv, Bv, B2v, off, csr, tab, out, N);
}

// Round 10
// 236.885 us; speedup vs baseline: 9.7821x; 1.0072x over previous
//
#include <hip/hip_runtime.h>

#define EPSF 1e-9f

typedef __bf16 bf16x8 __attribute__((ext_vector_type(8)));
typedef float  f32x4  __attribute__((ext_vector_type(4)));
typedef unsigned short ushort_t;
typedef unsigned int uint_t;
typedef ushort_t us8 __attribute__((ext_vector_type(8)));

__device__ __forceinline__ float2 cmul(float cr, float ci, float2 v) {
    return make_float2(cr * v.x - ci * v.y, ci * v.x + cr * v.y);
}

__device__ __forceinline__ ushort_t f2bf(float f) {
    unsigned int u = __float_as_uint(f);
    u += 0x7FFFu + ((u >> 16) & 1u);   // RNE
    return (ushort_t)(u >> 16);
}

// packed pair helpers: low 16 bits = element 2l, high = 2l+1
__device__ __forceinline__ float2 bfu2(uint_t u) {
    return make_float2(__uint_as_float(u << 16), __uint_as_float(u & 0xFFFF0000u));
}
__device__ __forceinline__ uint_t packbf(float2 v) {
    return ((uint_t)f2bf(v.y) << 16) | (uint_t)f2bf(v.x);
}

// ---------------- lambda tables: L1, O1(one-minus), L2, L3 ----------------
__global__ void k_lamtab(const float* __restrict__ ldt, const float* __restrict__ llr,
                         const float* __restrict__ lim, float* __restrict__ tab) {
    int p = threadIdx.x;
    if (p >= 64) return;
    float dt  = expf(ldt[0]);
    float mag = expf(-expf(llr[p]) * dt);
    float ph  = lim[p] * dt;
    float c = cosf(ph), s = sinf(ph);
    float m2 = mag * mag, m3 = m2 * mag;
    float c2 = c * c - s * s, s2 = 2.f * c * s;
    float c3 = c2 * c - s2 * s, s3 = s2 * c + c2 * s;
    tab[p]        = c * mag;          tab[64 + p]  = s * mag;          // L1
    tab[128 + p]  = c * (1.f - mag);  tab[192 + p] = s * (1.f - mag);  // O1
    tab[256 + p]  = c2 * m2;          tab[320 + p] = s2 * m2;          // L2
    tab[384 + p]  = c3 * m3;          tab[448 + p] = s3 * m3;          // L3
}

// ---------------- prep: W[K][ncols] -> bf16 B-fragment layout ----------------
__global__ void k_prepw(const float* __restrict__ w, ushort_t* __restrict__ wb,
                        int ncols, int nsteps, int total) {
    int tid = blockIdx.x * blockDim.x + threadIdx.x;
    if (tid >= total) return;
    int l  = tid & 63;
    int s  = (tid >> 6) % nsteps;
    int nt = tid / (64 * nsteps);
    int col = nt * 16 + (l & 15);
    int kb  = s * 32 + (l >> 4) * 8;
    us8 d;
#pragma unroll
    for (int j = 0; j < 8; ++j) d[j] = f2bf(w[(size_t)(kb + j) * ncols + col]);
    *(us8*)(wb + (size_t)tid * 8) = d;
}

// ---------------- MFMA fused MLP -> bf16 xpb (block-cooperative) ----------------
// One block = one m-tile pair. Phase1: wave w computes nt in {4w..4w+3} for both
// m-tiles into SHARED 16KB H. syncthreads. Phase2: wave w computes nt3 in
// {2w,2w+1} for both m-tiles. Grid = Mt2 blocks (4x more), LDS 16KB -> high occ.
__global__ void __launch_bounds__(256)
k_mlpf(const float* __restrict__ x, const ushort_t* __restrict__ wb1,
       const ushort_t* __restrict__ wb2, const ushort_t* __restrict__ wpb,
       const float* __restrict__ bp, ushort_t* __restrict__ xpb, int Mt) {
    __shared__ ushort_t hs[2][4096];   // 16KB: per-mtile 16x256 bf16 H (swizzled), block-shared
    const int wid = threadIdx.x >> 6, l = threadIdx.x & 63;
    const int mt0 = blockIdx.x * 2;
    const bool has1 = (mt0 + 1) < Mt;
    const int llo = l & 15, lhi = l >> 4;

    // A fragments for both m-tiles (K=128 -> 4 ksteps)
    bf16x8 af[2][4];
#pragma unroll
    for (int m = 0; m < 2; ++m) {
        int mt = (m == 1 && !has1) ? mt0 : (mt0 + m);   // clamp tail
        const float* xr = x + (size_t)(mt * 16 + llo) * 128 + lhi * 8;
#pragma unroll
        for (int s = 0; s < 4; ++s) {
            float4 v0 = *(const float4*)(xr + s * 32);
            float4 v1 = *(const float4*)(xr + s * 32 + 4);
            us8 d;
            d[0] = f2bf(v0.x); d[1] = f2bf(v0.y); d[2] = f2bf(v0.z); d[3] = f2bf(v0.w);
            d[4] = f2bf(v1.x); d[5] = f2bf(v1.y); d[6] = f2bf(v1.z); d[7] = f2bf(v1.w);
            af[m][s] = *(bf16x8*)&d;
        }
    }

    const bf16x8* B1 = (const bf16x8*)wb1;
    const bf16x8* B2 = (const bf16x8*)wb2;
    const bf16x8* BP = (const bf16x8*)wpb;
    const f32x4 zero = {0.f, 0.f, 0.f, 0.f};

    // ---- Phase 1: GEMM1/2 + silu; wave w owns nt = 4w..4w+3 ----
#pragma unroll
    for (int j = 0; j < 4; ++j) {
        int nt = wid * 4 + j;
        bf16x8 b1[4], b2[4];
#pragma unroll
        for (int s = 0; s < 4; ++s) {
            b1[s] = B1[(nt * 4 + s) * 64 + l];
            b2[s] = B2[(nt * 4 + s) * 64 + l];
        }
#pragma unroll
        for (int m = 0; m < 2; ++m) {
            f32x4 a1 = zero, a2 = zero;
#pragma unroll
            for (int s = 0; s < 4; ++s) {
                a1 = __builtin_amdgcn_mfma_f32_16x16x32_bf16(af[m][s], b1[s], a1, 0, 0, 0);
                a2 = __builtin_amdgcn_mfma_f32_16x16x32_bf16(af[m][s], b2[s], a2, 0, 0, 0);
            }
#pragma unroll
            for (int i = 0; i < 4; ++i) {
                float g = a1[i];
                float hv = (g / (1.f + __expf(-g))) * a2[i];
                int r = 4 * lhi + i;
                int byte = (r << 9) + ((nt * 16 + llo) << 1);  // row stride 512B (256 bf16)
                byte ^= (r & 7) << 4;
                hs[m][byte >> 1] = f2bf(hv);
            }
        }
    }
    __syncthreads();

    // ---- Phase 2: GEMM3 over K=256; wave w owns nt3 = 2w, 2w+1 ----
#pragma unroll
    for (int j = 0; j < 2; ++j) {
        int nt3 = wid * 2 + j;
        f32x4 acc0 = zero, acc1 = zero;
#pragma unroll
        for (int sg = 0; sg < 8; ++sg) {
            bf16x8 bw = BP[(nt3 * 8 + sg) * 64 + l];
            int byte = (llo << 9) + (sg << 6) + (lhi << 4);
            byte ^= (llo & 7) << 4;
            bf16x8 h0 = *(const bf16x8*)((const char*)hs[0] + byte);
            acc0 = __builtin_amdgcn_mfma_f32_16x16x32_bf16(h0, bw, acc0, 0, 0, 0);
            bf16x8 h1 = *(const bf16x8*)((const char*)hs[1] + byte);
            acc1 = __builtin_amdgcn_mfma_f32_16x16x32_bf16(h1, bw, acc1, 0, 0, 0);
        }
        float bpv = bp[nt3 * 16 + llo];
        {
            const int row0 = mt0 * 16;
#pragma unroll
            for (int i = 0; i < 4; ++i) {
                int r = row0 + 4 * lhi + i;
                xpb[(size_t)r * 128 + nt3 * 16 + llo] = f2bf(acc0[i] + bpv);
            }
        }
        if (has1) {
            const int row0 = (mt0 + 1) * 16;
#pragma unroll
            for (int i = 0; i < 4; ++i) {
                int r = row0 + 4 * lhi + i;
                xpb[(size_t)r * 128 + nt3 * 16 + llo] = f2bf(acc1[i] + bpv);
            }
        }
    }
}

// ---------------- CSR build (by dst). in-deg == out-deg for this edge list ----------------
__global__ void k_hist(const int* __restrict__ ei, int E, int* __restrict__ cnt) {
    int e = blockIdx.x * blockDim.x + threadIdx.x;
    if (e < E) atomicAdd(&cnt[ei[E + e]], 1);      // histogram over dst
}

__global__ void __launch_bounds__(256)
k_scanA(const int* __restrict__ cnt, int N, int* __restrict__ bsum) {
    __shared__ int s[256];
    int t = threadIdx.x;
    int i = blockIdx.x * 256 + t;
    int v = (i < N) ? cnt[i] : 0;
    s[t] = v;
    __syncthreads();
#pragma unroll
    for (int d = 128; d > 0; d >>= 1) {
        if (t < d) s[t] += s[t + d];
        __syncthreads();
    }
    if (t == 0) bsum[blockIdx.x] = s[0];
}

__global__ void __launch_bounds__(1024)
k_scanB(const int* __restrict__ bsum, int NB, int* __restrict__ bpre,
        int* __restrict__ offN) {
    __shared__ int s[1024];
    int t = threadIdx.x;
    int v = (t < NB) ? bsum[t] : 0;
    s[t] = v;
    __syncthreads();
    for (int d = 1; d < 1024; d <<= 1) {
        int u = (t >= d) ? s[t - d] : 0;
        __syncthreads();
        s[t] += u;
        __syncthreads();
    }
    if (t < NB) bpre[t] = s[t] - v;          // exclusive
    if (t == NB - 1) *offN = s[t];           // total
}

__global__ void __launch_bounds__(256)
k_scanC(const int* __restrict__ cnt, int N, const int* __restrict__ bpre,
        int* __restrict__ off, int* __restrict__ cursor, float* __restrict__ bv) {
    __shared__ int s[256];
    int t = threadIdx.x;
    int i = blockIdx.x * 256 + t;
    int v = (i < N) ? cnt[i] : 0;
    s[t] = v;
    __syncthreads();
    for (int d = 1; d < 256; d <<= 1) {
        int u = (t >= d) ? s[t - d] : 0;
        __syncthreads();
        s[t] += u;
        __syncthreads();
    }
    if (i < N) {
        int excl = bpre[blockIdx.x] + s[t] - v;
        off[i] = excl;
        cursor[i] = excl;
        bv[i] = (v > 1) ? (-1.f / ((float)v - 1.f + EPSF)) : 0.f;
    }
}

__global__ void k_fill(const int* __restrict__ ei, int E,
                       int* __restrict__ cursor, int* __restrict__ csr) {
    int e = blockIdx.x * blockDim.x + threadIdx.x;
    if (e < E) {
        int s = ei[e], d = ei[E + e];
        int p = atomicAdd(&cursor[d], 1);
        csr[p] = s;
    }
}

// ---------------- fused gather + node passes (one wave per node, all-bf16 tables) ----------------
__global__ void __launch_bounds__(256)
k_passA(const ushort_t* __restrict__ xpb, const float* __restrict__ bv,
        const int* __restrict__ off, const int* __restrict__ csr,
        const float* __restrict__ tab, ushort_t* __restrict__ Xbb,
        ushort_t* __restrict__ a1b, int N) {
    int tid = blockIdx.x * blockDim.x + threadIdx.x;
    int v = tid >> 6, l = tid & 63;
    if (v >= N) return;
    int beg = off[v], end = off[v + 1];
    float2 m0 = make_float2(0.f, 0.f), xb = make_float2(0.f, 0.f);
    const uint_t* tb = (const uint_t*)xpb;
    int k = beg;
    for (; k + 1 < end; k += 2) {
        int s0 = csr[k], s1 = csr[k + 1];
        uint_t u0 = tb[(size_t)s0 * 64 + l];
        uint_t u1 = tb[(size_t)s1 * 64 + l];
        float b0 = bv[s0], b1 = bv[s1];
        float2 t0 = bfu2(u0), t1v = bfu2(u1);
        m0.x += t0.x + t1v.x;        m0.y += t0.y + t1v.y;
        xb.x += b0 * t0.x + b1 * t1v.x;
        xb.y += b0 * t0.y + b1 * t1v.y;
    }
    if (k < end) {
        int s0 = csr[k];
        float2 t0 = bfu2(tb[(size_t)s0 * 64 + l]);
        float b0 = bv[s0];
        m0.x += t0.x; m0.y += t0.y;
        xb.x += b0 * t0.x; xb.y += b0 * t0.y;
    }
    ((uint_t*)Xbb)[(size_t)v * 64 + l] = packbf(xb);
    float2 xv = bfu2(tb[(size_t)v * 64 + l]);
    int dg = end - beg;
    float L1r = tab[l], L1i = tab[64 + l], O1r = tab[128 + l], O1i = tab[192 + l];
    float Q = 1.f / ((float)dg - 1.f + EPSF);
    float2 t1 = cmul(O1r, O1i, xv);
    float2 t2 = cmul(L1r, L1i, m0);
    float2 a = make_float2(t1.x + Q * t2.x, t1.y + Q * t2.y);
    if (dg == 1) a = xv;
    ((uint_t*)a1b)[(size_t)v * 64 + l] = packbf(a);
}

__global__ void __launch_bounds__(256)
k_passB(const ushort_t* __restrict__ xpb, const ushort_t* __restrict__ a1b,
        const float* __restrict__ bv, const int* __restrict__ off,
        const int* __restrict__ csr, const float* __restrict__ tab,
        ushort_t* __restrict__ ab1b, float* __restrict__ Bv, float* __restrict__ B2v,
        ushort_t* __restrict__ a2b, int N) {
    int tid = blockIdx.x * blockDim.x + threadIdx.x;
    int v = tid >> 6, l = tid & 63;
    if (v >= N) return;
    int beg = off[v], end = off[v + 1];
    float2 A1 = make_float2(0.f, 0.f), ab = make_float2(0.f, 0.f);
    float Bs = 0.f, B2s = 0.f;
    const uint_t* tb = (const uint_t*)a1b;
    int k = beg;
    for (; k + 1 < end; k += 2) {
        int s0 = csr[k], s1 = csr[k + 1];
        uint_t u0 = tb[(size_t)s0 * 64 + l];
        uint_t u1 = tb[(size_t)s1 * 64 + l];
        float b0 = bv[s0], b1 = bv[s1];
        float2 t0 = bfu2(u0), t1v = bfu2(u1);
        A1.x += t0.x + t1v.x;  A1.y += t0.y + t1v.y;
        ab.x += b0 * t0.x + b1 * t1v.x;
        ab.y += b0 * t0.y + b1 * t1v.y;
        Bs += b0 + b1; B2s += b0 * b0 + b1 * b1;
    }
    if (k < end) {
        int s0 = csr[k];
        float2 t0 = bfu2(tb[(size_t)s0 * 64 + l]);
        float b0 = bv[s0];
        A1.x += t0.x; A1.y += t0.y;
        ab.x += b0 * t0.x; ab.y += b0 * t0.y;
        Bs += b0; B2s += b0 * b0;
    }
    ((uint_t*)ab1b)[(size_t)v * 64 + l] = packbf(ab);
    if (l == 0) { Bv[v] = Bs; B2v[v] = B2s; }
    float2 xv = bfu2(((const uint_t*)xpb)[(size_t)v * 64 + l]);
    int dg = end - beg;
    float L1r = tab[l], L1i = tab[64 + l], O1r = tab[128 + l], O1i = tab[192 + l];
    float2 lx = cmul(L1r, L1i, xv);
    float2 m1 = make_float2(A1.x + Bs * lx.x, A1.y + Bs * lx.y);
    float Q = 1.f / ((float)dg - 1.f + EPSF);
    float2 t1 = cmul(O1r, O1i, xv);
    float2 lm = cmul(L1r, L1i, m1);
    float2 a = make_float2(t1.x + Q * lm.x, t1.y + Q * lm.y);
    if (dg == 1) a = xv;
    ((uint_t*)a2b)[(size_t)v * 64 + l] = packbf(a);
}

__global__ void __launch_bounds__(256)
k_passC(const ushort_t* __restrict__ xpb, const ushort_t* __restrict__ a2b,
        const ushort_t* __restrict__ a1b, const ushort_t* __restrict__ Xbb,
        const float* __restrict__ bv, const float* __restrict__ Bv,
        const int* __restrict__ off, const int* __restrict__ csr,
        const float* __restrict__ tab, ushort_t* __restrict__ a3b, int N) {
    int tid = blockIdx.x * blockDim.x + threadIdx.x;
    int v = tid >> 6, l = tid & 63;
    if (v >= N) return;
    int beg = off[v], end = off[v + 1];
    float2 A2 = make_float2(0.f, 0.f);
    const uint_t* tb = (const uint_t*)a2b;
    int k = beg;
    for (; k + 1 < end; k += 2) {
        int s0 = csr[k], s1 = csr[k + 1];
        float2 t0 = bfu2(tb[(size_t)s0 * 64 + l]);
        float2 t1v = bfu2(tb[(size_t)s1 * 64 + l]);
        A2.x += t0.x + t1v.x; A2.y += t0.y + t1v.y;
    }
    if (k < end) {
        float2 t0 = bfu2(tb[(size_t)csr[k] * 64 + l]);
        A2.x += t0.x; A2.y += t0.y;
    }
    float2 xv  = bfu2(((const uint_t*)xpb)[(size_t)v * 64 + l]);
    float2 a1v = bfu2(((const uint_t*)a1b)[(size_t)v * 64 + l]);
    float2 Xbv = bfu2(((const uint_t*)Xbb)[(size_t)v * 64 + l]);
    int dg = end - beg;
    float Bs = Bv[v], bs = bv[v];
    float L1r = tab[l], L1i = tab[64 + l], O1r = tab[128 + l], O1i = tab[192 + l];
    float L2r = tab[256 + l], L2i = tab[320 + l];
    float2 la1 = cmul(L1r, L1i, a1v);
    float2 lxb = cmul(L2r, L2i, Xbv);
    float2 m2 = make_float2(A2.x + Bs * la1.x + bs * lxb.x,
                            A2.y + Bs * la1.y + bs * lxb.y);
    float Q = 1.f / ((float)dg - 1.f + EPSF);
    float2 t1 = cmul(O1r, O1i, xv);
    float2 lm = cmul(L1r, L1i, m2);
    float2 a = make_float2(t1.x + Q * lm.x, t1.y + Q * lm.y);
    if (dg == 1) a = xv;
    ((uint_t*)a3b)[(size_t)v * 64 + l] = packbf(a);
}

__global__ void __launch_bounds__(256)
k_passD(const float* __restrict__ xin, const ushort_t* __restrict__ xpb,
        const ushort_t* __restrict__ a3b, const ushort_t* __restrict__ a2b,
        const ushort_t* __restrict__ ab1b, const float* __restrict__ bv,
        const float* __restrict__ Bv, const float* __restrict__ B2v,
        const int* __restrict__ off, const int* __restrict__ csr,
        const float* __restrict__ tab, float* __restrict__ out, int N) {
    int tid = blockIdx.x * blockDim.x + threadIdx.x;
    int v = tid >> 6, l = tid & 63;
    if (v >= N) return;
    int beg = off[v], end = off[v + 1];
    float2 A3 = make_float2(0.f, 0.f);
    const uint_t* tb = (const uint_t*)a3b;
    int k = beg;
    for (; k + 1 < end; k += 2) {
        int s0 = csr[k], s1 = csr[k + 1];
        float2 t0 = bfu2(tb[(size_t)s0 * 64 + l]);
        float2 t1v = bfu2(tb[(size_t)s1 * 64 + l]);
        A3.x += t0.x + t1v.x; A3.y += t0.y + t1v.y;
    }
    if (k < end) {
        float2 t0 = bfu2(tb[(size_t)csr[k] * 64 + l]);
        A3.x += t0.x; A3.y += t0.y;
    }
    size_t o = (size_t)v * 128 + 2 * l;
    float2 xv  = bfu2(((const uint_t*)xpb)[(size_t)v * 64 + l]);
    float2 a2v = bfu2(((const uint_t*)a2b)[(size_t)v * 64 + l]);
    float2 Abv = bfu2(((const uint_t*)ab1b)[(size_t)v * 64 + l]);
    int dg = end - beg;
    float Bs = Bv[v], bs = bv[v], B2s = B2v[v];
    float L1r = tab[l], L1i = tab[64 + l], O1r = tab[128 + l], O1i = tab[192 + l];
    float L2r = tab[256 + l], L2i = tab[320 + l];
    float L3r = tab[384 + l], L3i = tab[448 + l];
    float2 la2 = cmul(L1r, L1i, a2v);
    float2 lab = cmul(L2r, L2i, Abv);
    float2 lx3 = cmul(L3r, L3i, xv);
    float bB2 = bs * B2s;
    float2 m3 = make_float2(A3.x + Bs * la2.x + bs * lab.x + bB2 * lx3.x,
                            A3.y + Bs * la2.y + bs * lab.y + bB2 * lx3.y);
    float2 g;
    if (dg == 0) {
        g = xv;
    } else {
        float inv = 1.f / ((float)dg + EPSF);
        float2 t1 = cmul(O1r, O1i, xv);
        float2 lm = cmul(L1r, L1i, m3);
        g = make_float2(t1.x + lm.x * inv, t1.y + lm.y * inv);
    }
    float2 xi = *(const float2*)&xin[o];
    float2 res = make_float2(xi.x + fmaxf(g.x, 0.f), xi.y + fmaxf(g.y, 0.f));
    *(float2*)&out[o] = res;
}

extern "C" void kernel_launch(void* const* d_in, const int* in_sizes, int n_in,
                              void* d_out, int out_size, void* d_ws, size_t ws_size,
                              hipStream_t stream) {
    const float* x   = (const float*)d_in[0];
    const int*   ei  = (const int*)d_in[1];
    const float* ldt = (const float*)d_in[2];
    const float* llr = (const float*)d_in[3];
    const float* lim = (const float*)d_in[4];
    const float* W1  = (const float*)d_in[5];
    const float* W2  = (const float*)d_in[6];
    const float* Wp  = (const float*)d_in[7];
    const float* bp  = (const float*)d_in[8];
    float* out = (float*)d_out;

    const int N = in_sizes[0] / 128;
    const int E = in_sizes[1] / 2;
    const size_t nd = (size_t)N * 128;
    const int Mt = (N + 15) / 16;          // 16-row m-tiles
    const int Mt2 = (Mt + 1) / 2;          // m-tile pairs (one block each)
    const int NB = (N + 255) / 256;        // scan blocks

    ushort_t* xpb  = (ushort_t*)d_ws;      // all-bf16 node tables
    ushort_t* a1b  = xpb + nd;
    ushort_t* a2b  = a1b + nd;
    ushort_t* a3b  = a2b + nd;
    ushort_t* Xbb  = a3b + nd;
    ushort_t* ab1b = Xbb + nd;

    int*   cnt    = (int*)(ab1b + nd);     // N
    int*   off    = cnt + N;               // N+4 (padded)
    int*   cursor = off + N + 4;           // N
    float* bv     = (float*)(cursor + N);  // N
    float* Bv     = bv + N;                // N
    float* B2v    = Bv + N;                // N
    float* tab    = B2v + N;               // 512
    int*   bsum   = (int*)(tab + 512);     // NB
    int*   bpre   = bsum + NB;             // NB
    int*   csr    = bpre + NB;             // E
    ushort_t* wb1 = (ushort_t*)(csr + E);  // 32768
    ushort_t* wb2 = wb1 + 32768;           // 32768
    ushort_t* wpb = wb2 + 32768;           // 32768

    const int nodeBlocks = (int)(((size_t)N * 64 + 255) / 256);
    const int eBlocks    = (E + 255) / 256;

    hipMemsetAsync(cnt, 0, (size_t)N * sizeof(int), stream);
    k_lamtab<<<1, 64, 0, stream>>>(ldt, llr, lim, tab);

    // bf16 weight prep + MFMA MLP (x converted in-kernel)
    k_prepw<<<16, 256, 0, stream>>>(W1, wb1, 256, 4, 16 * 4 * 64);
    k_prepw<<<16, 256, 0, stream>>>(W2, wb2, 256, 4, 16 * 4 * 64);
    k_prepw<<<16, 256, 0, stream>>>(Wp, wpb, 128, 8, 8 * 8 * 64);
    k_mlpf<<<Mt2, 256, 0, stream>>>(x, wb1, wb2, wpb, bp, xpb, Mt);

    // CSR build (hierarchical scan)
    k_hist<<<eBlocks, 256, 0, stream>>>(ei, E, cnt);
    k_scanA<<<NB, 256, 0, stream>>>(cnt, N, bsum);
    k_scanB<<<1, 1024, 0, stream>>>(bsum, NB, bpre, &off[N]);
    k_scanC<<<NB, 256, 0, stream>>>(cnt, N, bpre, off, cursor, bv);
    k_fill<<<eBlocks, 256, 0, stream>>>(ei, E, cursor, csr);

    // fused gather + node passes (all-bf16 tables)
    k_passA<<<nodeBlocks, 256, 0, stream>>>(xpb, bv, off, csr, tab, Xbb, a1b, N);
    k_passB<<<nodeBlocks, 256, 0, stream>>>(xpb, a1b, bv, off, csr, tab, ab1b, Bv, B2v, a2b, N);
    k_passC<<<nodeBlocks, 256, 0, stream>>>(xpb, a2b, a1b, Xbb, bv, Bv, off, csr, tab, a3b, N);
    k_passD<<<nodeBlocks, 256, 0, stream>>>(x, xpb, a3b, a2b, ab1b, bv, Bv, B2v, off, csr, tab, out, N);
}